// Round 1
// baseline (5911.781 us; speedup 1.0000x reference)
//
#include <hip/hip_runtime.h>
#include <math.h>

namespace {

constexpr int B = 8, C = 384, S = 1024;
constexpr int HID = 512, HEADS = 4, HD = 96, FFN = 1536;
constexpr int M = B * S;          // 8192 rows
constexpr int C3 = 3 * C;         // 1152

// ---------------- transpose [C,S] -> [S,C] per batch ----------------
__global__ __launch_bounds__(256) void transpose_cs(const float* __restrict__ in,
                                                    float* __restrict__ out) {
  __shared__ float tile[32][33];
  int b = blockIdx.z;
  int s0 = blockIdx.x * 32, c0 = blockIdx.y * 32;
  const float* ip = in + (size_t)b * C * S;
  float* op = out + (size_t)b * S * C;
  int tx = threadIdx.x, ty = threadIdx.y;   // 32 x 8
#pragma unroll
  for (int i = 0; i < 32; i += 8)
    tile[ty + i][tx] = ip[(size_t)(c0 + ty + i) * S + s0 + tx];
  __syncthreads();
#pragma unroll
  for (int i = 0; i < 32; i += 8)
    op[(size_t)(s0 + ty + i) * C + c0 + tx] = tile[tx][ty + i];
}

// ---------------- generic NT GEMM: Cmat[M,N] = A[M,K] * W[N,K]^T ----------------
// EPI: 0 none, 1 SiLU, 2 GELU(exact). ACC: accumulate onto existing Cmat.
// resid (nullable): add resid[m*ldc+n] after bias/epilogue.
template <int EPI, bool ACC>
__global__ __launch_bounds__(256) void gemm_nt(const float* __restrict__ A, int lda,
                                               const float* __restrict__ Wt, int ldw,
                                               const float* __restrict__ bias,
                                               const float* __restrict__ resid,
                                               float* __restrict__ Cmat, int ldc,
                                               int Kdim) {
  constexpr int BM = 64, BN = 64, BK = 16;
  __shared__ float As[BM][BK + 1];
  __shared__ float Ws[BN][BK + 1];
  int tid = threadIdx.x;
  int bn = blockIdx.x * BN, bm = blockIdx.y * BM;
  int tx = tid & 15, ty = tid >> 4;
  float acc[4][4] = {};
  for (int k0 = 0; k0 < Kdim; k0 += BK) {
#pragma unroll
    for (int i = 0; i < 4; ++i) {
      int idx = tid + i * 256;
      int r = idx >> 4, kk = idx & 15;
      As[r][kk] = A[(size_t)(bm + r) * lda + k0 + kk];
      Ws[r][kk] = Wt[(size_t)(bn + r) * ldw + k0 + kk];
    }
    __syncthreads();
#pragma unroll
    for (int kk = 0; kk < BK; ++kk) {
      float a[4], w[4];
#pragma unroll
      for (int i = 0; i < 4; ++i) a[i] = As[ty * 4 + i][kk];
#pragma unroll
      for (int j = 0; j < 4; ++j) w[j] = Ws[tx * 4 + j][kk];
#pragma unroll
      for (int i = 0; i < 4; ++i)
#pragma unroll
        for (int j = 0; j < 4; ++j) acc[i][j] = fmaf(a[i], w[j], acc[i][j]);
    }
    __syncthreads();
  }
#pragma unroll
  for (int i = 0; i < 4; ++i) {
    int m = bm + ty * 4 + i;
#pragma unroll
    for (int j = 0; j < 4; ++j) {
      int n = bn + tx * 4 + j;
      float v = acc[i][j];
      if (ACC) v += Cmat[(size_t)m * ldc + n];
      if (bias) v += bias[n];
      if (EPI == 1) v = v / (1.f + expf(-v));                       // SiLU
      if (EPI == 2) v = 0.5f * v * (1.f + erff(v * 0.70710678f));   // exact GELU
      if (resid) v += resid[(size_t)m * ldc + n];
      Cmat[(size_t)m * ldc + n] = v;
    }
  }
}

// ---------------- agent logit + threshold ----------------
__global__ __launch_bounds__(64) void sel_kernel(const float* __restrict__ hidden,
                                                 const float* __restrict__ w2,
                                                 const float* __restrict__ b2,
                                                 int* __restrict__ sel) {
  int row = blockIdx.x, t = threadIdx.x;
  const float* hr = hidden + (size_t)row * HID;
  float s = 0.f;
#pragma unroll
  for (int i = 0; i < HID / 64; ++i) s += hr[t + i * 64] * w2[t + i * 64];
  for (int off = 32; off; off >>= 1) s += __shfl_down(s, off);
  if (t == 0) sel[row] = (s + b2[0]) > 0.f ? 1 : 0;
}

// ---------------- LayerNorm over C=384, one wave per row ----------------
__global__ __launch_bounds__(64) void ln_kernel(const float* __restrict__ x,
                                                const float* __restrict__ g,
                                                const float* __restrict__ bt,
                                                float* __restrict__ y) {
  int row = blockIdx.x, t = threadIdx.x;
  const float* xr = x + (size_t)row * C;
  float v[C / 64];
  float s = 0.f, s2 = 0.f;
#pragma unroll
  for (int i = 0; i < C / 64; ++i) {
    float a = xr[t + i * 64];
    v[i] = a;
    s += a;
    s2 += a * a;
  }
  for (int off = 32; off; off >>= 1) {
    s += __shfl_down(s, off);
    s2 += __shfl_down(s2, off);
  }
  s = __shfl(s, 0);
  s2 = __shfl(s2, 0);
  float mean = s / C;
  float var = s2 / C - mean * mean;
  float inv = rsqrtf(var + 1e-5f);
#pragma unroll
  for (int i = 0; i < C / 64; ++i) {
    int c = t + i * 64;
    y[(size_t)row * C + c] = (v[i] - mean) * inv * g[c] + bt[c];
  }
}

// ---------------- block reduction helper (256 threads = 4 waves) ----------------
__device__ inline float block_red(float v, float* red, int tid, bool ismax) {
  for (int off = 32; off; off >>= 1)
    v = ismax ? fmaxf(v, __shfl_down(v, off)) : v + __shfl_down(v, off);
  if ((tid & 63) == 0) red[tid >> 6] = v;
  __syncthreads();
  float r = ismax ? fmaxf(fmaxf(red[0], red[1]), fmaxf(red[2], red[3]))
                  : (red[0] + red[1] + red[2] + red[3]);
  __syncthreads();
  return r;
}

// ---------------- fused masked attention: one block per (b, h, q) ----------------
__global__ __launch_bounds__(256) void attn_kernel(const float* __restrict__ qkv,
                                                   const int* __restrict__ sel,
                                                   float* __restrict__ o) {
  __shared__ float qs[HD];
  __shared__ float sc[S];
  __shared__ float red[4];
  __shared__ float part[2][HD];
  int q = blockIdx.x;
  int bh = blockIdx.y;
  int b = bh / HEADS, h = bh % HEADS;
  int tid = threadIdx.x;
  const float* qrow = qkv + ((size_t)(b * S + q)) * C3 + h * HD;
  if (tid < HD) qs[tid] = qrow[tid];
  __syncthreads();
  const float scale = rsqrtf((float)HD);
  const float* kbase = qkv + (size_t)b * S * C3 + C + h * HD;
  const int* selb = sel + b * S;
  for (int k0 = tid; k0 < S; k0 += 256) {
    const float* krow = kbase + (size_t)k0 * C3;
    float acc = 0.f;
#pragma unroll 8
    for (int d = 0; d < HD; ++d) acc += qs[d] * krow[d];
    sc[k0] = selb[k0] ? acc * scale : -1e9f;
  }
  __syncthreads();
  float lm = -INFINITY;
  for (int i = tid; i < S; i += 256) lm = fmaxf(lm, sc[i]);
  float mx = block_red(lm, red, tid, true);
  float ls = 0.f;
  for (int i = tid; i < S; i += 256) {
    float e = expf(sc[i] - mx);
    sc[i] = e;
    ls += e;
  }
  float sum = block_red(ls, red, tid, false);  // trailing sync makes sc[] visible
  float inv = 1.f / sum;
  const float* vbase = qkv + (size_t)b * S * C3 + 2 * C + h * HD;
  int pr = tid >> 7, d = tid & 127;
  if (d < HD) {
    float accv = 0.f;
    int k0 = pr * (S / 2);
    for (int k = k0; k < k0 + S / 2; ++k) accv += sc[k] * vbase[(size_t)k * C3 + d];
    part[pr][d] = accv;
  }
  __syncthreads();
  if (tid < HD)
    o[((size_t)(b * S + q)) * C + h * HD + tid] = (part[0][tid] + part[1][tid]) * inv;
}

// ---------------- final scatter: out[b,c,s] ----------------
__global__ __launch_bounds__(256) void final_kernel(const float* __restrict__ x0,
                                                    const float* __restrict__ x1,
                                                    const int* __restrict__ sel,
                                                    const float* __restrict__ f_ir,
                                                    const float* __restrict__ f_vis,
                                                    float* __restrict__ out) {
  int i = blockIdx.x * 256 + threadIdx.x;  // over B*C*S = 3145728
  int s = i & (S - 1);
  int bc = i >> 10;
  int c = bc % C, b = bc / C;
  float v;
  if (sel[b * S + s]) {
    size_t r = ((size_t)(b * S + s)) * C + c;
    v = x0[r] + x1[r];
  } else {
    v = f_ir[i] + f_vis[i];
  }
  out[i] = v;
}

}  // namespace

extern "C" void kernel_launch(void* const* d_in, const int* in_sizes, int n_in,
                              void* d_out, int out_size, void* d_ws, size_t ws_size,
                              hipStream_t stream) {
  const float* f_ir = (const float*)d_in[0];
  const float* f_vis = (const float*)d_in[1];
  const float* agent_w1 = (const float*)d_in[2];
  const float* agent_b1 = (const float*)d_in[3];
  const float* agent_w2 = (const float*)d_in[4];
  const float* agent_b2 = (const float*)d_in[5];
  const float* norm_g = (const float*)d_in[6];
  const float* norm_b = (const float*)d_in[7];
  const float* in_w = (const float*)d_in[8];
  const float* in_b = (const float*)d_in[9];
  const float* out_w = (const float*)d_in[10];
  const float* out_b = (const float*)d_in[11];
  const float* ffn_w1 = (const float*)d_in[12];
  const float* ffn_b1 = (const float*)d_in[13];
  const float* ffn_w2 = (const float*)d_in[14];
  const float* ffn_b2 = (const float*)d_in[15];
  float* out = (float*)d_out;

  constexpr size_t MS = (size_t)M * C;  // 3145728 floats
  float* ws = (float*)d_ws;
  float* x0 = ws;                    // stream-0 state (starts as flat_ir)
  float* x1 = ws + MS;               // stream-1 state (starts as flat_vis)
  float* Dbuf = ws + 2 * MS;         // xn / attn_o   [M, C]
  float* Ebuf = ws + 3 * MS;         // hidden / qkv / ffn_h  [M, 1536] max
  int* sel = (int*)(ws + 3 * MS + (size_t)M * FFN);

  // 1) transposes
  transpose_cs<<<dim3(S / 32, C / 32, B), dim3(32, 8), 0, stream>>>(f_ir, x0);
  transpose_cs<<<dim3(S / 32, C / 32, B), dim3(32, 8), 0, stream>>>(f_vis, x1);

  // 2) agent hidden = SiLU(w1 @ [ir;vis] + b1), split over the two halves of K
  gemm_nt<0, false><<<dim3(HID / 64, M / 64), 256, 0, stream>>>(
      x0, C, agent_w1, 2 * C, nullptr, nullptr, Ebuf, HID, C);
  gemm_nt<1, true><<<dim3(HID / 64, M / 64), 256, 0, stream>>>(
      x1, C, agent_w1 + C, 2 * C, agent_b1, nullptr, Ebuf, HID, C);

  // 3) selection mask
  sel_kernel<<<M, 64, 0, stream>>>(Ebuf, agent_w2, agent_b2, sel);

  // 4) two mixer streams
  for (int t = 0; t < 2; ++t) {
    float* x = t ? x1 : x0;
    const float* g = norm_g + t * C;
    const float* bt = norm_b + t * C;
    // LN1
    ln_kernel<<<M, 64, 0, stream>>>(x, g, bt, Dbuf);
    // QKV
    gemm_nt<0, false><<<dim3(C3 / 64, M / 64), 256, 0, stream>>>(
        Dbuf, C, in_w + (size_t)t * C3 * C, C, in_b + t * C3, nullptr, Ebuf, C3, C);
    // attention
    attn_kernel<<<dim3(S, B * HEADS), 256, 0, stream>>>(Ebuf, sel, Dbuf);
    // out proj + residual
    gemm_nt<0, false><<<dim3(C / 64, M / 64), 256, 0, stream>>>(
        Dbuf, C, out_w + (size_t)t * C * C, C, out_b + t * C, x, x, C, C);
    // LN2
    ln_kernel<<<M, 64, 0, stream>>>(x, g, bt, Dbuf);
    // FFN1 (GELU)
    gemm_nt<2, false><<<dim3(FFN / 64, M / 64), 256, 0, stream>>>(
        Dbuf, C, ffn_w1 + (size_t)t * FFN * C, C, ffn_b1 + t * FFN, nullptr, Ebuf, FFN, C);
    // FFN2 + residual
    gemm_nt<0, false><<<dim3(C / 64, M / 64), 256, 0, stream>>>(
        Ebuf, FFN, ffn_w2 + (size_t)t * C * FFN, FFN, ffn_b2 + t * C, x, x, C, FFN);
  }

  // 5) final scatter back to [B,C,H,W]
  final_kernel<<<(B * C * S) / 256, 256, 0, stream>>>(x0, x1, sel, f_ir, f_vis, out);
}

// Round 3
// 1755.460 us; speedup vs baseline: 3.3677x; 3.3677x over previous
//
#include <hip/hip_runtime.h>
#include <math.h>

namespace {

constexpr int B = 8, C = 384, S = 1024;
constexpr int HID = 512, HEADS = 4, HD = 96, FFN = 1536;
constexpr int M = B * S;          // 8192 rows
constexpr int C3 = 3 * C;         // 1152

using short8 = __attribute__((ext_vector_type(8))) short;
using short4 = __attribute__((ext_vector_type(4))) short;
using f32x4 = __attribute__((ext_vector_type(4))) float;

__device__ inline unsigned short f2bf(float f) {
  unsigned int u = __builtin_bit_cast(unsigned int, f);
  u += 0x7fffu + ((u >> 16) & 1u);
  return (unsigned short)(u >> 16);
}

// ---------------- transpose [C,S] -> [S,C] per batch ----------------
__global__ __launch_bounds__(256) void transpose_cs(const float* __restrict__ in,
                                                    float* __restrict__ out) {
  __shared__ float tile[32][33];
  int b = blockIdx.z;
  int s0 = blockIdx.x * 32, c0 = blockIdx.y * 32;
  const float* ip = in + (size_t)b * C * S;
  float* op = out + (size_t)b * S * C;
  int tx = threadIdx.x, ty = threadIdx.y;   // 32 x 8
#pragma unroll
  for (int i = 0; i < 32; i += 8)
    tile[ty + i][tx] = ip[(size_t)(c0 + ty + i) * S + s0 + tx];
  __syncthreads();
#pragma unroll
  for (int i = 0; i < 32; i += 8)
    op[(size_t)(s0 + ty + i) * C + c0 + tx] = tile[tx][ty + i];
}

// ---------------- generic NT GEMM: Cmat[M,N] = A[M,K] * W[N,K]^T ----------------
template <int EPI, bool ACC>
__global__ __launch_bounds__(256) void gemm_nt(const float* __restrict__ A, int lda,
                                               const float* __restrict__ Wt, int ldw,
                                               const float* __restrict__ bias,
                                               const float* __restrict__ resid,
                                               float* __restrict__ Cmat, int ldc,
                                               int Kdim) {
  constexpr int BM = 64, BN = 64, BK = 16;
  __shared__ float As[BM][BK + 1];
  __shared__ float Ws[BN][BK + 1];
  int tid = threadIdx.x;
  int bn = blockIdx.x * BN, bm = blockIdx.y * BM;
  int tx = tid & 15, ty = tid >> 4;
  float acc[4][4] = {};
  for (int k0 = 0; k0 < Kdim; k0 += BK) {
#pragma unroll
    for (int i = 0; i < 4; ++i) {
      int idx = tid + i * 256;
      int r = idx >> 4, kk = idx & 15;
      As[r][kk] = A[(size_t)(bm + r) * lda + k0 + kk];
      Ws[r][kk] = Wt[(size_t)(bn + r) * ldw + k0 + kk];
    }
    __syncthreads();
#pragma unroll
    for (int kk = 0; kk < BK; ++kk) {
      float a[4], w[4];
#pragma unroll
      for (int i = 0; i < 4; ++i) a[i] = As[ty * 4 + i][kk];
#pragma unroll
      for (int j = 0; j < 4; ++j) w[j] = Ws[tx * 4 + j][kk];
#pragma unroll
      for (int i = 0; i < 4; ++i)
#pragma unroll
        for (int j = 0; j < 4; ++j) acc[i][j] = fmaf(a[i], w[j], acc[i][j]);
    }
    __syncthreads();
  }
#pragma unroll
  for (int i = 0; i < 4; ++i) {
    int m = bm + ty * 4 + i;
#pragma unroll
    for (int j = 0; j < 4; ++j) {
      int n = bn + tx * 4 + j;
      float v = acc[i][j];
      if (ACC) v += Cmat[(size_t)m * ldc + n];
      if (bias) v += bias[n];
      if (EPI == 1) v = v / (1.f + expf(-v));                       // SiLU
      if (EPI == 2) v = 0.5f * v * (1.f + erff(v * 0.70710678f));   // exact GELU
      if (resid) v += resid[(size_t)m * ldc + n];
      Cmat[(size_t)m * ldc + n] = v;
    }
  }
}

// ---------------- agent logit + threshold ----------------
__global__ __launch_bounds__(64) void sel_kernel(const float* __restrict__ hidden,
                                                 const float* __restrict__ w2,
                                                 const float* __restrict__ b2,
                                                 int* __restrict__ sel) {
  int row = blockIdx.x, t = threadIdx.x;
  const float* hr = hidden + (size_t)row * HID;
  float s = 0.f;
#pragma unroll
  for (int i = 0; i < HID / 64; ++i) s += hr[t + i * 64] * w2[t + i * 64];
  for (int off = 32; off; off >>= 1) s += __shfl_down(s, off);
  if (t == 0) sel[row] = (s + b2[0]) > 0.f ? 1 : 0;
}

// ---------------- LayerNorm over C=384, one wave per row ----------------
__global__ __launch_bounds__(64) void ln_kernel(const float* __restrict__ x,
                                                const float* __restrict__ g,
                                                const float* __restrict__ bt,
                                                float* __restrict__ y) {
  int row = blockIdx.x, t = threadIdx.x;
  const float* xr = x + (size_t)row * C;
  float v[C / 64];
  float s = 0.f, s2 = 0.f;
#pragma unroll
  for (int i = 0; i < C / 64; ++i) {
    float a = xr[t + i * 64];
    v[i] = a;
    s += a;
    s2 += a * a;
  }
  for (int off = 32; off; off >>= 1) {
    s += __shfl_down(s, off);
    s2 += __shfl_down(s2, off);
  }
  s = __shfl(s, 0);
  s2 = __shfl(s2, 0);
  float mean = s / C;
  float var = s2 / C - mean * mean;
  float inv = rsqrtf(var + 1e-5f);
#pragma unroll
  for (int i = 0; i < C / 64; ++i) {
    int c = t + i * 64;
    y[(size_t)row * C + c] = (v[i] - mean) * inv * g[c] + bt[c];
  }
}

// ---------------- flash MFMA attention ----------------
// Block: one (b,h), 64 q-rows; 4 waves x 16 q-rows. K-tiles of 32.
// Scores via mfma(A=K, B=Q) -> lane owns 8 scores of ONE q-row (q = lane&15,
// k = 4*(lane>>4)+reg (+16)). Online softmax in-register; P bounced through a
// per-wave LDS tile to re-fragment as the PV B-operand. PV: mfma(A=V^T, B=P^T)
// accumulates O^T[d, q]; C/D layout col=lane&15, row=(lane>>4)*4+reg.
__global__ __launch_bounds__(256) void attn_mfma(const float* __restrict__ qkv,
                                                 const int* __restrict__ sel,
                                                 float* __restrict__ o_out) {
  __shared__ unsigned short Qs[64][104];   // [q][d], pad for banks
  __shared__ unsigned short Ks[32][104];   // [k][d]
  __shared__ unsigned short Vt[96][40];    // [d][k]
  __shared__ unsigned short Ps[4][16][40]; // per-wave [q][k]
  __shared__ float msk[S];

  int bq0 = blockIdx.x * 64;
  int bh = blockIdx.y;
  int b = bh >> 2, h = bh & 3;
  int tid = threadIdx.x;
  int wave = tid >> 6, lane = tid & 63;
  int lo = lane & 15, g = lane >> 4;

  // stage Q tile (64 x 96) as bf16
  const float* qbase = qkv + ((size_t)(b * S + bq0)) * C3 + h * HD;
#pragma unroll
  for (int i = 0; i < 24; ++i) {
    int idx = i * 256 + tid;
    int r = idx / 96, d = idx - r * 96;
    Qs[r][d] = f2bf(qbase[(size_t)r * C3 + d]);
  }
  // stage additive mask for the whole batch row
  const int* selb = sel + b * S;
#pragma unroll
  for (int i = 0; i < 4; ++i) {
    int k = i * 256 + tid;
    msk[k] = selb[k] ? 0.f : -1e9f;
  }
  __syncthreads();

  const float scale = 0.1020620726f;  // 1/sqrt(96)
  float m = -INFINITY, l = 0.f;
  f32x4 o[6] = {};

  for (int kt0 = 0; kt0 < S; kt0 += 32) {
    // stage K tile [32][96] and V^T tile [96][32]
    const float* kbase = qkv + ((size_t)(b * S + kt0)) * C3 + C + h * HD;
    const float* vbase = qkv + ((size_t)(b * S + kt0)) * C3 + 2 * C + h * HD;
#pragma unroll
    for (int i = 0; i < 12; ++i) {
      int idx = i * 256 + tid;
      int r = idx / 96, d = idx - r * 96;
      Ks[r][d] = f2bf(kbase[(size_t)r * C3 + d]);
      Vt[d][r] = f2bf(vbase[(size_t)r * C3 + d]);
    }
    __syncthreads();

    // scores S^T[k, q] for this wave's q rows
    f32x4 st0 = {}, st1 = {};
#pragma unroll
    for (int c = 0; c < 3; ++c) {
      short8 bq = *reinterpret_cast<const short8*>(&Qs[wave * 16 + lo][c * 32 + g * 8]);
      short8 ak0 = *reinterpret_cast<const short8*>(&Ks[lo][c * 32 + g * 8]);
      short8 ak1 = *reinterpret_cast<const short8*>(&Ks[lo + 16][c * 32 + g * 8]);
      st0 = __builtin_amdgcn_mfma_f32_16x16x32_bf16(ak0, bq, st0, 0, 0, 0);
      st1 = __builtin_amdgcn_mfma_f32_16x16x32_bf16(ak1, bq, st1, 0, 0, 0);
    }

    // mask + scale; per-lane row softmax pieces
    float s0[4], s1[4];
    float pmax = -INFINITY;
#pragma unroll
    for (int r = 0; r < 4; ++r) {
      s0[r] = st0[r] * scale + msk[kt0 + g * 4 + r];
      s1[r] = st1[r] * scale + msk[kt0 + 16 + g * 4 + r];
      pmax = fmaxf(pmax, fmaxf(s0[r], s1[r]));
    }
    pmax = fmaxf(pmax, __shfl_xor(pmax, 16));
    pmax = fmaxf(pmax, __shfl_xor(pmax, 32));
    float mn = fmaxf(m, pmax);
    float sc = __expf(m - mn);
    m = mn;
    float p0[4], p1[4], ps = 0.f;
#pragma unroll
    for (int r = 0; r < 4; ++r) {
      p0[r] = __expf(s0[r] - mn);
      p1[r] = __expf(s1[r] - mn);
      ps += p0[r] + p1[r];
    }
    ps += __shfl_xor(ps, 16);
    ps += __shfl_xor(ps, 32);
    l = l * sc + ps;
#pragma unroll
    for (int dt = 0; dt < 6; ++dt)
#pragma unroll
      for (int r = 0; r < 4; ++r) o[dt][r] *= sc;

    // bounce P through per-wave LDS to re-fragment for PV
    short4 w0, w1;
#pragma unroll
    for (int r = 0; r < 4; ++r) {
      w0[r] = (short)f2bf(p0[r]);
      w1[r] = (short)f2bf(p1[r]);
    }
    *reinterpret_cast<short4*>(&Ps[wave][lo][g * 4]) = w0;
    *reinterpret_cast<short4*>(&Ps[wave][lo][g * 4 + 16]) = w1;

    short8 bp = *reinterpret_cast<const short8*>(&Ps[wave][lo][g * 8]);
#pragma unroll
    for (int dt = 0; dt < 6; ++dt) {
      short8 av = *reinterpret_cast<const short8*>(&Vt[dt * 16 + lo][g * 8]);
      o[dt] = __builtin_amdgcn_mfma_f32_16x16x32_bf16(av, bp, o[dt], 0, 0, 0);
    }
    __syncthreads();
  }

  float inv = 1.f / l;
  size_t orow = ((size_t)(b * S + bq0 + wave * 16 + lo)) * C + h * HD;
#pragma unroll
  for (int dt = 0; dt < 6; ++dt)
#pragma unroll
    for (int r = 0; r < 4; ++r)
      o_out[orow + dt * 16 + g * 4 + r] = o[dt][r] * inv;
}

// ---------------- final scatter: out[b,c,s] ----------------
__global__ __launch_bounds__(256) void final_kernel(const float* __restrict__ x0,
                                                    const float* __restrict__ x1,
                                                    const int* __restrict__ sel,
                                                    const float* __restrict__ f_ir,
                                                    const float* __restrict__ f_vis,
                                                    float* __restrict__ out) {
  int i = blockIdx.x * 256 + threadIdx.x;  // over B*C*S = 3145728
  int s = i & (S - 1);
  int bc = i >> 10;
  int c = bc % C, b = bc / C;
  float v;
  if (sel[b * S + s]) {
    size_t r = ((size_t)(b * S + s)) * C + c;
    v = x0[r] + x1[r];
  } else {
    v = f_ir[i] + f_vis[i];
  }
  out[i] = v;
}

}  // namespace

extern "C" void kernel_launch(void* const* d_in, const int* in_sizes, int n_in,
                              void* d_out, int out_size, void* d_ws, size_t ws_size,
                              hipStream_t stream) {
  const float* f_ir = (const float*)d_in[0];
  const float* f_vis = (const float*)d_in[1];
  const float* agent_w1 = (const float*)d_in[2];
  const float* agent_b1 = (const float*)d_in[3];
  const float* agent_w2 = (const float*)d_in[4];
  const float* agent_b2 = (const float*)d_in[5];
  const float* norm_g = (const float*)d_in[6];
  const float* norm_b = (const float*)d_in[7];
  const float* in_w = (const float*)d_in[8];
  const float* in_b = (const float*)d_in[9];
  const float* out_w = (const float*)d_in[10];
  const float* out_b = (const float*)d_in[11];
  const float* ffn_w1 = (const float*)d_in[12];
  const float* ffn_b1 = (const float*)d_in[13];
  const float* ffn_w2 = (const float*)d_in[14];
  const float* ffn_b2 = (const float*)d_in[15];
  float* out = (float*)d_out;

  constexpr size_t MS = (size_t)M * C;  // 3145728 floats
  float* ws = (float*)d_ws;
  float* x0 = ws;                    // stream-0 state (starts as flat_ir)
  float* x1 = ws + MS;               // stream-1 state (starts as flat_vis)
  float* Dbuf = ws + 2 * MS;         // xn / attn_o   [M, C]
  float* Ebuf = ws + 3 * MS;         // hidden / qkv / ffn_h  [M, 1536] max
  int* sel = (int*)(ws + 3 * MS + (size_t)M * FFN);

  // 1) transposes
  transpose_cs<<<dim3(S / 32, C / 32, B), dim3(32, 8), 0, stream>>>(f_ir, x0);
  transpose_cs<<<dim3(S / 32, C / 32, B), dim3(32, 8), 0, stream>>>(f_vis, x1);

  // 2) agent hidden = SiLU(w1 @ [ir;vis] + b1), split over the two halves of K
  gemm_nt<0, false><<<dim3(HID / 64, M / 64), 256, 0, stream>>>(
      x0, C, agent_w1, 2 * C, nullptr, nullptr, Ebuf, HID, C);
  gemm_nt<1, true><<<dim3(HID / 64, M / 64), 256, 0, stream>>>(
      x1, C, agent_w1 + C, 2 * C, agent_b1, nullptr, Ebuf, HID, C);

  // 3) selection mask
  sel_kernel<<<M, 64, 0, stream>>>(Ebuf, agent_w2, agent_b2, sel);

  // 4) two mixer streams
  for (int t = 0; t < 2; ++t) {
    float* x = t ? x1 : x0;
    const float* g = norm_g + t * C;
    const float* bt = norm_b + t * C;
    // LN1
    ln_kernel<<<M, 64, 0, stream>>>(x, g, bt, Dbuf);
    // QKV
    gemm_nt<0, false><<<dim3(C3 / 64, M / 64), 256, 0, stream>>>(
        Dbuf, C, in_w + (size_t)t * C3 * C, C, in_b + t * C3, nullptr, Ebuf, C3, C);
    // attention (flash, MFMA bf16)
    attn_mfma<<<dim3(S / 64, B * HEADS), 256, 0, stream>>>(Ebuf, sel, Dbuf);
    // out proj + residual
    gemm_nt<0, false><<<dim3(C / 64, M / 64), 256, 0, stream>>>(
        Dbuf, C, out_w + (size_t)t * C * C, C, out_b + t * C, x, x, C, C);
    // LN2
    ln_kernel<<<M, 64, 0, stream>>>(x, g, bt, Dbuf);
    // FFN1 (GELU)
    gemm_nt<2, false><<<dim3(FFN / 64, M / 64), 256, 0, stream>>>(
        Dbuf, C, ffn_w1 + (size_t)t * FFN * C, C, ffn_b1 + t * FFN, nullptr, Ebuf, FFN, C);
    // FFN2 + residual
    gemm_nt<0, false><<<dim3(C / 64, M / 64), 256, 0, stream>>>(
        Ebuf, FFN, ffn_w2 + (size_t)t * C * FFN, FFN, ffn_b2 + t * C, x, x, C, FFN);
  }

  // 5) final scatter back to [B,C,H,W]
  final_kernel<<<(B * C * S) / 256, 256, 0, stream>>>(x0, x1, sel, f_ir, f_vis, out);
}

// Round 7
// 544.711 us; speedup vs baseline: 10.8531x; 3.2227x over previous
//
#include <hip/hip_runtime.h>
#include <math.h>

namespace {

constexpr int B = 8, C = 384, S = 1024;
constexpr int HID = 512, HEADS = 4, HD = 96, FFN = 1536;
constexpr int M = B * S;          // 8192 rows
constexpr int C3 = 3 * C;         // 1152

using u16 = unsigned short;
using short8 = __attribute__((ext_vector_type(8))) short;
using short4 = __attribute__((ext_vector_type(4))) short;
using f32x4 = __attribute__((ext_vector_type(4))) float;
using u16x4 = __attribute__((ext_vector_type(4))) unsigned short;

__device__ inline u16 f2bf(float f) {
  unsigned int u = __builtin_bit_cast(unsigned int, f);
  u += 0x7fffu + ((u >> 16) & 1u);
  return (u16)(u >> 16);
}

// ---------------- fp32 -> bf16 bulk convert (weights) ----------------
__global__ __launch_bounds__(256) void cvt_bf16(const float* __restrict__ in,
                                                u16* __restrict__ out, int n4) {
  int i = blockIdx.x * 256 + threadIdx.x;
  if (i >= n4) return;
  f32x4 v = reinterpret_cast<const f32x4*>(in)[i];
  u16x4 o;
#pragma unroll
  for (int j = 0; j < 4; ++j) o[j] = f2bf(v[j]);
  reinterpret_cast<u16x4*>(out)[i] = o;
}

// ---------------- transpose [C,S] -> [S,C] per batch ----------------
__global__ __launch_bounds__(256) void transpose_cs(const float* __restrict__ in,
                                                    float* __restrict__ out) {
  __shared__ float tile[32][33];
  int b = blockIdx.z;
  int s0 = blockIdx.x * 32, c0 = blockIdx.y * 32;
  const float* ip = in + (size_t)b * C * S;
  float* op = out + (size_t)b * S * C;
  int tx = threadIdx.x, ty = threadIdx.y;   // 32 x 8
#pragma unroll
  for (int i = 0; i < 32; i += 8)
    tile[ty + i][tx] = ip[(size_t)(c0 + ty + i) * S + s0 + tx];
  __syncthreads();
#pragma unroll
  for (int i = 0; i < 32; i += 8)
    op[(size_t)(s0 + ty + i) * C + c0 + tx] = tile[tx][ty + i];
}

// ---------------- fp32 NT GEMM (agent only): Cmat[M,N] = A[M,K] * W[N,K]^T ----
template <int EPI, bool ACC>
__global__ __launch_bounds__(256) void gemm_nt(const float* __restrict__ A, int lda,
                                               const float* __restrict__ Wt, int ldw,
                                               const float* __restrict__ bias,
                                               float* __restrict__ Cmat, int ldc,
                                               int Kdim) {
  constexpr int BK = 16;
  __shared__ float As[64][BK + 1];
  __shared__ float Ws[64][BK + 1];
  int tid = threadIdx.x;
  int bn = blockIdx.x * 64, bm = blockIdx.y * 64;
  int tx = tid & 15, ty = tid >> 4;
  float acc[4][4] = {};
  for (int k0 = 0; k0 < Kdim; k0 += BK) {
#pragma unroll
    for (int i = 0; i < 4; ++i) {
      int idx = tid + i * 256;
      int r = idx >> 4, kk = idx & 15;
      As[r][kk] = A[(size_t)(bm + r) * lda + k0 + kk];
      Ws[r][kk] = Wt[(size_t)(bn + r) * ldw + k0 + kk];
    }
    __syncthreads();
#pragma unroll
    for (int kk = 0; kk < BK; ++kk) {
      float a[4], w[4];
#pragma unroll
      for (int i = 0; i < 4; ++i) a[i] = As[ty * 4 + i][kk];
#pragma unroll
      for (int j = 0; j < 4; ++j) w[j] = Ws[tx * 4 + j][kk];
#pragma unroll
      for (int i = 0; i < 4; ++i)
#pragma unroll
        for (int j = 0; j < 4; ++j) acc[i][j] = fmaf(a[i], w[j], acc[i][j]);
    }
    __syncthreads();
  }
#pragma unroll
  for (int i = 0; i < 4; ++i) {
    int m = bm + ty * 4 + i;
#pragma unroll
    for (int j = 0; j < 4; ++j) {
      int n = bn + tx * 4 + j;
      float v = acc[i][j];
      if (ACC) v += Cmat[(size_t)m * ldc + n];
      if (bias) v += bias[n];
      if (EPI == 1) v = v / (1.f + expf(-v));   // SiLU
      Cmat[(size_t)m * ldc + n] = v;
    }
  }
}

// ---------------- bf16 MFMA GEMM: out[M,N] = A[M,K](bf16) * W[N,K]^T(bf16) ----
// 128x128 tile, BK=64, 4 waves 2x2 (64x64 each). LDS staged via global_load_lds
// width=16 with XOR swizzle (slot ^= row&7) applied on the GLOBAL source and on
// the ds_read address (rule: both-sides-or-neither); LDS dest stays linear.
// MODE 0: +bias -> bf16 out. MODE 1: +bias, GELU -> bf16 out.
// MODE 2: +bias + xres(fp32) -> xres (residual update).
__device__ inline void stage_tile(const u16* __restrict__ g, int ldk,
                                  u16* lds, int tid) {
  int w = tid >> 6, l = tid & 63;
#pragma unroll
  for (int i = 0; i < 4; ++i) {
    int lin = i * 4096 + w * 1024 + l * 16;   // byte within 16KB tile
    int row = lin >> 7;                        // 128B per row (64 bf16)
    int slot = (lin >> 4) & 7;
    int k = (slot ^ (row & 7)) * 8;            // inverse-swizzled source
    const u16* gp = g + (size_t)row * ldk + k;
    u16* lp = lds + i * 2048 + w * 512;        // wave-uniform dest (elements)
    __builtin_amdgcn_global_load_lds(
        (const __attribute__((address_space(1))) unsigned int*)gp,
        (__attribute__((address_space(3))) unsigned int*)lp, 16, 0, 0);
  }
}

__device__ inline short8 frag_ld(const u16* lds, int row, int slot) {
  int s = slot ^ (row & 7);
  return *reinterpret_cast<const short8*>(lds + row * 64 + s * 8);
}

template <int MODE>
__global__ __launch_bounds__(256) void gemm_bf16(const u16* __restrict__ A,
                                                 const u16* __restrict__ W,
                                                 const float* __restrict__ bias,
                                                 float* __restrict__ xres,
                                                 u16* __restrict__ obf,
                                                 int N, int K) {
  __shared__ u16 Asb[128 * 64];
  __shared__ u16 Wsb[128 * 64];
  int tid = threadIdx.x;
  int wave = tid >> 6, lane = tid & 63, lo = lane & 15, hi = lane >> 4;
  int wr = wave >> 1, wc = wave & 1;
  int bn = blockIdx.x * 128, bm = blockIdx.y * 128;
  const u16* Ag = A + (size_t)bm * K;
  const u16* Wg = W + (size_t)bn * K;
  f32x4 acc[4][4] = {};
  for (int k0 = 0; k0 < K; k0 += 64) {
    stage_tile(Ag + k0, K, Asb, tid);
    stage_tile(Wg + k0, K, Wsb, tid);
    __syncthreads();   // compiler drains vmcnt before s_barrier
#pragma unroll
    for (int ks = 0; ks < 2; ++ks) {
      short8 a[4], b[4];
#pragma unroll
      for (int mi = 0; mi < 4; ++mi) a[mi] = frag_ld(Asb, wr * 64 + mi * 16 + lo, ks * 4 + hi);
#pragma unroll
      for (int nj = 0; nj < 4; ++nj) b[nj] = frag_ld(Wsb, wc * 64 + nj * 16 + lo, ks * 4 + hi);
#pragma unroll
      for (int mi = 0; mi < 4; ++mi)
#pragma unroll
        for (int nj = 0; nj < 4; ++nj)
          acc[mi][nj] = __builtin_amdgcn_mfma_f32_16x16x32_bf16(a[mi], b[nj], acc[mi][nj], 0, 0, 0);
    }
    __syncthreads();
  }
  // epilogue: D row=(lane>>4)*4+reg -> m, col=lane&15 -> n
  float bv[4];
#pragma unroll
  for (int nj = 0; nj < 4; ++nj) bv[nj] = bias[bn + wc * 64 + nj * 16 + lo];
#pragma unroll
  for (int mi = 0; mi < 4; ++mi) {
#pragma unroll
    for (int r = 0; r < 4; ++r) {
      int m = bm + wr * 64 + mi * 16 + hi * 4 + r;
#pragma unroll
      for (int nj = 0; nj < 4; ++nj) {
        int n = bn + wc * 64 + nj * 16 + lo;
        float v = acc[mi][nj][r] + bv[nj];
        size_t idx = (size_t)m * N + n;
        if (MODE == 0) {
          obf[idx] = f2bf(v);
        } else if (MODE == 1) {
          v = 0.5f * v * (1.f + erff(v * 0.70710678f));
          obf[idx] = f2bf(v);
        } else {
          xres[idx] += v;
        }
      }
    }
  }
}

// ---------------- agent logit + threshold ----------------
__global__ __launch_bounds__(64) void sel_kernel(const float* __restrict__ hidden,
                                                 const float* __restrict__ w2,
                                                 const float* __restrict__ b2,
                                                 int* __restrict__ sel) {
  int row = blockIdx.x, t = threadIdx.x;
  const float* hr = hidden + (size_t)row * HID;
  float s = 0.f;
#pragma unroll
  for (int i = 0; i < HID / 64; ++i) s += hr[t + i * 64] * w2[t + i * 64];
  for (int off = 32; off; off >>= 1) s += __shfl_down(s, off);
  if (t == 0) sel[row] = (s + b2[0]) > 0.f ? 1 : 0;
}

// ---------------- LayerNorm over C=384 -> bf16, one wave per row ----------------
__global__ __launch_bounds__(64) void ln_kernel(const float* __restrict__ x,
                                                const float* __restrict__ g,
                                                const float* __restrict__ bt,
                                                u16* __restrict__ y) {
  int row = blockIdx.x, t = threadIdx.x;
  const float* xr = x + (size_t)row * C;
  float v[C / 64];
  float s = 0.f, s2 = 0.f;
#pragma unroll
  for (int i = 0; i < C / 64; ++i) {
    float a = xr[t + i * 64];
    v[i] = a;
    s += a;
    s2 += a * a;
  }
  for (int off = 32; off; off >>= 1) {
    s += __shfl_down(s, off);
    s2 += __shfl_down(s2, off);
  }
  s = __shfl(s, 0);
  s2 = __shfl(s2, 0);
  float mean = s / C;
  float var = s2 / C - mean * mean;
  float inv = rsqrtf(var + 1e-5f);
#pragma unroll
  for (int i = 0; i < C / 64; ++i) {
    int c = t + i * 64;
    y[(size_t)row * C + c] = f2bf((v[i] - mean) * inv * g[c] + bt[c]);
  }
}

// ---------------- block reduction helper not needed; attn below ----------------
// flash MFMA attention: qkv is bf16. One block per (b,h,64q); 4 waves x 16 q.
__global__ __launch_bounds__(256) void attn_mfma(const u16* __restrict__ qkv,
                                                 const int* __restrict__ sel,
                                                 u16* __restrict__ o_out) {
  __shared__ u16 Qs[64][104];
  __shared__ u16 Ks[32][104];
  __shared__ u16 Vt[96][40];
  __shared__ u16 Ps[4][16][40];
  __shared__ float msk[S];

  int bq0 = blockIdx.x * 64;
  int bh = blockIdx.y;
  int b = bh >> 2, h = bh & 3;
  int tid = threadIdx.x;
  int wave = tid >> 6, lane = tid & 63;
  int lo = lane & 15, g = lane >> 4;

  const u16* qbase = qkv + ((size_t)(b * S + bq0)) * C3 + h * HD;
#pragma unroll
  for (int i = 0; i < 24; ++i) {
    int idx = i * 256 + tid;
    int r = idx / 96, d = idx - r * 96;
    Qs[r][d] = qbase[(size_t)r * C3 + d];
  }
  const int* selb = sel + b * S;
#pragma unroll
  for (int i = 0; i < 4; ++i) {
    int k = i * 256 + tid;
    msk[k] = selb[k] ? 0.f : -1e9f;
  }
  __syncthreads();

  const float scale = 0.1020620726f;  // 1/sqrt(96)
  float m = -INFINITY, l = 0.f;
  f32x4 o[6] = {};

  for (int kt0 = 0; kt0 < S; kt0 += 32) {
    const u16* kbase = qkv + ((size_t)(b * S + kt0)) * C3 + C + h * HD;
    const u16* vbase = qkv + ((size_t)(b * S + kt0)) * C3 + 2 * C + h * HD;
#pragma unroll
    for (int i = 0; i < 12; ++i) {
      int idx = i * 256 + tid;
      int r = idx / 96, d = idx - r * 96;
      Ks[r][d] = kbase[(size_t)r * C3 + d];
      Vt[d][r] = vbase[(size_t)r * C3 + d];
    }
    __syncthreads();

    f32x4 st0 = {}, st1 = {};
#pragma unroll
    for (int c = 0; c < 3; ++c) {
      short8 bq = *reinterpret_cast<const short8*>(&Qs[wave * 16 + lo][c * 32 + g * 8]);
      short8 ak0 = *reinterpret_cast<const short8*>(&Ks[lo][c * 32 + g * 8]);
      short8 ak1 = *reinterpret_cast<const short8*>(&Ks[lo + 16][c * 32 + g * 8]);
      st0 = __builtin_amdgcn_mfma_f32_16x16x32_bf16(ak0, bq, st0, 0, 0, 0);
      st1 = __builtin_amdgcn_mfma_f32_16x16x32_bf16(ak1, bq, st1, 0, 0, 0);
    }

    float s0[4], s1[4];
    float pmax = -INFINITY;
#pragma unroll
    for (int r = 0; r < 4; ++r) {
      s0[r] = st0[r] * scale + msk[kt0 + g * 4 + r];
      s1[r] = st1[r] * scale + msk[kt0 + 16 + g * 4 + r];
      pmax = fmaxf(pmax, fmaxf(s0[r], s1[r]));
    }
    pmax = fmaxf(pmax, __shfl_xor(pmax, 16));
    pmax = fmaxf(pmax, __shfl_xor(pmax, 32));
    float mn = fmaxf(m, pmax);
    float sc = __expf(m - mn);
    m = mn;
    float p0[4], p1[4], ps = 0.f;
#pragma unroll
    for (int r = 0; r < 4; ++r) {
      p0[r] = __expf(s0[r] - mn);
      p1[r] = __expf(s1[r] - mn);
      ps += p0[r] + p1[r];
    }
    ps += __shfl_xor(ps, 16);
    ps += __shfl_xor(ps, 32);
    l = l * sc + ps;
#pragma unroll
    for (int dt = 0; dt < 6; ++dt)
#pragma unroll
      for (int r = 0; r < 4; ++r) o[dt][r] *= sc;

    short4 w0, w1;
#pragma unroll
    for (int r = 0; r < 4; ++r) {
      w0[r] = (short)f2bf(p0[r]);
      w1[r] = (short)f2bf(p1[r]);
    }
    *reinterpret_cast<short4*>(&Ps[wave][lo][g * 4]) = w0;
    *reinterpret_cast<short4*>(&Ps[wave][lo][g * 4 + 16]) = w1;

    short8 bp = *reinterpret_cast<const short8*>(&Ps[wave][lo][g * 8]);
#pragma unroll
    for (int dt = 0; dt < 6; ++dt) {
      short8 av = *reinterpret_cast<const short8*>(&Vt[dt * 16 + lo][g * 8]);
      o[dt] = __builtin_amdgcn_mfma_f32_16x16x32_bf16(av, bp, o[dt], 0, 0, 0);
    }
    __syncthreads();
  }

  float inv = 1.f / l;
  size_t orow = ((size_t)(b * S + bq0 + wave * 16 + lo)) * C + h * HD;
#pragma unroll
  for (int dt = 0; dt < 6; ++dt)
#pragma unroll
    for (int r = 0; r < 4; ++r)
      o_out[orow + dt * 16 + g * 4 + r] = f2bf(o[dt][r] * inv);
}

// ---------------- final scatter: out[b,c,s] ----------------
__global__ __launch_bounds__(256) void final_kernel(const float* __restrict__ x0,
                                                    const float* __restrict__ x1,
                                                    const int* __restrict__ sel,
                                                    const float* __restrict__ f_ir,
                                                    const float* __restrict__ f_vis,
                                                    float* __restrict__ out) {
  int i = blockIdx.x * 256 + threadIdx.x;
  int s = i & (S - 1);
  int bc = i >> 10;
  int c = bc % C, b = bc / C;
  float v;
  if (sel[b * S + s]) {
    size_t r = ((size_t)(b * S + s)) * C + c;
    v = x0[r] + x1[r];
  } else {
    v = f_ir[i] + f_vis[i];
  }
  out[i] = v;
}

}  // namespace

extern "C" void kernel_launch(void* const* d_in, const int* in_sizes, int n_in,
                              void* d_out, int out_size, void* d_ws, size_t ws_size,
                              hipStream_t stream) {
  const float* f_ir = (const float*)d_in[0];
  const float* f_vis = (const float*)d_in[1];
  const float* agent_w1 = (const float*)d_in[2];
  const float* agent_b1 = (const float*)d_in[3];
  const float* agent_w2 = (const float*)d_in[4];
  const float* agent_b2 = (const float*)d_in[5];
  const float* norm_g = (const float*)d_in[6];
  const float* norm_b = (const float*)d_in[7];
  const float* in_w = (const float*)d_in[8];
  const float* in_b = (const float*)d_in[9];
  const float* out_w = (const float*)d_in[10];
  const float* out_b = (const float*)d_in[11];
  const float* ffn_w1 = (const float*)d_in[12];
  const float* ffn_b1 = (const float*)d_in[13];
  const float* ffn_w2 = (const float*)d_in[14];
  const float* ffn_b2 = (const float*)d_in[15];
  float* out = (float*)d_out;

  constexpr size_t MS = (size_t)M * C;
  float* ws = (float*)d_ws;
  float* x0 = ws;                                  // fp32 residual stream 0
  float* x1 = x0 + MS;                             // fp32 residual stream 1
  u16* Dbf = (u16*)(x1 + MS);                      // [M,C]  xn / attn_o (bf16)
  u16* qkvb = Dbf + MS;                            // [M,C3] qkv (bf16)
  u16* Hbf = qkvb + (size_t)M * C3;                // [M,FFN] ffn hidden (bf16)
  float* hiddenF = (float*)Hbf;                    // [M,HID] agent hidden (fp32, aliased)
  u16* wb_in = Hbf + (size_t)M * FFN;              // 2*C3*C
  u16* wb_out = wb_in + 2 * C3 * C;                // 2*C*C
  u16* wb_f1 = wb_out + 2 * C * C;                 // 2*FFN*C
  u16* wb_f2 = wb_f1 + 2 * FFN * C;                // 2*C*FFN
  int* sel = (int*)(wb_f2 + 2 * C * FFN);

  // 0) weights -> bf16
  auto cvt = [&](const float* src, u16* dst, int n) {
    int n4 = n / 4;
    cvt_bf16<<<(n4 + 255) / 256, 256, 0, stream>>>(src, dst, n4);
  };
  cvt(in_w, wb_in, 2 * C3 * C);
  cvt(out_w, wb_out, 2 * C * C);
  cvt(ffn_w1, wb_f1, 2 * FFN * C);
  cvt(ffn_w2, wb_f2, 2 * C * FFN);

  // 1) transposes
  transpose_cs<<<dim3(S / 32, C / 32, B), dim3(32, 8), 0, stream>>>(f_ir, x0);
  transpose_cs<<<dim3(S / 32, C / 32, B), dim3(32, 8), 0, stream>>>(f_vis, x1);

  // 2) agent hidden = SiLU(w1 @ [ir;vis] + b1) — fp32 (sel sign must be exact)
  gemm_nt<0, false><<<dim3(HID / 64, M / 64), 256, 0, stream>>>(
      x0, C, agent_w1, 2 * C, nullptr, hiddenF, HID, C);
  gemm_nt<1, true><<<dim3(HID / 64, M / 64), 256, 0, stream>>>(
      x1, C, agent_w1 + C, 2 * C, agent_b1, hiddenF, HID, C);

  // 3) selection mask
  sel_kernel<<<M, 64, 0, stream>>>(hiddenF, agent_w2, agent_b2, sel);

  // 4) two mixer streams (bf16 MFMA GEMMs)
  for (int t = 0; t < 2; ++t) {
    float* x = t ? x1 : x0;
    const float* g = norm_g + t * C;
    const float* bt = norm_b + t * C;
    ln_kernel<<<M, 64, 0, stream>>>(x, g, bt, Dbf);
    gemm_bf16<0><<<dim3(C3 / 128, M / 128), 256, 0, stream>>>(
        Dbf, wb_in + (size_t)t * C3 * C, in_b + t * C3, nullptr, qkvb, C3, C);
    attn_mfma<<<dim3(S / 64, B * HEADS), 256, 0, stream>>>(qkvb, sel, Dbf);
    gemm_bf16<2><<<dim3(C / 128, M / 128), 256, 0, stream>>>(
        Dbf, wb_out + (size_t)t * C * C, out_b + t * C, x, nullptr, C, C);
    ln_kernel<<<M, 64, 0, stream>>>(x, g, bt, Dbf);
    gemm_bf16<1><<<dim3(FFN / 128, M / 128), 256, 0, stream>>>(
        Dbf, wb_f1 + (size_t)t * FFN * C, ffn_b1 + t * FFN, nullptr, Hbf, FFN, C);
    gemm_bf16<2><<<dim3(C / 128, M / 128), 256, 0, stream>>>(
        Hbf, wb_f2 + (size_t)t * C * FFN, ffn_b2 + t * C, x, nullptr, C, FFN);
  }

  // 5) final scatter back to [B,C,H,W]
  final_kernel<<<(B * C * S) / 256, 256, 0, stream>>>(x0, x1, sel, f_ir, f_vis, out);
}

// Round 8
// 518.120 us; speedup vs baseline: 11.4101x; 1.0513x over previous
//
#include <hip/hip_runtime.h>
#include <math.h>

namespace {

constexpr int B = 8, C = 384, S = 1024;
constexpr int HID = 512, HEADS = 4, HD = 96, FFN = 1536;
constexpr int M = B * S;          // 8192 rows
constexpr int C3 = 3 * C;         // 1152
constexpr int K2C = 2 * C;        // 768 (agent K)
constexpr int FIXCAP = 4096;

using u16 = unsigned short;
using short8 = __attribute__((ext_vector_type(8))) short;
using short4 = __attribute__((ext_vector_type(4))) short;
using f32x4 = __attribute__((ext_vector_type(4))) float;
using u16x4 = __attribute__((ext_vector_type(4))) unsigned short;

__device__ inline u16 f2bf(float f) {
  unsigned int u = __builtin_bit_cast(unsigned int, f);
  u += 0x7fffu + ((u >> 16) & 1u);
  return (u16)(u >> 16);
}
__device__ inline float bf2f(u16 h) {
  unsigned int u = ((unsigned int)h) << 16;
  return __builtin_bit_cast(float, u);
}

// ---------------- fp32 -> bf16 bulk convert (weights) ----------------
__global__ __launch_bounds__(256) void cvt_bf16(const float* __restrict__ in,
                                                u16* __restrict__ out, int n4) {
  int i = blockIdx.x * 256 + threadIdx.x;
  if (i >= n4) return;
  f32x4 v = reinterpret_cast<const f32x4*>(in)[i];
  u16x4 o;
#pragma unroll
  for (int j = 0; j < 4; ++j) o[j] = f2bf(v[j]);
  reinterpret_cast<u16x4*>(out)[i] = o;
}

// ---------------- fp32 -> bf16 hi/lo split (w1) ----------------
__global__ __launch_bounds__(256) void cvt_hilo(const float* __restrict__ in,
                                                u16* __restrict__ hi,
                                                u16* __restrict__ lo, int n4) {
  int i = blockIdx.x * 256 + threadIdx.x;
  if (i >= n4) return;
  f32x4 v = reinterpret_cast<const f32x4*>(in)[i];
  u16x4 oh, ol;
#pragma unroll
  for (int j = 0; j < 4; ++j) {
    u16 h = f2bf(v[j]);
    oh[j] = h;
    ol[j] = f2bf(v[j] - bf2f(h));
  }
  reinterpret_cast<u16x4*>(hi)[i] = oh;
  reinterpret_cast<u16x4*>(lo)[i] = ol;
}

// ---------------- activations -> interleaved [x0;x1] hi/lo bf16 ----------------
// Ahi/Alo are [M, 768]: cols 0..383 from x0, 384..767 from x1.
__global__ __launch_bounds__(256) void act_hilo(const float* __restrict__ x0,
                                                const float* __restrict__ x1,
                                                u16* __restrict__ Ahi,
                                                u16* __restrict__ Alo) {
  int j = blockIdx.x * 256 + threadIdx.x;  // vec4 index over M*C/4
  if (j >= M * C / 4) return;
  int m = j / (C / 4), c4 = j - m * (C / 4);
  f32x4 v0 = reinterpret_cast<const f32x4*>(x0)[j];
  f32x4 v1 = reinterpret_cast<const f32x4*>(x1)[j];
  u16x4 h0, l0, h1, l1;
#pragma unroll
  for (int t = 0; t < 4; ++t) {
    u16 h = f2bf(v0[t]); h0[t] = h; l0[t] = f2bf(v0[t] - bf2f(h));
    h = f2bf(v1[t]); h1[t] = h; l1[t] = f2bf(v1[t] - bf2f(h));
  }
  size_t base = (size_t)m * K2C;
  *reinterpret_cast<u16x4*>(Ahi + base + c4 * 4) = h0;
  *reinterpret_cast<u16x4*>(Alo + base + c4 * 4) = l0;
  *reinterpret_cast<u16x4*>(Ahi + base + C + c4 * 4) = h1;
  *reinterpret_cast<u16x4*>(Alo + base + C + c4 * 4) = l1;
}

// ---------------- transpose [C,S] -> [S,C] per batch ----------------
__global__ __launch_bounds__(256) void transpose_cs(const float* __restrict__ in,
                                                    float* __restrict__ out) {
  __shared__ float tile[32][33];
  int b = blockIdx.z;
  int s0 = blockIdx.x * 32, c0 = blockIdx.y * 32;
  const float* ip = in + (size_t)b * C * S;
  float* op = out + (size_t)b * S * C;
  int tx = threadIdx.x, ty = threadIdx.y;   // 32 x 8
#pragma unroll
  for (int i = 0; i < 32; i += 8)
    tile[ty + i][tx] = ip[(size_t)(c0 + ty + i) * S + s0 + tx];
  __syncthreads();
#pragma unroll
  for (int i = 0; i < 32; i += 8)
    op[(size_t)(s0 + ty + i) * C + c0 + tx] = tile[tx][ty + i];
}

// ---------------- bf16 MFMA GEMM: out[M,N] = A[M,K](bf16) * W[N,K]^T(bf16) ----
// 128x128 tile, BK=64, 4 waves 2x2 (64x64 each). LDS staged via global_load_lds
// width=16 with XOR swizzle (slot ^= row&7) on the GLOBAL source and on the
// ds_read address; LDS dest stays linear (both-sides-or-neither rule).
// MODE 0: +bias -> bf16 out. MODE 1: +bias, GELU -> bf16 out.
// MODE 2: +bias + xres(fp32) -> xres (residual update).
// MODE 3: raw  -> fp32 store.   MODE 4: fp32 +=.   MODE 5: fp32 +=, +bias, SiLU.
__device__ inline void stage_tile(const u16* __restrict__ g, int ldk,
                                  u16* lds, int tid) {
  int w = tid >> 6, l = tid & 63;
#pragma unroll
  for (int i = 0; i < 4; ++i) {
    int lin = i * 4096 + w * 1024 + l * 16;   // byte within 16KB tile
    int row = lin >> 7;                        // 128B per row (64 bf16)
    int slot = (lin >> 4) & 7;
    int k = (slot ^ (row & 7)) * 8;            // inverse-swizzled source
    const u16* gp = g + (size_t)row * ldk + k;
    u16* lp = lds + i * 2048 + w * 512;        // wave-uniform dest (elements)
    __builtin_amdgcn_global_load_lds(
        (const __attribute__((address_space(1))) unsigned int*)gp,
        (__attribute__((address_space(3))) unsigned int*)lp, 16, 0, 0);
  }
}

__device__ inline short8 frag_ld(const u16* lds, int row, int slot) {
  int s = slot ^ (row & 7);
  return *reinterpret_cast<const short8*>(lds + row * 64 + s * 8);
}

template <int MODE>
__global__ __launch_bounds__(256) void gemm_bf16(const u16* __restrict__ A,
                                                 const u16* __restrict__ W,
                                                 const float* __restrict__ bias,
                                                 float* __restrict__ xres,
                                                 u16* __restrict__ obf,
                                                 int N, int K) {
  __shared__ u16 Asb[128 * 64];
  __shared__ u16 Wsb[128 * 64];
  int tid = threadIdx.x;
  int wave = tid >> 6, lane = tid & 63, lo = lane & 15, hi = lane >> 4;
  int wr = wave >> 1, wc = wave & 1;
  int bn = blockIdx.x * 128, bm = blockIdx.y * 128;
  const u16* Ag = A + (size_t)bm * K;
  const u16* Wg = W + (size_t)bn * K;
  f32x4 acc[4][4] = {};
  for (int k0 = 0; k0 < K; k0 += 64) {
    stage_tile(Ag + k0, K, Asb, tid);
    stage_tile(Wg + k0, K, Wsb, tid);
    __syncthreads();   // compiler drains vmcnt before s_barrier
#pragma unroll
    for (int ks = 0; ks < 2; ++ks) {
      short8 a[4], b[4];
#pragma unroll
      for (int mi = 0; mi < 4; ++mi) a[mi] = frag_ld(Asb, wr * 64 + mi * 16 + lo, ks * 4 + hi);
#pragma unroll
      for (int nj = 0; nj < 4; ++nj) b[nj] = frag_ld(Wsb, wc * 64 + nj * 16 + lo, ks * 4 + hi);
#pragma unroll
      for (int mi = 0; mi < 4; ++mi)
#pragma unroll
        for (int nj = 0; nj < 4; ++nj)
          acc[mi][nj] = __builtin_amdgcn_mfma_f32_16x16x32_bf16(a[mi], b[nj], acc[mi][nj], 0, 0, 0);
    }
    __syncthreads();
  }
  // epilogue: D row=(lane>>4)*4+reg -> m, col=lane&15 -> n
  float bv[4];
#pragma unroll
  for (int nj = 0; nj < 4; ++nj)
    bv[nj] = (MODE == 0 || MODE == 1 || MODE == 2 || MODE == 5)
                 ? bias[bn + wc * 64 + nj * 16 + lo] : 0.f;
#pragma unroll
  for (int mi = 0; mi < 4; ++mi) {
#pragma unroll
    for (int r = 0; r < 4; ++r) {
      int m = bm + wr * 64 + mi * 16 + hi * 4 + r;
#pragma unroll
      for (int nj = 0; nj < 4; ++nj) {
        int n = bn + wc * 64 + nj * 16 + lo;
        float v = acc[mi][nj][r];
        size_t idx = (size_t)m * N + n;
        if (MODE == 0) {
          obf[idx] = f2bf(v + bv[nj]);
        } else if (MODE == 1) {
          v += bv[nj];
          v = 0.5f * v * (1.f + erff(v * 0.70710678f));
          obf[idx] = f2bf(v);
        } else if (MODE == 2) {
          xres[idx] += v + bv[nj];
        } else if (MODE == 3) {
          xres[idx] = v;
        } else if (MODE == 4) {
          xres[idx] += v;
        } else {  // MODE 5
          float t = xres[idx] + v + bv[nj];
          xres[idx] = t / (1.f + expf(-t));   // SiLU, fp32 out
        }
      }
    }
  }
}

// ---------------- zero the fixup counter ----------------
__global__ void zero_ctr(int* ctr) { if (threadIdx.x == 0) ctr[0] = 0; }

// ---------------- agent logit + threshold + ambiguity list ----------------
__global__ __launch_bounds__(64) void sel_kernel(const float* __restrict__ hidden,
                                                 const float* __restrict__ w2,
                                                 const float* __restrict__ b2,
                                                 int* __restrict__ sel,
                                                 int* __restrict__ ctr,
                                                 int* __restrict__ list) {
  int row = blockIdx.x, t = threadIdx.x;
  const float* hr = hidden + (size_t)row * HID;
  float s = 0.f;
#pragma unroll
  for (int i = 0; i < HID / 64; ++i) s += hr[t + i * 64] * w2[t + i * 64];
  for (int off = 32; off; off >>= 1) s += __shfl_down(s, off);
  if (t == 0) {
    float logit = s + b2[0];
    sel[row] = logit > 0.f ? 1 : 0;
    if (fabsf(logit) < 1e-3f) {
      int idx = atomicAdd(ctr, 1);
      if (idx < FIXCAP) list[idx] = row;
    }
  }
}

// ---------------- exact fp32 recompute of ambiguous rows ----------------
__global__ __launch_bounds__(256) void fixup_kernel(const float* __restrict__ x0,
                                                    const float* __restrict__ x1,
                                                    const float* __restrict__ w1,
                                                    const float* __restrict__ b1,
                                                    const float* __restrict__ w2,
                                                    const float* __restrict__ b2,
                                                    const int* __restrict__ ctr,
                                                    const int* __restrict__ list,
                                                    int* __restrict__ sel) {
  __shared__ float xs[K2C];
  __shared__ float red[4];
  int cnt = ctr[0];
  if (cnt > FIXCAP) cnt = FIXCAP;
  int tid = threadIdx.x;
  for (int ii = blockIdx.x; ii < cnt; ii += gridDim.x) {
    int row = list[ii];
    // stage xcat row
    for (int k = tid; k < C; k += 256) {
      xs[k] = x0[(size_t)row * C + k];
      xs[C + k] = x1[(size_t)row * C + k];
    }
    __syncthreads();
    float partial = 0.f;
#pragma unroll
    for (int u = 0; u < 2; ++u) {
      int n = tid + u * 256;
      const float* wr = w1 + (size_t)n * K2C;
      float acc = 0.f;
      for (int k = 0; k < K2C; ++k) acc = fmaf(wr[k], xs[k], acc);
      acc += b1[n];
      acc = acc / (1.f + expf(-acc));  // SiLU
      partial = fmaf(acc, w2[n], partial);
    }
    for (int off = 32; off; off >>= 1) partial += __shfl_down(partial, off);
    if ((tid & 63) == 0) red[tid >> 6] = partial;
    __syncthreads();
    if (tid == 0) {
      float logit = red[0] + red[1] + red[2] + red[3] + b2[0];
      sel[row] = logit > 0.f ? 1 : 0;
    }
    __syncthreads();
  }
}

// ---------------- LayerNorm over C=384 -> bf16, one wave per row ----------------
__global__ __launch_bounds__(64) void ln_kernel(const float* __restrict__ x,
                                                const float* __restrict__ g,
                                                const float* __restrict__ bt,
                                                u16* __restrict__ y) {
  int row = blockIdx.x, t = threadIdx.x;
  const float* xr = x + (size_t)row * C;
  float v[C / 64];
  float s = 0.f, s2 = 0.f;
#pragma unroll
  for (int i = 0; i < C / 64; ++i) {
    float a = xr[t + i * 64];
    v[i] = a;
    s += a;
    s2 += a * a;
  }
  for (int off = 32; off; off >>= 1) {
    s += __shfl_down(s, off);
    s2 += __shfl_down(s2, off);
  }
  s = __shfl(s, 0);
  s2 = __shfl(s2, 0);
  float mean = s / C;
  float var = s2 / C - mean * mean;
  float inv = rsqrtf(var + 1e-5f);
#pragma unroll
  for (int i = 0; i < C / 64; ++i) {
    int c = t + i * 64;
    y[(size_t)row * C + c] = f2bf((v[i] - mean) * inv * g[c] + bt[c]);
  }
}

// ---------------- flash MFMA attention (bf16 qkv) ----------------
__global__ __launch_bounds__(256) void attn_mfma(const u16* __restrict__ qkv,
                                                 const int* __restrict__ sel,
                                                 u16* __restrict__ o_out) {
  __shared__ u16 Qs[64][104];
  __shared__ u16 Ks[32][104];
  __shared__ u16 Vt[96][40];
  __shared__ u16 Ps[4][16][40];
  __shared__ float msk[S];

  int bq0 = blockIdx.x * 64;
  int bh = blockIdx.y;
  int b = bh >> 2, h = bh & 3;
  int tid = threadIdx.x;
  int wave = tid >> 6, lane = tid & 63;
  int lo = lane & 15, g = lane >> 4;

  const u16* qbase = qkv + ((size_t)(b * S + bq0)) * C3 + h * HD;
#pragma unroll
  for (int i = 0; i < 24; ++i) {
    int idx = i * 256 + tid;
    int r = idx / 96, d = idx - r * 96;
    Qs[r][d] = qbase[(size_t)r * C3 + d];
  }
  const int* selb = sel + b * S;
#pragma unroll
  for (int i = 0; i < 4; ++i) {
    int k = i * 256 + tid;
    msk[k] = selb[k] ? 0.f : -1e9f;
  }
  __syncthreads();

  const float scale = 0.1020620726f;  // 1/sqrt(96)
  float m = -INFINITY, l = 0.f;
  f32x4 o[6] = {};

  for (int kt0 = 0; kt0 < S; kt0 += 32) {
    const u16* kbase = qkv + ((size_t)(b * S + kt0)) * C3 + C + h * HD;
    const u16* vbase = qkv + ((size_t)(b * S + kt0)) * C3 + 2 * C + h * HD;
#pragma unroll
    for (int i = 0; i < 12; ++i) {
      int idx = i * 256 + tid;
      int r = idx / 96, d = idx - r * 96;
      Ks[r][d] = kbase[(size_t)r * C3 + d];
      Vt[d][r] = vbase[(size_t)r * C3 + d];
    }
    __syncthreads();

    f32x4 st0 = {}, st1 = {};
#pragma unroll
    for (int c = 0; c < 3; ++c) {
      short8 bq = *reinterpret_cast<const short8*>(&Qs[wave * 16 + lo][c * 32 + g * 8]);
      short8 ak0 = *reinterpret_cast<const short8*>(&Ks[lo][c * 32 + g * 8]);
      short8 ak1 = *reinterpret_cast<const short8*>(&Ks[lo + 16][c * 32 + g * 8]);
      st0 = __builtin_amdgcn_mfma_f32_16x16x32_bf16(ak0, bq, st0, 0, 0, 0);
      st1 = __builtin_amdgcn_mfma_f32_16x16x32_bf16(ak1, bq, st1, 0, 0, 0);
    }

    float s0[4], s1[4];
    float pmax = -INFINITY;
#pragma unroll
    for (int r = 0; r < 4; ++r) {
      s0[r] = st0[r] * scale + msk[kt0 + g * 4 + r];
      s1[r] = st1[r] * scale + msk[kt0 + 16 + g * 4 + r];
      pmax = fmaxf(pmax, fmaxf(s0[r], s1[r]));
    }
    pmax = fmaxf(pmax, __shfl_xor(pmax, 16));
    pmax = fmaxf(pmax, __shfl_xor(pmax, 32));
    float mn = fmaxf(m, pmax);
    float sc = __expf(m - mn);
    m = mn;
    float p0[4], p1[4], ps = 0.f;
#pragma unroll
    for (int r = 0; r < 4; ++r) {
      p0[r] = __expf(s0[r] - mn);
      p1[r] = __expf(s1[r] - mn);
      ps += p0[r] + p1[r];
    }
    ps += __shfl_xor(ps, 16);
    ps += __shfl_xor(ps, 32);
    l = l * sc + ps;
#pragma unroll
    for (int dt = 0; dt < 6; ++dt)
#pragma unroll
      for (int r = 0; r < 4; ++r) o[dt][r] *= sc;

    short4 w0, w1;
#pragma unroll
    for (int r = 0; r < 4; ++r) {
      w0[r] = (short)f2bf(p0[r]);
      w1[r] = (short)f2bf(p1[r]);
    }
    *reinterpret_cast<short4*>(&Ps[wave][lo][g * 4]) = w0;
    *reinterpret_cast<short4*>(&Ps[wave][lo][g * 4 + 16]) = w1;

    short8 bp = *reinterpret_cast<const short8*>(&Ps[wave][lo][g * 8]);
#pragma unroll
    for (int dt = 0; dt < 6; ++dt) {
      short8 av = *reinterpret_cast<const short8*>(&Vt[dt * 16 + lo][g * 8]);
      o[dt] = __builtin_amdgcn_mfma_f32_16x16x32_bf16(av, bp, o[dt], 0, 0, 0);
    }
    __syncthreads();
  }

  float inv = 1.f / l;
  size_t orow = ((size_t)(b * S + bq0 + wave * 16 + lo)) * C + h * HD;
#pragma unroll
  for (int dt = 0; dt < 6; ++dt)
#pragma unroll
    for (int r = 0; r < 4; ++r)
      o_out[orow + dt * 16 + g * 4 + r] = f2bf(o[dt][r] * inv);
}

// ---------------- final scatter, LDS-tiled transpose ----------------
__global__ __launch_bounds__(256) void final_kernel(const float* __restrict__ x0,
                                                    const float* __restrict__ x1,
                                                    const int* __restrict__ sel,
                                                    const float* __restrict__ f_ir,
                                                    const float* __restrict__ f_vis,
                                                    float* __restrict__ out) {
  __shared__ float tile[32][33];
  int b = blockIdx.z;
  int s0 = blockIdx.x * 32, c0 = blockIdx.y * 32;
  int tx = threadIdx.x, ty = threadIdx.y;  // 32 x 8
  // read refined [s][c] coalesced along c
#pragma unroll
  for (int i = 0; i < 32; i += 8) {
    size_t r = ((size_t)(b * S + s0 + ty + i)) * C + c0 + tx;
    tile[ty + i][tx] = x0[r] + x1[r];
  }
  __syncthreads();
  const int* selb = sel + b * S;
#pragma unroll
  for (int i = 0; i < 32; i += 8) {
    int c = c0 + ty + i, s = s0 + tx;
    size_t idx = ((size_t)(b * C + c)) * S + s;
    float v = selb[s] ? tile[tx][ty + i] : (f_ir[idx] + f_vis[idx]);
    out[idx] = v;
  }
}

}  // namespace

extern "C" void kernel_launch(void* const* d_in, const int* in_sizes, int n_in,
                              void* d_out, int out_size, void* d_ws, size_t ws_size,
                              hipStream_t stream) {
  const float* f_ir = (const float*)d_in[0];
  const float* f_vis = (const float*)d_in[1];
  const float* agent_w1 = (const float*)d_in[2];
  const float* agent_b1 = (const float*)d_in[3];
  const float* agent_w2 = (const float*)d_in[4];
  const float* agent_b2 = (const float*)d_in[5];
  const float* norm_g = (const float*)d_in[6];
  const float* norm_b = (const float*)d_in[7];
  const float* in_w = (const float*)d_in[8];
  const float* in_b = (const float*)d_in[9];
  const float* out_w = (const float*)d_in[10];
  const float* out_b = (const float*)d_in[11];
  const float* ffn_w1 = (const float*)d_in[12];
  const float* ffn_b1 = (const float*)d_in[13];
  const float* ffn_w2 = (const float*)d_in[14];
  const float* ffn_b2 = (const float*)d_in[15];
  float* out = (float*)d_out;

  constexpr size_t MS = (size_t)M * C;
  float* ws = (float*)d_ws;
  float* x0 = ws;                                  // fp32 residual stream 0
  float* x1 = x0 + MS;                             // fp32 residual stream 1
  u16* Dbf = (u16*)(x1 + MS);                      // [M,C]  xn / attn_o (bf16)
  u16* qkvb = Dbf + MS;                            // [M,C3] qkv (bf16)
  u16* Hbf = qkvb + (size_t)M * C3;                // [M,FFN] ffn hidden (bf16)
  u16* Ahi = qkvb;                                 // [M,768] agent act hi (aliased)
  u16* Alo = Hbf;                                  // [M,768] agent act lo (aliased)
  u16* wb_in = Hbf + (size_t)M * FFN;              // 2*C3*C
  u16* wb_out = wb_in + 2 * C3 * C;                // 2*C*C
  u16* wb_f1 = wb_out + 2 * C * C;                 // 2*FFN*C
  u16* wb_f2 = wb_f1 + 2 * FFN * C;                // 2*C*FFN
  u16* w1hi = wb_f2 + 2 * C * FFN;                 // 512*768
  u16* w1lo = w1hi + HID * K2C;                    // 512*768
  float* hiddenF = (float*)(w1lo + HID * K2C);     // [M,HID] fp32
  int* sel = (int*)(hiddenF + (size_t)M * HID);
  int* ctr = sel + M;
  int* fixlist = ctr + 1;

  // 0) weights -> bf16 (+ w1 hi/lo split)
  auto cvt = [&](const float* src, u16* dst, int n) {
    int n4 = n / 4;
    cvt_bf16<<<(n4 + 255) / 256, 256, 0, stream>>>(src, dst, n4);
  };
  cvt(in_w, wb_in, 2 * C3 * C);
  cvt(out_w, wb_out, 2 * C * C);
  cvt(ffn_w1, wb_f1, 2 * FFN * C);
  cvt(ffn_w2, wb_f2, 2 * C * FFN);
  cvt_hilo<<<(HID * K2C / 4 + 255) / 256, 256, 0, stream>>>(agent_w1, w1hi, w1lo,
                                                            HID * K2C / 4);

  // 1) transposes
  transpose_cs<<<dim3(S / 32, C / 32, B), dim3(32, 8), 0, stream>>>(f_ir, x0);
  transpose_cs<<<dim3(S / 32, C / 32, B), dim3(32, 8), 0, stream>>>(f_vis, x1);

  // 2) agent hidden via bf16x3 MFMA: hidden = xh*wh + xh*wl + xl*wh (+b1, SiLU)
  act_hilo<<<(M * C / 4 + 255) / 256, 256, 0, stream>>>(x0, x1, Ahi, Alo);
  gemm_bf16<3><<<dim3(HID / 128, M / 128), 256, 0, stream>>>(
      Ahi, w1hi, nullptr, hiddenF, nullptr, HID, K2C);
  gemm_bf16<4><<<dim3(HID / 128, M / 128), 256, 0, stream>>>(
      Ahi, w1lo, nullptr, hiddenF, nullptr, HID, K2C);
  gemm_bf16<5><<<dim3(HID / 128, M / 128), 256, 0, stream>>>(
      Alo, w1hi, agent_b1, hiddenF, nullptr, HID, K2C);

  // 3) selection mask + exact fp32 fixup of near-zero logits
  zero_ctr<<<1, 64, 0, stream>>>(ctr);
  sel_kernel<<<M, 64, 0, stream>>>(hiddenF, agent_w2, agent_b2, sel, ctr, fixlist);
  fixup_kernel<<<64, 256, 0, stream>>>(x0, x1, agent_w1, agent_b1, agent_w2,
                                       agent_b2, ctr, fixlist, sel);

  // 4) two mixer streams (bf16 MFMA GEMMs)
  for (int t = 0; t < 2; ++t) {
    float* x = t ? x1 : x0;
    const float* g = norm_g + t * C;
    const float* bt = norm_b + t * C;
    ln_kernel<<<M, 64, 0, stream>>>(x, g, bt, Dbf);
    gemm_bf16<0><<<dim3(C3 / 128, M / 128), 256, 0, stream>>>(
        Dbf, wb_in + (size_t)t * C3 * C, in_b + t * C3, nullptr, qkvb, C3, C);
    attn_mfma<<<dim3(S / 64, B * HEADS), 256, 0, stream>>>(qkvb, sel, Dbf);
    gemm_bf16<2><<<dim3(C / 128, M / 128), 256, 0, stream>>>(
        Dbf, wb_out + (size_t)t * C * C, out_b + t * C, x, nullptr, C, C);
    ln_kernel<<<M, 64, 0, stream>>>(x, g, bt, Dbf);
    gemm_bf16<1><<<dim3(FFN / 128, M / 128), 256, 0, stream>>>(
        Dbf, wb_f1 + (size_t)t * FFN * C, ffn_b1 + t * FFN, nullptr, Hbf, FFN, C);
    gemm_bf16<2><<<dim3(C / 128, M / 128), 256, 0, stream>>>(
        Hbf, wb_f2 + (size_t)t * C * FFN, ffn_b2 + t * C, x, nullptr, C, FFN);
  }

  // 5) final scatter back to [B,C,H,W]
  final_kernel<<<dim3(S / 32, C / 32, B), dim3(32, 8), 0, stream>>>(
      x0, x1, sel, f_ir, f_vis, out);
}

// Round 9
// 444.141 us; speedup vs baseline: 13.3106x; 1.1666x over previous
//
#include <hip/hip_runtime.h>
#include <math.h>

namespace {

constexpr int B = 8, C = 384, S = 1024;
constexpr int HID = 512, HEADS = 4, HD = 96, FFN = 1536;
constexpr int M = B * S;          // 8192 rows
constexpr int C3 = 3 * C;         // 1152
constexpr int K2C = 2 * C;        // 768 (agent K)
constexpr int FIXCAP = 4096;

using u16 = unsigned short;
using short8 = __attribute__((ext_vector_type(8))) short;
using short4 = __attribute__((ext_vector_type(4))) short;
using f32x4 = __attribute__((ext_vector_type(4))) float;
using u16x4 = __attribute__((ext_vector_type(4))) unsigned short;

__device__ inline u16 f2bf(float f) {
  unsigned int u = __builtin_bit_cast(unsigned int, f);
  u += 0x7fffu + ((u >> 16) & 1u);
  return (u16)(u >> 16);
}
__device__ inline float bf2f(u16 h) {
  unsigned int u = ((unsigned int)h) << 16;
  return __builtin_bit_cast(float, u);
}

// ---------------- fp32 -> bf16 bulk convert (weights) ----------------
__global__ __launch_bounds__(256) void cvt_bf16(const float* __restrict__ in,
                                                u16* __restrict__ out, int n4) {
  int i = blockIdx.x * 256 + threadIdx.x;
  if (i >= n4) return;
  f32x4 v = reinterpret_cast<const f32x4*>(in)[i];
  u16x4 o;
#pragma unroll
  for (int j = 0; j < 4; ++j) o[j] = f2bf(v[j]);
  reinterpret_cast<u16x4*>(out)[i] = o;
}

// ---------------- fp32 -> bf16 hi/lo split (w1) ----------------
__global__ __launch_bounds__(256) void cvt_hilo(const float* __restrict__ in,
                                                u16* __restrict__ hi,
                                                u16* __restrict__ lo, int n4) {
  int i = blockIdx.x * 256 + threadIdx.x;
  if (i >= n4) return;
  f32x4 v = reinterpret_cast<const f32x4*>(in)[i];
  u16x4 oh, ol;
#pragma unroll
  for (int j = 0; j < 4; ++j) {
    u16 h = f2bf(v[j]);
    oh[j] = h;
    ol[j] = f2bf(v[j] - bf2f(h));
  }
  reinterpret_cast<u16x4*>(hi)[i] = oh;
  reinterpret_cast<u16x4*>(lo)[i] = ol;
}

// ---------------- activations -> interleaved [x0;x1] hi/lo bf16 ----------------
__global__ __launch_bounds__(256) void act_hilo(const float* __restrict__ x0,
                                                const float* __restrict__ x1,
                                                u16* __restrict__ Ahi,
                                                u16* __restrict__ Alo) {
  int j = blockIdx.x * 256 + threadIdx.x;  // vec4 index over M*C/4
  if (j >= M * C / 4) return;
  int m = j / (C / 4), c4 = j - m * (C / 4);
  f32x4 v0 = reinterpret_cast<const f32x4*>(x0)[j];
  f32x4 v1 = reinterpret_cast<const f32x4*>(x1)[j];
  u16x4 h0, l0, h1, l1;
#pragma unroll
  for (int t = 0; t < 4; ++t) {
    u16 h = f2bf(v0[t]); h0[t] = h; l0[t] = f2bf(v0[t] - bf2f(h));
    h = f2bf(v1[t]); h1[t] = h; l1[t] = f2bf(v1[t] - bf2f(h));
  }
  size_t base = (size_t)m * K2C;
  *reinterpret_cast<u16x4*>(Ahi + base + c4 * 4) = h0;
  *reinterpret_cast<u16x4*>(Alo + base + c4 * 4) = l0;
  *reinterpret_cast<u16x4*>(Ahi + base + C + c4 * 4) = h1;
  *reinterpret_cast<u16x4*>(Alo + base + C + c4 * 4) = l1;
}

// ---------------- transpose [C,S] -> [S,C] per batch ----------------
__global__ __launch_bounds__(256) void transpose_cs(const float* __restrict__ in,
                                                    float* __restrict__ out) {
  __shared__ float tile[32][33];
  int b = blockIdx.z;
  int s0 = blockIdx.x * 32, c0 = blockIdx.y * 32;
  const float* ip = in + (size_t)b * C * S;
  float* op = out + (size_t)b * S * C;
  int tx = threadIdx.x, ty = threadIdx.y;   // 32 x 8
#pragma unroll
  for (int i = 0; i < 32; i += 8)
    tile[ty + i][tx] = ip[(size_t)(c0 + ty + i) * S + s0 + tx];
  __syncthreads();
#pragma unroll
  for (int i = 0; i < 32; i += 8)
    op[(size_t)(s0 + ty + i) * C + c0 + tx] = tile[tx][ty + i];
}

// ---------------- bf16 MFMA GEMM helpers (swizzled global_load_lds) ----------
__device__ inline void stage_tile(const u16* __restrict__ g, int ldk,
                                  u16* lds, int tid) {
  int w = tid >> 6, l = tid & 63;
#pragma unroll
  for (int i = 0; i < 4; ++i) {
    int lin = i * 4096 + w * 1024 + l * 16;   // byte within 16KB tile
    int row = lin >> 7;                        // 128B per row (64 bf16)
    int slot = (lin >> 4) & 7;
    int k = (slot ^ (row & 7)) * 8;            // inverse-swizzled source
    const u16* gp = g + (size_t)row * ldk + k;
    u16* lp = lds + i * 2048 + w * 512;        // wave-uniform dest (elements)
    __builtin_amdgcn_global_load_lds(
        (const __attribute__((address_space(1))) unsigned int*)gp,
        (__attribute__((address_space(3))) unsigned int*)lp, 16, 0, 0);
  }
}

__device__ inline short8 frag_ld(const u16* lds, int row, int slot) {
  int s = slot ^ (row & 7);
  return *reinterpret_cast<const short8*>(lds + row * 64 + s * 8);
}

// out[M,N] = A[M,K](bf16) * W[N,K]^T(bf16); 128x128 tile, BK=64, 4 waves 2x2.
// MODE 0: +bias -> bf16. MODE 1: +bias, GELU -> bf16. MODE 2: +bias += fp32 xres.
// blockIdx.z batches independent problems via element strides zs*.
template <int MODE>
__global__ __launch_bounds__(256) void gemm_bf16(const u16* __restrict__ A,
                                                 const u16* __restrict__ W,
                                                 const float* __restrict__ bias,
                                                 float* __restrict__ xres,
                                                 u16* __restrict__ obf,
                                                 int N, int K,
                                                 int zsA, int zsW, int zsB, int zsO) {
  __shared__ u16 Asb[128 * 64];
  __shared__ u16 Wsb[128 * 64];
  int z = blockIdx.z;
  if (z) {
    A += (size_t)z * zsA;
    W += (size_t)z * zsW;
    bias += (size_t)z * zsB;
    if (MODE == 2) xres += (size_t)z * zsO;
    else obf += (size_t)z * zsO;
  }
  int tid = threadIdx.x;
  int wave = tid >> 6, lane = tid & 63, lo = lane & 15, hi = lane >> 4;
  int wr = wave >> 1, wc = wave & 1;
  int bn = blockIdx.x * 128, bm = blockIdx.y * 128;
  const u16* Ag = A + (size_t)bm * K;
  const u16* Wg = W + (size_t)bn * K;
  f32x4 acc[4][4] = {};
  for (int k0 = 0; k0 < K; k0 += 64) {
    stage_tile(Ag + k0, K, Asb, tid);
    stage_tile(Wg + k0, K, Wsb, tid);
    __syncthreads();
#pragma unroll
    for (int ks = 0; ks < 2; ++ks) {
      short8 a[4], b[4];
#pragma unroll
      for (int mi = 0; mi < 4; ++mi) a[mi] = frag_ld(Asb, wr * 64 + mi * 16 + lo, ks * 4 + hi);
#pragma unroll
      for (int nj = 0; nj < 4; ++nj) b[nj] = frag_ld(Wsb, wc * 64 + nj * 16 + lo, ks * 4 + hi);
#pragma unroll
      for (int mi = 0; mi < 4; ++mi)
#pragma unroll
        for (int nj = 0; nj < 4; ++nj)
          acc[mi][nj] = __builtin_amdgcn_mfma_f32_16x16x32_bf16(a[mi], b[nj], acc[mi][nj], 0, 0, 0);
    }
    __syncthreads();
  }
  float bv[4];
#pragma unroll
  for (int nj = 0; nj < 4; ++nj) bv[nj] = bias[bn + wc * 64 + nj * 16 + lo];
#pragma unroll
  for (int mi = 0; mi < 4; ++mi) {
#pragma unroll
    for (int r = 0; r < 4; ++r) {
      int m = bm + wr * 64 + mi * 16 + hi * 4 + r;
#pragma unroll
      for (int nj = 0; nj < 4; ++nj) {
        int n = bn + wc * 64 + nj * 16 + lo;
        float v = acc[mi][nj][r] + bv[nj];
        size_t idx = (size_t)m * N + n;
        if (MODE == 0) {
          obf[idx] = f2bf(v);
        } else if (MODE == 1) {
          v = 0.5f * v * (1.f + erff(v * 0.70710678f));
          obf[idx] = f2bf(v);
        } else {
          xres[idx] += v;
        }
      }
    }
  }
}

// ---------------- agent fused 3-pass GEMM: SiLU(xh*wh + xh*wl + xl*wh + b1) ----
__global__ __launch_bounds__(256) void gemm_agent(const u16* __restrict__ Ahi,
                                                  const u16* __restrict__ Alo,
                                                  const u16* __restrict__ w1hi,
                                                  const u16* __restrict__ w1lo,
                                                  const float* __restrict__ b1,
                                                  float* __restrict__ hid) {
  __shared__ u16 Asb[128 * 64];
  __shared__ u16 Wsb[128 * 64];
  int tid = threadIdx.x;
  int wave = tid >> 6, lane = tid & 63, lo = lane & 15, hi = lane >> 4;
  int wr = wave >> 1, wc = wave & 1;
  int bn = blockIdx.x * 128, bm = blockIdx.y * 128;
  const u16* Alist[3] = {Ahi, Ahi, Alo};
  const u16* Wlist[3] = {w1hi, w1lo, w1hi};
  f32x4 acc[4][4] = {};
  for (int p = 0; p < 3; ++p) {
    const u16* Ag = Alist[p] + (size_t)bm * K2C;
    const u16* Wg = Wlist[p] + (size_t)bn * K2C;
    for (int k0 = 0; k0 < K2C; k0 += 64) {
      stage_tile(Ag + k0, K2C, Asb, tid);
      stage_tile(Wg + k0, K2C, Wsb, tid);
      __syncthreads();
#pragma unroll
      for (int ks = 0; ks < 2; ++ks) {
        short8 a[4], b[4];
#pragma unroll
        for (int mi = 0; mi < 4; ++mi) a[mi] = frag_ld(Asb, wr * 64 + mi * 16 + lo, ks * 4 + hi);
#pragma unroll
        for (int nj = 0; nj < 4; ++nj) b[nj] = frag_ld(Wsb, wc * 64 + nj * 16 + lo, ks * 4 + hi);
#pragma unroll
        for (int mi = 0; mi < 4; ++mi)
#pragma unroll
          for (int nj = 0; nj < 4; ++nj)
            acc[mi][nj] = __builtin_amdgcn_mfma_f32_16x16x32_bf16(a[mi], b[nj], acc[mi][nj], 0, 0, 0);
      }
      __syncthreads();
    }
  }
  float bv[4];
#pragma unroll
  for (int nj = 0; nj < 4; ++nj) bv[nj] = b1[bn + wc * 64 + nj * 16 + lo];
#pragma unroll
  for (int mi = 0; mi < 4; ++mi) {
#pragma unroll
    for (int r = 0; r < 4; ++r) {
      int m = bm + wr * 64 + mi * 16 + hi * 4 + r;
#pragma unroll
      for (int nj = 0; nj < 4; ++nj) {
        int n = bn + wc * 64 + nj * 16 + lo;
        float v = acc[mi][nj][r] + bv[nj];
        hid[(size_t)m * HID + n] = v / (1.f + expf(-v));  // SiLU
      }
    }
  }
}

// ---------------- zero the fixup counter ----------------
__global__ void zero_ctr(int* ctr) { if (threadIdx.x == 0) ctr[0] = 0; }

// ---------------- agent logit + threshold + ambiguity list ----------------
__global__ __launch_bounds__(64) void sel_kernel(const float* __restrict__ hidden,
                                                 const float* __restrict__ w2,
                                                 const float* __restrict__ b2,
                                                 int* __restrict__ sel,
                                                 int* __restrict__ ctr,
                                                 int* __restrict__ list) {
  int row = blockIdx.x, t = threadIdx.x;
  const float* hr = hidden + (size_t)row * HID;
  float s = 0.f;
#pragma unroll
  for (int i = 0; i < HID / 64; ++i) s += hr[t + i * 64] * w2[t + i * 64];
  for (int off = 32; off; off >>= 1) s += __shfl_down(s, off);
  if (t == 0) {
    float logit = s + b2[0];
    sel[row] = logit > 0.f ? 1 : 0;
    if (fabsf(logit) < 1e-3f) {
      int idx = atomicAdd(ctr, 1);
      if (idx < FIXCAP) list[idx] = row;
    }
  }
}

// ---------------- exact fp32 recompute of ambiguous rows ----------------
__global__ __launch_bounds__(256) void fixup_kernel(const float* __restrict__ x0,
                                                    const float* __restrict__ x1,
                                                    const float* __restrict__ w1,
                                                    const float* __restrict__ b1,
                                                    const float* __restrict__ w2,
                                                    const float* __restrict__ b2,
                                                    const int* __restrict__ ctr,
                                                    const int* __restrict__ list,
                                                    int* __restrict__ sel) {
  __shared__ float xs[K2C];
  __shared__ float red[4];
  int cnt = ctr[0];
  if (cnt > FIXCAP) cnt = FIXCAP;
  int tid = threadIdx.x;
  for (int ii = blockIdx.x; ii < cnt; ii += gridDim.x) {
    int row = list[ii];
    for (int k = tid; k < C; k += 256) {
      xs[k] = x0[(size_t)row * C + k];
      xs[C + k] = x1[(size_t)row * C + k];
    }
    __syncthreads();
    float partial = 0.f;
#pragma unroll
    for (int u = 0; u < 2; ++u) {
      int n = tid + u * 256;
      const float* wr = w1 + (size_t)n * K2C;
      float acc = 0.f;
      for (int k = 0; k < K2C; ++k) acc = fmaf(wr[k], xs[k], acc);
      acc += b1[n];
      acc = acc / (1.f + expf(-acc));  // SiLU
      partial = fmaf(acc, w2[n], partial);
    }
    for (int off = 32; off; off >>= 1) partial += __shfl_down(partial, off);
    if ((tid & 63) == 0) red[tid >> 6] = partial;
    __syncthreads();
    if (tid == 0) {
      float logit = red[0] + red[1] + red[2] + red[3] + b2[0];
      sel[row] = logit > 0.f ? 1 : 0;
    }
    __syncthreads();
  }
}

// ---------------- batched LayerNorm over C=384 -> bf16, one wave per row ------
// grid = 2M rows; rows [0,M) use params[0], rows [M,2M) use params[1].
__global__ __launch_bounds__(64) void ln_kernel(const float* __restrict__ x,
                                                const float* __restrict__ g_all,
                                                const float* __restrict__ b_all,
                                                u16* __restrict__ y) {
  int row = blockIdx.x, t = threadIdx.x;
  int strm = row >> 13;  // row / M
  const float* g = g_all + strm * C;
  const float* bt = b_all + strm * C;
  const float* xr = x + (size_t)row * C;
  float v[C / 64];
  float s = 0.f, s2 = 0.f;
#pragma unroll
  for (int i = 0; i < C / 64; ++i) {
    float a = xr[t + i * 64];
    v[i] = a;
    s += a;
    s2 += a * a;
  }
  for (int off = 32; off; off >>= 1) {
    s += __shfl_down(s, off);
    s2 += __shfl_down(s2, off);
  }
  s = __shfl(s, 0);
  s2 = __shfl(s2, 0);
  float mean = s / C;
  float var = s2 / C - mean * mean;
  float inv = rsqrtf(var + 1e-5f);
#pragma unroll
  for (int i = 0; i < C / 64; ++i) {
    int c = t + i * 64;
    y[(size_t)row * C + c] = f2bf((v[i] - mean) * inv * g[c] + bt[c]);
  }
}

// ---------------- flash MFMA attention, both streams batched ------------------
// grid.y = 64: t = y>>5, bh = y&31. Vectorized short8 staging.
__global__ __launch_bounds__(256) void attn_mfma(const u16* __restrict__ qkv,
                                                 const int* __restrict__ sel,
                                                 u16* __restrict__ o_out) {
  __shared__ u16 Qs[64][104];
  __shared__ u16 Ks[32][104];
  __shared__ u16 Vt[96][40];
  __shared__ u16 Ps[4][16][40];
  __shared__ float msk[S];

  int bq0 = blockIdx.x * 64;
  int bh2 = blockIdx.y;
  int t = bh2 >> 5, bh = bh2 & 31;
  int b = bh >> 2, h = bh & 3;
  qkv += (size_t)t * M * C3;
  o_out += (size_t)t * M * C;
  int tid = threadIdx.x;
  int wave = tid >> 6, lane = tid & 63;
  int lo = lane & 15, g = lane >> 4;

  // stage Q tile (64 x 96) vectorized: 768 short8 slots
  const u16* qbase = qkv + ((size_t)(b * S + bq0)) * C3 + h * HD;
  for (int idx = tid; idx < 768; idx += 256) {
    int r = idx / 12, j = idx % 12;
    *reinterpret_cast<short8*>(&Qs[r][j * 8]) =
        *reinterpret_cast<const short8*>(qbase + (size_t)r * C3 + j * 8);
  }
  const int* selb = sel + b * S;
#pragma unroll
  for (int i = 0; i < 4; ++i) {
    int k = i * 256 + tid;
    msk[k] = selb[k] ? 0.f : -1e9f;
  }
  __syncthreads();

  const float scale = 0.1020620726f;  // 1/sqrt(96)
  float m = -INFINITY, l = 0.f;
  f32x4 o[6] = {};

  for (int kt0 = 0; kt0 < S; kt0 += 32) {
    const u16* kbase = qkv + ((size_t)(b * S + kt0)) * C3 + C + h * HD;
    const u16* vbase = qkv + ((size_t)(b * S + kt0)) * C3 + 2 * C + h * HD;
    // K tile: 384 short8 slots, row-major
    for (int idx = tid; idx < 384; idx += 256) {
      int r = idx / 12, j = idx % 12;
      *reinterpret_cast<short8*>(&Ks[r][j * 8]) =
          *reinterpret_cast<const short8*>(kbase + (size_t)r * C3 + j * 8);
    }
    // V tile: short8 loads + transposed scalar writes (r-major mapping)
    for (int idx = tid; idx < 384; idx += 256) {
      int r = idx & 31, j = idx >> 5;
      short8 v = *reinterpret_cast<const short8*>(vbase + (size_t)r * C3 + j * 8);
#pragma unroll
      for (int e = 0; e < 8; ++e) Vt[j * 8 + e][r] = (u16)v[e];
    }
    __syncthreads();

    f32x4 st0 = {}, st1 = {};
#pragma unroll
    for (int c = 0; c < 3; ++c) {
      short8 bq = *reinterpret_cast<const short8*>(&Qs[wave * 16 + lo][c * 32 + g * 8]);
      short8 ak0 = *reinterpret_cast<const short8*>(&Ks[lo][c * 32 + g * 8]);
      short8 ak1 = *reinterpret_cast<const short8*>(&Ks[lo + 16][c * 32 + g * 8]);
      st0 = __builtin_amdgcn_mfma_f32_16x16x32_bf16(ak0, bq, st0, 0, 0, 0);
      st1 = __builtin_amdgcn_mfma_f32_16x16x32_bf16(ak1, bq, st1, 0, 0, 0);
    }

    float s0[4], s1[4];
    float pmax = -INFINITY;
#pragma unroll
    for (int r = 0; r < 4; ++r) {
      s0[r] = st0[r] * scale + msk[kt0 + g * 4 + r];
      s1[r] = st1[r] * scale + msk[kt0 + 16 + g * 4 + r];
      pmax = fmaxf(pmax, fmaxf(s0[r], s1[r]));
    }
    pmax = fmaxf(pmax, __shfl_xor(pmax, 16));
    pmax = fmaxf(pmax, __shfl_xor(pmax, 32));
    float mn = fmaxf(m, pmax);
    float sc = __expf(m - mn);
    m = mn;
    float p0[4], p1[4], ps = 0.f;
#pragma unroll
    for (int r = 0; r < 4; ++r) {
      p0[r] = __expf(s0[r] - mn);
      p1[r] = __expf(s1[r] - mn);
      ps += p0[r] + p1[r];
    }
    ps += __shfl_xor(ps, 16);
    ps += __shfl_xor(ps, 32);
    l = l * sc + ps;
#pragma unroll
    for (int dt = 0; dt < 6; ++dt)
#pragma unroll
      for (int r = 0; r < 4; ++r) o[dt][r] *= sc;

    short4 w0, w1;
#pragma unroll
    for (int r = 0; r < 4; ++r) {
      w0[r] = (short)f2bf(p0[r]);
      w1[r] = (short)f2bf(p1[r]);
    }
    *reinterpret_cast<short4*>(&Ps[wave][lo][g * 4]) = w0;
    *reinterpret_cast<short4*>(&Ps[wave][lo][g * 4 + 16]) = w1;

    short8 bp = *reinterpret_cast<const short8*>(&Ps[wave][lo][g * 8]);
#pragma unroll
    for (int dt = 0; dt < 6; ++dt) {
      short8 av = *reinterpret_cast<const short8*>(&Vt[dt * 16 + lo][g * 8]);
      o[dt] = __builtin_amdgcn_mfma_f32_16x16x32_bf16(av, bp, o[dt], 0, 0, 0);
    }
    __syncthreads();
  }

  float inv = 1.f / l;
  size_t orow = ((size_t)(b * S + bq0 + wave * 16 + lo)) * C + h * HD;
#pragma unroll
  for (int dt = 0; dt < 6; ++dt)
#pragma unroll
    for (int r = 0; r < 4; ++r)
      o_out[orow + dt * 16 + g * 4 + r] = f2bf(o[dt][r] * inv);
}

// ---------------- final scatter, LDS-tiled transpose ----------------
__global__ __launch_bounds__(256) void final_kernel(const float* __restrict__ x0,
                                                    const float* __restrict__ x1,
                                                    const int* __restrict__ sel,
                                                    const float* __restrict__ f_ir,
                                                    const float* __restrict__ f_vis,
                                                    float* __restrict__ out) {
  __shared__ float tile[32][33];
  int b = blockIdx.z;
  int s0 = blockIdx.x * 32, c0 = blockIdx.y * 32;
  int tx = threadIdx.x, ty = threadIdx.y;  // 32 x 8
#pragma unroll
  for (int i = 0; i < 32; i += 8) {
    size_t r = ((size_t)(b * S + s0 + ty + i)) * C + c0 + tx;
    tile[ty + i][tx] = x0[r] + x1[r];
  }
  __syncthreads();
  const int* selb = sel + b * S;
#pragma unroll
  for (int i = 0; i < 32; i += 8) {
    int c = c0 + ty + i, s = s0 + tx;
    size_t idx = ((size_t)(b * C + c)) * S + s;
    float v = selb[s] ? tile[tx][ty + i] : (f_ir[idx] + f_vis[idx]);
    out[idx] = v;
  }
}

}  // namespace

extern "C" void kernel_launch(void* const* d_in, const int* in_sizes, int n_in,
                              void* d_out, int out_size, void* d_ws, size_t ws_size,
                              hipStream_t stream) {
  const float* f_ir = (const float*)d_in[0];
  const float* f_vis = (const float*)d_in[1];
  const float* agent_w1 = (const float*)d_in[2];
  const float* agent_b1 = (const float*)d_in[3];
  const float* agent_w2 = (const float*)d_in[4];
  const float* agent_b2 = (const float*)d_in[5];
  const float* norm_g = (const float*)d_in[6];
  const float* norm_b = (const float*)d_in[7];
  const float* in_w = (const float*)d_in[8];
  const float* in_b = (const float*)d_in[9];
  const float* out_w = (const float*)d_in[10];
  const float* out_b = (const float*)d_in[11];
  const float* ffn_w1 = (const float*)d_in[12];
  const float* ffn_b1 = (const float*)d_in[13];
  const float* ffn_w2 = (const float*)d_in[14];
  const float* ffn_b2 = (const float*)d_in[15];
  float* out = (float*)d_out;

  constexpr size_t MS = (size_t)M * C;
  float* ws = (float*)d_ws;
  float* x0 = ws;                                  // fp32 [2M,C]: x0 | x1
  u16* Dbf = (u16*)(x0 + 2 * MS);                  // [2M,C]  xn / attn_o (bf16)
  u16* qkvb = Dbf + 2 * MS;                        // [2M,C3] qkv (bf16)
  u16* Hbf = qkvb + (size_t)2 * M * C3;            // [M,FFN] ffn hidden (bf16)
  u16* wb_in = Hbf + (size_t)M * FFN;              // 2*C3*C
  u16* wb_out = wb_in + 2 * C3 * C;                // 2*C*C
  u16* wb_f1 = wb_out + 2 * C * C;                 // 2*FFN*C
  u16* wb_f2 = wb_f1 + 2 * FFN * C;                // 2*C*FFN
  u16* w1hi = wb_f2 + 2 * C * FFN;                 // 512*768
  u16* w1lo = w1hi + HID * K2C;                    // 512*768
  int* sel = (int*)(w1lo + HID * K2C);
  int* ctr = sel + M;
  int* fixlist = ctr + 1;
  // aliases (dead before their hosts are written)
  u16* Ahi = qkvb;                                 // [M,768]
  u16* Alo = qkvb + (size_t)M * K2C;               // [M,768]
  float* hiddenF = (float*)Hbf;                    // [M,HID] fp32
  float* x1 = x0 + MS;

  // 0) weights -> bf16 (+ w1 hi/lo split)
  auto cvt = [&](const float* src, u16* dst, int n) {
    int n4 = n / 4;
    cvt_bf16<<<(n4 + 255) / 256, 256, 0, stream>>>(src, dst, n4);
  };
  cvt(in_w, wb_in, 2 * C3 * C);
  cvt(out_w, wb_out, 2 * C * C);
  cvt(ffn_w1, wb_f1, 2 * FFN * C);
  cvt(ffn_w2, wb_f2, 2 * C * FFN);
  cvt_hilo<<<(HID * K2C / 4 + 255) / 256, 256, 0, stream>>>(agent_w1, w1hi, w1lo,
                                                            HID * K2C / 4);

  // 1) transposes
  transpose_cs<<<dim3(S / 32, C / 32, B), dim3(32, 8), 0, stream>>>(f_ir, x0);
  transpose_cs<<<dim3(S / 32, C / 32, B), dim3(32, 8), 0, stream>>>(f_vis, x1);

  // 2) agent hidden via fused bf16x3 MFMA + SiLU
  act_hilo<<<(M * C / 4 + 255) / 256, 256, 0, stream>>>(x0, x1, Ahi, Alo);
  gemm_agent<<<dim3(HID / 128, M / 128), 256, 0, stream>>>(Ahi, Alo, w1hi, w1lo,
                                                           agent_b1, hiddenF);

  // 3) selection mask + exact fp32 fixup of near-zero logits
  zero_ctr<<<1, 64, 0, stream>>>(ctr);
  sel_kernel<<<M, 64, 0, stream>>>(hiddenF, agent_w2, agent_b2, sel, ctr, fixlist);
  fixup_kernel<<<64, 256, 0, stream>>>(x0, x1, agent_w1, agent_b1, agent_w2,
                                       agent_b2, ctr, fixlist, sel);

  // 4) mixer, both streams batched through LN/QKV/attn/outproj/LN2
  ln_kernel<<<2 * M, 64, 0, stream>>>(x0, norm_g, norm_b, Dbf);
  gemm_bf16<0><<<dim3(C3 / 128, M / 128, 2), 256, 0, stream>>>(
      Dbf, wb_in, in_b, nullptr, qkvb, C3, C, M * C, C3 * C, C3, M * C3);
  attn_mfma<<<dim3(S / 64, B * HEADS * 2), 256, 0, stream>>>(qkvb, sel, Dbf);
  gemm_bf16<2><<<dim3(C / 128, M / 128, 2), 256, 0, stream>>>(
      Dbf, wb_out, out_b, x0, nullptr, C, C, M * C, C * C, C, M * C);
  ln_kernel<<<2 * M, 64, 0, stream>>>(x0, norm_g, norm_b, Dbf);
  // FFN per stream (Hbf sized for one stream)
  for (int t = 0; t < 2; ++t) {
    gemm_bf16<1><<<dim3(FFN / 128, M / 128), 256, 0, stream>>>(
        Dbf + (size_t)t * M * C, wb_f1 + (size_t)t * FFN * C, ffn_b1 + t * FFN,
        nullptr, Hbf, FFN, C, 0, 0, 0, 0);
    gemm_bf16<2><<<dim3(C / 128, M / 128), 256, 0, stream>>>(
        Hbf, wb_f2 + (size_t)t * C * FFN, ffn_b2 + t * C, x0 + (size_t)t * MS,
        nullptr, C, FFN, 0, 0, 0, 0);
  }

  // 5) final scatter back to [B,C,H,W]
  final_kernel<<<dim3(S / 32, C / 32, B), dim3(32, 8), 0, stream>>>(
      x0, x1, sel, f_ir, f_vis, out);
}

// Round 10
// 375.722 us; speedup vs baseline: 15.7344x; 1.1821x over previous
//
#include <hip/hip_runtime.h>
#include <math.h>

namespace {

constexpr int B = 8, C = 384, S = 1024;
constexpr int HID = 512, HEADS = 4, HD = 96, FFN = 1536;
constexpr int M = B * S;          // 8192 rows
constexpr int C3 = 3 * C;         // 1152
constexpr int K2C = 2 * C;        // 768 (agent K)
constexpr int FIXCAP = 4096;

using u16 = unsigned short;
using short8 = __attribute__((ext_vector_type(8))) short;
using short4 = __attribute__((ext_vector_type(4))) short;
using f32x4 = __attribute__((ext_vector_type(4))) float;
using u16x4 = __attribute__((ext_vector_type(4))) unsigned short;

__device__ inline u16 f2bf(float f) {
  unsigned int u = __builtin_bit_cast(unsigned int, f);
  u += 0x7fffu + ((u >> 16) & 1u);
  return (u16)(u >> 16);
}
__device__ inline float bf2f(u16 h) {
  unsigned int u = ((unsigned int)h) << 16;
  return __builtin_bit_cast(float, u);
}
__device__ inline unsigned int cvtpk(float a, float b) {  // [bf16(b)<<16 | bf16(a)]
  unsigned int r;
  asm("v_cvt_pk_bf16_f32 %0, %1, %2" : "=v"(r) : "v"(a), "v"(b));
  return r;
}

// ---------------- fp32 -> bf16 bulk convert (weights) ----------------
__global__ __launch_bounds__(256) void cvt_bf16(const float* __restrict__ in,
                                                u16* __restrict__ out, int n4) {
  int i = blockIdx.x * 256 + threadIdx.x;
  if (i >= n4) return;
  f32x4 v = reinterpret_cast<const f32x4*>(in)[i];
  u16x4 o;
#pragma unroll
  for (int j = 0; j < 4; ++j) o[j] = f2bf(v[j]);
  reinterpret_cast<u16x4*>(out)[i] = o;
}

// ---------------- fp32 -> bf16 hi/lo split (w1) ----------------
__global__ __launch_bounds__(256) void cvt_hilo(const float* __restrict__ in,
                                                u16* __restrict__ hi,
                                                u16* __restrict__ lo, int n4) {
  int i = blockIdx.x * 256 + threadIdx.x;
  if (i >= n4) return;
  f32x4 v = reinterpret_cast<const f32x4*>(in)[i];
  u16x4 oh, ol;
#pragma unroll
  for (int j = 0; j < 4; ++j) {
    u16 h = f2bf(v[j]);
    oh[j] = h;
    ol[j] = f2bf(v[j] - bf2f(h));
  }
  reinterpret_cast<u16x4*>(hi)[i] = oh;
  reinterpret_cast<u16x4*>(lo)[i] = ol;
}

// ------- transpose [C,S] -> [S,C] per batch, fused agent hi/lo emit -------
__global__ __launch_bounds__(256) void transpose_cs(const float* __restrict__ in,
                                                    float* __restrict__ out,
                                                    u16* __restrict__ Ahi,
                                                    u16* __restrict__ Alo, int coff) {
  __shared__ float tile[32][33];
  int b = blockIdx.z;
  int s0 = blockIdx.x * 32, c0 = blockIdx.y * 32;
  const float* ip = in + (size_t)b * C * S;
  float* op = out + (size_t)b * S * C;
  int tx = threadIdx.x, ty = threadIdx.y;   // 32 x 8
#pragma unroll
  for (int i = 0; i < 32; i += 8)
    tile[ty + i][tx] = ip[(size_t)(c0 + ty + i) * S + s0 + tx];
  __syncthreads();
#pragma unroll
  for (int i = 0; i < 32; i += 8) {
    int s = s0 + ty + i;
    float v = tile[tx][ty + i];
    op[(size_t)s * C + c0 + tx] = v;
    u16 hb = f2bf(v);
    size_t am = (size_t)(b * S + s) * K2C + coff + c0 + tx;
    Ahi[am] = hb;
    Alo[am] = f2bf(v - bf2f(hb));
  }
}

// ---------------- bf16 MFMA GEMM helpers (swizzled global_load_lds) ----------
__device__ inline void stage_tile(const u16* __restrict__ g, int ldk,
                                  u16* lds, int tid) {
  int w = tid >> 6, l = tid & 63;
#pragma unroll
  for (int i = 0; i < 4; ++i) {
    int lin = i * 4096 + w * 1024 + l * 16;   // byte within 16KB tile
    int row = lin >> 7;                        // 128B per row (64 bf16)
    int slot = (lin >> 4) & 7;
    int k = (slot ^ (row & 7)) * 8;            // inverse-swizzled source
    const u16* gp = g + (size_t)row * ldk + k;
    u16* lp = lds + i * 2048 + w * 512;        // wave-uniform dest (elements)
    __builtin_amdgcn_global_load_lds(
        (const __attribute__((address_space(1))) unsigned int*)gp,
        (__attribute__((address_space(3))) unsigned int*)lp, 16, 0, 0);
  }
}

__device__ inline short8 frag_ld(const u16* lds, int row, int slot) {
  int s = slot ^ (row & 7);
  return *reinterpret_cast<const short8*>(lds + row * 64 + s * 8);
}

// out[M,N] = A[M,K](bf16) * W[N,K]^T(bf16); 128x128 tile, BK=64, 4 waves 2x2.
// MODE 0: +bias -> bf16. MODE 1: +bias, GELU -> bf16. MODE 2: +bias += fp32 xres.
// blockIdx.z batches independent problems via element strides zs*.
template <int MODE>
__global__ __launch_bounds__(256) void gemm_bf16(const u16* __restrict__ A,
                                                 const u16* __restrict__ W,
                                                 const float* __restrict__ bias,
                                                 float* __restrict__ xres,
                                                 u16* __restrict__ obf,
                                                 int N, int K,
                                                 int zsA, int zsW, int zsB, int zsO) {
  __shared__ u16 Asb[128 * 64];
  __shared__ u16 Wsb[128 * 64];
  int z = blockIdx.z;
  if (z) {
    A += (size_t)z * zsA;
    W += (size_t)z * zsW;
    bias += (size_t)z * zsB;
    if (MODE == 2) xres += (size_t)z * zsO;
    else obf += (size_t)z * zsO;
  }
  int tid = threadIdx.x;
  int wave = tid >> 6, lane = tid & 63, lo = lane & 15, hi = lane >> 4;
  int wr = wave >> 1, wc = wave & 1;
  int bn = blockIdx.x * 128, bm = blockIdx.y * 128;
  const u16* Ag = A + (size_t)bm * K;
  const u16* Wg = W + (size_t)bn * K;
  f32x4 acc[4][4] = {};
  for (int k0 = 0; k0 < K; k0 += 64) {
    stage_tile(Ag + k0, K, Asb, tid);
    stage_tile(Wg + k0, K, Wsb, tid);
    __syncthreads();
#pragma unroll
    for (int ks = 0; ks < 2; ++ks) {
      short8 a[4], b[4];
#pragma unroll
      for (int mi = 0; mi < 4; ++mi) a[mi] = frag_ld(Asb, wr * 64 + mi * 16 + lo, ks * 4 + hi);
#pragma unroll
      for (int nj = 0; nj < 4; ++nj) b[nj] = frag_ld(Wsb, wc * 64 + nj * 16 + lo, ks * 4 + hi);
#pragma unroll
      for (int mi = 0; mi < 4; ++mi)
#pragma unroll
        for (int nj = 0; nj < 4; ++nj)
          acc[mi][nj] = __builtin_amdgcn_mfma_f32_16x16x32_bf16(a[mi], b[nj], acc[mi][nj], 0, 0, 0);
    }
    __syncthreads();
  }
  float bv[4];
#pragma unroll
  for (int nj = 0; nj < 4; ++nj) bv[nj] = bias[bn + wc * 64 + nj * 16 + lo];
#pragma unroll
  for (int mi = 0; mi < 4; ++mi) {
#pragma unroll
    for (int r = 0; r < 4; ++r) {
      int m = bm + wr * 64 + mi * 16 + hi * 4 + r;
#pragma unroll
      for (int nj = 0; nj < 4; ++nj) {
        int n = bn + wc * 64 + nj * 16 + lo;
        float v = acc[mi][nj][r] + bv[nj];
        size_t idx = (size_t)m * N + n;
        if (MODE == 0) {
          obf[idx] = f2bf(v);
        } else if (MODE == 1) {
          v = 0.5f * v * (1.f + erff(v * 0.70710678f));
          obf[idx] = f2bf(v);
        } else {
          xres[idx] += v;
        }
      }
    }
  }
}

// ---------------- agent fused 3-pass GEMM: SiLU(xh*wh + xh*wl + xl*wh + b1) ----
__global__ __launch_bounds__(256) void gemm_agent(const u16* __restrict__ Ahi,
                                                  const u16* __restrict__ Alo,
                                                  const u16* __restrict__ w1hi,
                                                  const u16* __restrict__ w1lo,
                                                  const float* __restrict__ b1,
                                                  float* __restrict__ hid) {
  __shared__ u16 Asb[128 * 64];
  __shared__ u16 Wsb[128 * 64];
  int tid = threadIdx.x;
  int wave = tid >> 6, lane = tid & 63, lo = lane & 15, hi = lane >> 4;
  int wr = wave >> 1, wc = wave & 1;
  int bn = blockIdx.x * 128, bm = blockIdx.y * 128;
  const u16* Alist[3] = {Ahi, Ahi, Alo};
  const u16* Wlist[3] = {w1hi, w1lo, w1hi};
  f32x4 acc[4][4] = {};
  for (int p = 0; p < 3; ++p) {
    const u16* Ag = Alist[p] + (size_t)bm * K2C;
    const u16* Wg = Wlist[p] + (size_t)bn * K2C;
    for (int k0 = 0; k0 < K2C; k0 += 64) {
      stage_tile(Ag + k0, K2C, Asb, tid);
      stage_tile(Wg + k0, K2C, Wsb, tid);
      __syncthreads();
#pragma unroll
      for (int ks = 0; ks < 2; ++ks) {
        short8 a[4], b[4];
#pragma unroll
        for (int mi = 0; mi < 4; ++mi) a[mi] = frag_ld(Asb, wr * 64 + mi * 16 + lo, ks * 4 + hi);
#pragma unroll
        for (int nj = 0; nj < 4; ++nj) b[nj] = frag_ld(Wsb, wc * 64 + nj * 16 + lo, ks * 4 + hi);
#pragma unroll
        for (int mi = 0; mi < 4; ++mi)
#pragma unroll
          for (int nj = 0; nj < 4; ++nj)
            acc[mi][nj] = __builtin_amdgcn_mfma_f32_16x16x32_bf16(a[mi], b[nj], acc[mi][nj], 0, 0, 0);
      }
      __syncthreads();
    }
  }
  float bv[4];
#pragma unroll
  for (int nj = 0; nj < 4; ++nj) bv[nj] = b1[bn + wc * 64 + nj * 16 + lo];
#pragma unroll
  for (int mi = 0; mi < 4; ++mi) {
#pragma unroll
    for (int r = 0; r < 4; ++r) {
      int m = bm + wr * 64 + mi * 16 + hi * 4 + r;
#pragma unroll
      for (int nj = 0; nj < 4; ++nj) {
        int n = bn + wc * 64 + nj * 16 + lo;
        float v = acc[mi][nj][r] + bv[nj];
        hid[(size_t)m * HID + n] = v / (1.f + expf(-v));  // SiLU
      }
    }
  }
}

// ---------------- zero the fixup counter ----------------
__global__ void zero_ctr(int* ctr) { if (threadIdx.x == 0) ctr[0] = 0; }

// ---------------- agent logit + threshold + ambiguity list ----------------
__global__ __launch_bounds__(64) void sel_kernel(const float* __restrict__ hidden,
                                                 const float* __restrict__ w2,
                                                 const float* __restrict__ b2,
                                                 int* __restrict__ sel,
                                                 int* __restrict__ ctr,
                                                 int* __restrict__ list) {
  int row = blockIdx.x, t = threadIdx.x;
  const float* hr = hidden + (size_t)row * HID;
  float s = 0.f;
#pragma unroll
  for (int i = 0; i < HID / 64; ++i) s += hr[t + i * 64] * w2[t + i * 64];
  for (int off = 32; off; off >>= 1) s += __shfl_down(s, off);
  if (t == 0) {
    float logit = s + b2[0];
    sel[row] = logit > 0.f ? 1 : 0;
    if (fabsf(logit) < 1e-3f) {
      int idx = atomicAdd(ctr, 1);
      if (idx < FIXCAP) list[idx] = row;
    }
  }
}

// ---------------- exact fp32 recompute of ambiguous rows ----------------
__global__ __launch_bounds__(256) void fixup_kernel(const float* __restrict__ x0,
                                                    const float* __restrict__ x1,
                                                    const float* __restrict__ w1,
                                                    const float* __restrict__ b1,
                                                    const float* __restrict__ w2,
                                                    const float* __restrict__ b2,
                                                    const int* __restrict__ ctr,
                                                    const int* __restrict__ list,
                                                    int* __restrict__ sel) {
  __shared__ float xs[K2C];
  __shared__ float red[4];
  int cnt = ctr[0];
  if (cnt > FIXCAP) cnt = FIXCAP;
  int tid = threadIdx.x;
  for (int ii = blockIdx.x; ii < cnt; ii += gridDim.x) {
    int row = list[ii];
    for (int k = tid; k < C; k += 256) {
      xs[k] = x0[(size_t)row * C + k];
      xs[C + k] = x1[(size_t)row * C + k];
    }
    __syncthreads();
    float partial = 0.f;
#pragma unroll
    for (int u = 0; u < 2; ++u) {
      int n = tid + u * 256;
      const float* wr = w1 + (size_t)n * K2C;
      float acc = 0.f;
      for (int k = 0; k < K2C; ++k) acc = fmaf(wr[k], xs[k], acc);
      acc += b1[n];
      acc = acc / (1.f + expf(-acc));  // SiLU
      partial = fmaf(acc, w2[n], partial);
    }
    for (int off = 32; off; off >>= 1) partial += __shfl_down(partial, off);
    if ((tid & 63) == 0) red[tid >> 6] = partial;
    __syncthreads();
    if (tid == 0) {
      float logit = red[0] + red[1] + red[2] + red[3] + b2[0];
      sel[row] = logit > 0.f ? 1 : 0;
    }
    __syncthreads();
  }
}

// ---------------- batched LayerNorm over C=384 -> bf16, one wave per row ------
__global__ __launch_bounds__(64) void ln_kernel(const float* __restrict__ x,
                                                const float* __restrict__ g_all,
                                                const float* __restrict__ b_all,
                                                u16* __restrict__ y) {
  int row = blockIdx.x, t = threadIdx.x;
  int strm = row >> 13;  // row / M
  const float* g = g_all + strm * C;
  const float* bt = b_all + strm * C;
  const float* xr = x + (size_t)row * C;
  float v[C / 64];
  float s = 0.f, s2 = 0.f;
#pragma unroll
  for (int i = 0; i < C / 64; ++i) {
    float a = xr[t + i * 64];
    v[i] = a;
    s += a;
    s2 += a * a;
  }
  for (int off = 32; off; off >>= 1) {
    s += __shfl_down(s, off);
    s2 += __shfl_down(s2, off);
  }
  s = __shfl(s, 0);
  s2 = __shfl(s2, 0);
  float mean = s / C;
  float var = s2 / C - mean * mean;
  float inv = rsqrtf(var + 1e-5f);
#pragma unroll
  for (int i = 0; i < C / 64; ++i) {
    int c = t + i * 64;
    y[(size_t)row * C + c] = f2bf((v[i] - mean) * inv * g[c] + bt[c]);
  }
}

// ---------------- flash MFMA attention v3 (both streams batched) --------------
// KT=64, Q pre-scaled in registers, defer-max, P stays in registers (k-slot
// permutation shared between Vt reads and P pack), Vt stride 72.
__global__ __launch_bounds__(256) void attn_mfma(const u16* __restrict__ qkv,
                                                 const int* __restrict__ sel,
                                                 u16* __restrict__ o_out) {
  __shared__ u16 Ks[64][104];
  __shared__ u16 Vt[96][72];
  __shared__ float msk[S];

  int bq0 = blockIdx.x * 64;
  int bh2 = blockIdx.y;                  // 64 = 2 streams x 8 b x 4 h
  int strm = bh2 >> 5, bh = bh2 & 31;
  int b = bh >> 2, h = bh & 3;
  qkv += (size_t)strm * M * C3;
  o_out += (size_t)strm * M * C;
  int tid = threadIdx.x;
  int wave = tid >> 6, lane = tid & 63;
  int lo = lane & 15, g = lane >> 4;

  const int* selb = sel + b * S;
#pragma unroll
  for (int i = 0; i < 4; ++i) {
    int k = i * 256 + tid;
    msk[k] = selb[k] ? 0.f : -1e9f;
  }

  // Q fragments in registers, pre-scaled by 1/sqrt(HD)
  const float scale = 0.1020620726f;
  short8 bq[3];
  const u16* qrow = qkv + ((size_t)(b * S + bq0 + wave * 16 + lo)) * C3 + h * HD;
#pragma unroll
  for (int c = 0; c < 3; ++c) {
    short8 q = *reinterpret_cast<const short8*>(qrow + c * 32 + g * 8);
    short8 r;
#pragma unroll
    for (int e = 0; e < 8; ++e) r[e] = (short)f2bf(bf2f((u16)q[e]) * scale);
    bq[c] = r;
  }

  float m = -30.f, l = 0.f;
  f32x4 o[6] = {};

  for (int kt0 = 0; kt0 < S; kt0 += 64) {
    const u16* kbase = qkv + ((size_t)(b * S + kt0)) * C3 + C + h * HD;
    const u16* vbase = qkv + ((size_t)(b * S + kt0)) * C3 + 2 * C + h * HD;
    // K: row-major [64][96] (pad 104), coalesced short8
#pragma unroll
    for (int i = 0; i < 3; ++i) {
      int idx = i * 256 + tid;
      int r = idx / 12, j = idx - r * 12;
      *reinterpret_cast<short8*>(&Ks[r][j * 8]) =
          *reinterpret_cast<const short8*>(kbase + (size_t)r * C3 + j * 8);
    }
    // V^T: [96][72]; r = lane -> transposed scalar writes are 2-way (free)
#pragma unroll
    for (int i = 0; i < 3; ++i) {
      int idx = i * 256 + tid;
      int r = idx & 63, j = idx >> 6;
      short8 v = *reinterpret_cast<const short8*>(vbase + (size_t)r * C3 + j * 8);
#pragma unroll
      for (int e = 0; e < 8; ++e) Vt[j * 8 + e][r] = (u16)v[e];
    }
    __syncthreads();

    // QK^T: st[t4][r] = S[k=kt0+16t4+4g+r][q=lo] (scale folded into Q)
    f32x4 st[4] = {};
#pragma unroll
    for (int c = 0; c < 3; ++c)
#pragma unroll
      for (int t4 = 0; t4 < 4; ++t4) {
        short8 ak = *reinterpret_cast<const short8*>(&Ks[t4 * 16 + lo][c * 32 + g * 8]);
        st[t4] = __builtin_amdgcn_mfma_f32_16x16x32_bf16(ak, bq[c], st[t4], 0, 0, 0);
      }

    // masked scores + row max
    float p[4][4];
    float pmax = -INFINITY;
#pragma unroll
    for (int t4 = 0; t4 < 4; ++t4) {
      f32x4 mk = *reinterpret_cast<const f32x4*>(&msk[kt0 + t4 * 16 + g * 4]);
#pragma unroll
      for (int r = 0; r < 4; ++r) {
        float s = st[t4][r] + mk[r];
        p[t4][r] = s;
        pmax = fmaxf(pmax, s);
      }
    }
    pmax = fmaxf(pmax, __shfl_xor(pmax, 16));
    pmax = fmaxf(pmax, __shfl_xor(pmax, 32));
    // defer-max: only rescale when the running max grew by > 8
    if (__any(pmax - m > 8.f)) {
      float mn = fmaxf(m, pmax);
      float sc = __expf(m - mn);
      m = mn;
      l *= sc;
#pragma unroll
      for (int dt = 0; dt < 6; ++dt)
#pragma unroll
        for (int r = 0; r < 4; ++r) o[dt][r] *= sc;
    }
    float ps = 0.f;
#pragma unroll
    for (int t4 = 0; t4 < 4; ++t4)
#pragma unroll
      for (int r = 0; r < 4; ++r) {
        float e = __expf(p[t4][r] - m);
        p[t4][r] = e;
        ps += e;
      }
    ps += __shfl_xor(ps, 16);
    ps += __shfl_xor(ps, 32);
    l += ps;

    // pack P -> bf16 B-fragments; slot e<4: k=32h2+4g+e, e>=4: k=32h2+16+4g+(e-4)
    short8 bp[2];
#pragma unroll
    for (int h2 = 0; h2 < 2; ++h2) {
      union { short8 s8; unsigned int u[4]; } u_;
      u_.u[0] = cvtpk(p[2 * h2][0], p[2 * h2][1]);
      u_.u[1] = cvtpk(p[2 * h2][2], p[2 * h2][3]);
      u_.u[2] = cvtpk(p[2 * h2 + 1][0], p[2 * h2 + 1][1]);
      u_.u[3] = cvtpk(p[2 * h2 + 1][2], p[2 * h2 + 1][3]);
      bp[h2] = u_.s8;
    }

    // PV: A = V^T with the same k-slot permutation (two b64 reads per mfma)
#pragma unroll
    for (int dt = 0; dt < 6; ++dt)
#pragma unroll
      for (int h2 = 0; h2 < 2; ++h2) {
        union { short8 s8; short4 s4[2]; } a_;
        a_.s4[0] = *reinterpret_cast<const short4*>(&Vt[dt * 16 + lo][h2 * 32 + g * 4]);
        a_.s4[1] = *reinterpret_cast<const short4*>(&Vt[dt * 16 + lo][h2 * 32 + 16 + g * 4]);
        o[dt] = __builtin_amdgcn_mfma_f32_16x16x32_bf16(a_.s8, bp[h2], o[dt], 0, 0, 0);
      }
    __syncthreads();
  }

  float inv = 1.f / l;
  size_t orow = ((size_t)(b * S + bq0 + wave * 16 + lo)) * C + h * HD;
#pragma unroll
  for (int dt = 0; dt < 6; ++dt)
#pragma unroll
    for (int r = 0; r < 4; ++r)
      o_out[orow + dt * 16 + g * 4 + r] = f2bf(o[dt][r] * inv);
}

// ---------------- final scatter, LDS-tiled transpose ----------------
__global__ __launch_bounds__(256) void final_kernel(const float* __restrict__ x0,
                                                    const float* __restrict__ x1,
                                                    const int* __restrict__ sel,
                                                    const float* __restrict__ f_ir,
                                                    const float* __restrict__ f_vis,
                                                    float* __restrict__ out) {
  __shared__ float tile[32][33];
  int b = blockIdx.z;
  int s0 = blockIdx.x * 32, c0 = blockIdx.y * 32;
  int tx = threadIdx.x, ty = threadIdx.y;  // 32 x 8
#pragma unroll
  for (int i = 0; i < 32; i += 8) {
    size_t r = ((size_t)(b * S + s0 + ty + i)) * C + c0 + tx;
    tile[ty + i][tx] = x0[r] + x1[r];
  }
  __syncthreads();
  const int* selb = sel + b * S;
#pragma unroll
  for (int i = 0; i < 32; i += 8) {
    int c = c0 + ty + i, s = s0 + tx;
    size_t idx = ((size_t)(b * C + c)) * S + s;
    float v = selb[s] ? tile[tx][ty + i] : (f_ir[idx] + f_vis[idx]);
    out[idx] = v;
  }
}

}  // namespace

extern "C" void kernel_launch(void* const* d_in, const int* in_sizes, int n_in,
                              void* d_out, int out_size, void* d_ws, size_t ws_size,
                              hipStream_t stream) {
  const float* f_ir = (const float*)d_in[0];
  const float* f_vis = (const float*)d_in[1];
  const float* agent_w1 = (const float*)d_in[2];
  const float* agent_b1 = (const float*)d_in[3];
  const float* agent_w2 = (const float*)d_in[4];
  const float* agent_b2 = (const float*)d_in[5];
  const float* norm_g = (const float*)d_in[6];
  const float* norm_b = (const float*)d_in[7];
  const float* in_w = (const float*)d_in[8];
  const float* in_b = (const float*)d_in[9];
  const float* out_w = (const float*)d_in[10];
  const float* out_b = (const float*)d_in[11];
  const float* ffn_w1 = (const float*)d_in[12];
  const float* ffn_b1 = (const float*)d_in[13];
  const float* ffn_w2 = (const float*)d_in[14];
  const float* ffn_b2 = (const float*)d_in[15];
  float* out = (float*)d_out;

  constexpr size_t MS = (size_t)M * C;
  float* ws = (float*)d_ws;
  float* x0 = ws;                                  // fp32 [2M,C]: x0 | x1
  u16* Dbf = (u16*)(x0 + 2 * MS);                  // [2M,C]  xn / attn_o (bf16)
  u16* qkvb = Dbf + 2 * MS;                        // [2M,C3] qkv (bf16)
  u16* Hext = qkvb + (size_t)2 * M * C3;           // [M,FFN] u16 extension
  u16* wb_in = Hext + (size_t)M * FFN;             // 2*C3*C
  u16* wb_out = wb_in + 2 * C3 * C;                // 2*C*C
  u16* wb_f1 = wb_out + 2 * C * C;                 // 2*FFN*C
  u16* wb_f2 = wb_f1 + 2 * FFN * C;                // 2*C*FFN
  u16* w1hi = wb_f2 + 2 * C * FFN;                 // 512*768
  u16* w1lo = w1hi + HID * K2C;                    // 512*768
  int* sel = (int*)(w1lo + HID * K2C);
  int* ctr = sel + M;
  int* fixlist = ctr + 1;
  // aliases (each dead before its host region is rewritten)
  u16* Ahi = qkvb;                                 // [M,768]  (dead before QKV)
  u16* Alo = qkvb + (size_t)M * K2C;               // [M,768]
  float* hiddenF = (float*)Hext;                   // [M,HID] fp32 (dead before FFN)
  u16* Hbf = qkvb;                                 // FFN hidden [2M,FFN] spans qkvb+Hext
  float* x1 = x0 + MS;

  // 0) weights -> bf16 (+ w1 hi/lo split)
  auto cvt = [&](const float* src, u16* dst, int n) {
    int n4 = n / 4;
    cvt_bf16<<<(n4 + 255) / 256, 256, 0, stream>>>(src, dst, n4);
  };
  cvt(in_w, wb_in, 2 * C3 * C);
  cvt(out_w, wb_out, 2 * C * C);
  cvt(ffn_w1, wb_f1, 2 * FFN * C);
  cvt(ffn_w2, wb_f2, 2 * C * FFN);
  cvt_hilo<<<(HID * K2C / 4 + 255) / 256, 256, 0, stream>>>(agent_w1, w1hi, w1lo,
                                                            HID * K2C / 4);

  // 1) transposes (fused agent hi/lo activation emit)
  transpose_cs<<<dim3(S / 32, C / 32, B), dim3(32, 8), 0, stream>>>(
      f_ir, x0, Ahi, Alo, 0);
  transpose_cs<<<dim3(S / 32, C / 32, B), dim3(32, 8), 0, stream>>>(
      f_vis, x1, Ahi, Alo, C);

  // 2) agent hidden via fused bf16x3 MFMA + SiLU
  gemm_agent<<<dim3(HID / 128, M / 128), 256, 0, stream>>>(Ahi, Alo, w1hi, w1lo,
                                                           agent_b1, hiddenF);

  // 3) selection mask + exact fp32 fixup of near-zero logits
  zero_ctr<<<1, 64, 0, stream>>>(ctr);
  sel_kernel<<<M, 64, 0, stream>>>(hiddenF, agent_w2, agent_b2, sel, ctr, fixlist);
  fixup_kernel<<<64, 256, 0, stream>>>(x0, x1, agent_w1, agent_b1, agent_w2,
                                       agent_b2, ctr, fixlist, sel);

  // 4) mixer, both streams batched end-to-end
  ln_kernel<<<2 * M, 64, 0, stream>>>(x0, norm_g, norm_b, Dbf);
  gemm_bf16<0><<<dim3(C3 / 128, M / 128, 2), 256, 0, stream>>>(
      Dbf, wb_in, in_b, nullptr, qkvb, C3, C, M * C, C3 * C, C3, M * C3);
  attn_mfma<<<dim3(S / 64, B * HEADS * 2), 256, 0, stream>>>(qkvb, sel, Dbf);
  gemm_bf16<2><<<dim3(C / 128, M / 128, 2), 256, 0, stream>>>(
      Dbf, wb_out, out_b, x0, nullptr, C, C, M * C, C * C, C, M * C);
  ln_kernel<<<2 * M, 64, 0, stream>>>(x0, norm_g, norm_b, Dbf);
  gemm_bf16<1><<<dim3(FFN / 128, M / 128, 2), 256, 0, stream>>>(
      Dbf, wb_f1, ffn_b1, nullptr, Hbf, FFN, C, M * C, FFN * C, FFN, M * FFN);
  gemm_bf16<2><<<dim3(C / 128, M / 128, 2), 256, 0, stream>>>(
      Hbf, wb_f2, ffn_b2, x0, nullptr, C, FFN, M * FFN, C * FFN, C, M * C);

  // 5) final scatter back to [B,C,H,W]
  final_kernel<<<dim3(S / 32, C / 32, B), dim3(32, 8), 0, stream>>>(
      x0, x1, sel, f_ir, f_vis, out);
}

// Round 11
// 371.308 us; speedup vs baseline: 15.9215x; 1.0119x over previous
//
#include <hip/hip_runtime.h>
#include <math.h>

namespace {

constexpr int B = 8, C = 384, S = 1024;
constexpr int HID = 512, HEADS = 4, HD = 96, FFN = 1536;
constexpr int M = B * S;          // 8192 rows
constexpr int C3 = 3 * C;         // 1152
constexpr int K2C = 2 * C;        // 768 (agent K)
constexpr int FIXCAP = 4096;

using u16 = unsigned short;
using short8 = __attribute__((ext_vector_type(8))) short;
using short4 = __attribute__((ext_vector_type(4))) short;
using f32x4 = __attribute__((ext_vector_type(4))) float;
using u16x4 = __attribute__((ext_vector_type(4))) unsigned short;

__device__ inline u16 f2bf(float f) {
  unsigned int u = __builtin_bit_cast(unsigned int, f);
  u += 0x7fffu + ((u >> 16) & 1u);
  return (u16)(u >> 16);
}
__device__ inline float bf2f(u16 h) {
  unsigned int u = ((unsigned int)h) << 16;
  return __builtin_bit_cast(float, u);
}
__device__ inline unsigned int cvtpk(float a, float b) {  // [bf16(b)<<16 | bf16(a)]
  unsigned int r;
  asm("v_cvt_pk_bf16_f32 %0, %1, %2" : "=v"(r) : "v"(a), "v"(b));
  return r;
}

// ------- all mixer weights -> bf16 in one dispatch (dst regions contiguous);
// also zeroes the fixup counter (runs before sel each launch) -------
constexpr int N4_IN = 2 * C3 * C / 4;        // 221184
constexpr int N4_OUT = 2 * C * C / 4;        // 73728
constexpr int N4_F1 = 2 * FFN * C / 4;       // 294912
constexpr int N4_F2 = 2 * C * FFN / 4;       // 294912
constexpr int N4_ALL = N4_IN + N4_OUT + N4_F1 + N4_F2;

__global__ __launch_bounds__(256) void cvt_all(const float* __restrict__ in_w,
                                               const float* __restrict__ out_w,
                                               const float* __restrict__ f1,
                                               const float* __restrict__ f2,
                                               u16* __restrict__ dst,
                                               int* __restrict__ ctr) {
  int i = blockIdx.x * 256 + threadIdx.x;
  if (i == 0) ctr[0] = 0;
  if (i >= N4_ALL) return;
  const float* src;
  int off = i;
  if (i < N4_IN) {
    src = in_w;
  } else if (i < N4_IN + N4_OUT) {
    src = out_w; off = i - N4_IN;
  } else if (i < N4_IN + N4_OUT + N4_F1) {
    src = f1; off = i - N4_IN - N4_OUT;
  } else {
    src = f2; off = i - N4_IN - N4_OUT - N4_F1;
  }
  f32x4 v = reinterpret_cast<const f32x4*>(src)[off];
  u16x4 o;
#pragma unroll
  for (int j = 0; j < 4; ++j) o[j] = f2bf(v[j]);
  reinterpret_cast<u16x4*>(dst)[i] = o;
}

// ---------------- fp32 -> bf16 hi/lo split (w1) ----------------
__global__ __launch_bounds__(256) void cvt_hilo(const float* __restrict__ in,
                                                u16* __restrict__ hi,
                                                u16* __restrict__ lo, int n4) {
  int i = blockIdx.x * 256 + threadIdx.x;
  if (i >= n4) return;
  f32x4 v = reinterpret_cast<const f32x4*>(in)[i];
  u16x4 oh, ol;
#pragma unroll
  for (int j = 0; j < 4; ++j) {
    u16 h = f2bf(v[j]);
    oh[j] = h;
    ol[j] = f2bf(v[j] - bf2f(h));
  }
  reinterpret_cast<u16x4*>(hi)[i] = oh;
  reinterpret_cast<u16x4*>(lo)[i] = ol;
}

// ------- both transposes [C,S]->[S,C] in one dispatch, fused agent hi/lo -----
__global__ __launch_bounds__(256) void transpose_cs(const float* __restrict__ f_ir,
                                                    const float* __restrict__ f_vis,
                                                    float* __restrict__ x0,
                                                    u16* __restrict__ Ahi,
                                                    u16* __restrict__ Alo) {
  __shared__ float tile[32][33];
  int bz = blockIdx.z;
  int b = bz & 7, which = bz >> 3;
  const float* in = which ? f_vis : f_ir;
  float* out = x0 + (size_t)which * M * C;
  int coff = which ? C : 0;
  int s0 = blockIdx.x * 32, c0 = blockIdx.y * 32;
  const float* ip = in + (size_t)b * C * S;
  float* op = out + (size_t)b * S * C;
  int tx = threadIdx.x, ty = threadIdx.y;   // 32 x 8
#pragma unroll
  for (int i = 0; i < 32; i += 8)
    tile[ty + i][tx] = ip[(size_t)(c0 + ty + i) * S + s0 + tx];
  __syncthreads();
#pragma unroll
  for (int i = 0; i < 32; i += 8) {
    int s = s0 + ty + i;
    float v = tile[tx][ty + i];
    op[(size_t)s * C + c0 + tx] = v;
    u16 hb = f2bf(v);
    size_t am = (size_t)(b * S + s) * K2C + coff + c0 + tx;
    Ahi[am] = hb;
    Alo[am] = f2bf(v - bf2f(hb));
  }
}

// ---------------- bf16 MFMA GEMM helpers (swizzled global_load_lds) ----------
__device__ inline void stage_tile(const u16* __restrict__ g, int ldk,
                                  u16* lds, int tid) {
  int w = tid >> 6, l = tid & 63;
#pragma unroll
  for (int i = 0; i < 4; ++i) {
    int lin = i * 4096 + w * 1024 + l * 16;   // byte within 16KB tile
    int row = lin >> 7;                        // 128B per row (64 bf16)
    int slot = (lin >> 4) & 7;
    int k = (slot ^ (row & 7)) * 8;            // inverse-swizzled source
    const u16* gp = g + (size_t)row * ldk + k;
    u16* lp = lds + i * 2048 + w * 512;        // wave-uniform dest (elements)
    __builtin_amdgcn_global_load_lds(
        (const __attribute__((address_space(1))) unsigned int*)gp,
        (__attribute__((address_space(3))) unsigned int*)lp, 16, 0, 0);
  }
}

__device__ inline short8 frag_ld(const u16* lds, int row, int slot) {
  int s = slot ^ (row & 7);
  return *reinterpret_cast<const short8*>(lds + row * 64 + s * 8);
}

// out[M,N] = A[M,K](bf16) * W[N,K]^T(bf16); 128x128 tile, BK=64, 4 waves 2x2.
// MODE 0: +bias -> bf16. MODE 1: +bias, GELU -> bf16. MODE 2: +bias += fp32 xres.
template <int MODE>
__global__ __launch_bounds__(256) void gemm_bf16(const u16* __restrict__ A,
                                                 const u16* __restrict__ W,
                                                 const float* __restrict__ bias,
                                                 float* __restrict__ xres,
                                                 u16* __restrict__ obf,
                                                 int N, int K,
                                                 int zsA, int zsW, int zsB, int zsO) {
  __shared__ u16 Asb[128 * 64];
  __shared__ u16 Wsb[128 * 64];
  int z = blockIdx.z;
  if (z) {
    A += (size_t)z * zsA;
    W += (size_t)z * zsW;
    bias += (size_t)z * zsB;
    if (MODE == 2) xres += (size_t)z * zsO;
    else obf += (size_t)z * zsO;
  }
  int tid = threadIdx.x;
  int wave = tid >> 6, lane = tid & 63, lo = lane & 15, hi = lane >> 4;
  int wr = wave >> 1, wc = wave & 1;
  int bn = blockIdx.x * 128, bm = blockIdx.y * 128;
  const u16* Ag = A + (size_t)bm * K;
  const u16* Wg = W + (size_t)bn * K;
  f32x4 acc[4][4] = {};
  for (int k0 = 0; k0 < K; k0 += 64) {
    stage_tile(Ag + k0, K, Asb, tid);
    stage_tile(Wg + k0, K, Wsb, tid);
    __syncthreads();
#pragma unroll
    for (int ks = 0; ks < 2; ++ks) {
      short8 a[4], b[4];
#pragma unroll
      for (int mi = 0; mi < 4; ++mi) a[mi] = frag_ld(Asb, wr * 64 + mi * 16 + lo, ks * 4 + hi);
#pragma unroll
      for (int nj = 0; nj < 4; ++nj) b[nj] = frag_ld(Wsb, wc * 64 + nj * 16 + lo, ks * 4 + hi);
#pragma unroll
      for (int mi = 0; mi < 4; ++mi)
#pragma unroll
        for (int nj = 0; nj < 4; ++nj)
          acc[mi][nj] = __builtin_amdgcn_mfma_f32_16x16x32_bf16(a[mi], b[nj], acc[mi][nj], 0, 0, 0);
    }
    __syncthreads();
  }
  float bv[4];
#pragma unroll
  for (int nj = 0; nj < 4; ++nj) bv[nj] = bias[bn + wc * 64 + nj * 16 + lo];
#pragma unroll
  for (int mi = 0; mi < 4; ++mi) {
#pragma unroll
    for (int r = 0; r < 4; ++r) {
      int m = bm + wr * 64 + mi * 16 + hi * 4 + r;
#pragma unroll
      for (int nj = 0; nj < 4; ++nj) {
        int n = bn + wc * 64 + nj * 16 + lo;
        float v = acc[mi][nj][r] + bv[nj];
        size_t idx = (size_t)m * N + n;
        if (MODE == 0) {
          obf[idx] = f2bf(v);
        } else if (MODE == 1) {
          v = 0.5f * v * (1.f + erff(v * 0.70710678f));
          obf[idx] = f2bf(v);
        } else {
          xres[idx] += v;
        }
      }
    }
  }
}

// ---------------- agent fused 3-pass GEMM: SiLU(xh*wh + xh*wl + xl*wh + b1) ----
__global__ __launch_bounds__(256) void gemm_agent(const u16* __restrict__ Ahi,
                                                  const u16* __restrict__ Alo,
                                                  const u16* __restrict__ w1hi,
                                                  const u16* __restrict__ w1lo,
                                                  const float* __restrict__ b1,
                                                  float* __restrict__ hid) {
  __shared__ u16 Asb[128 * 64];
  __shared__ u16 Wsb[128 * 64];
  int tid = threadIdx.x;
  int wave = tid >> 6, lane = tid & 63, lo = lane & 15, hi = lane >> 4;
  int wr = wave >> 1, wc = wave & 1;
  int bn = blockIdx.x * 128, bm = blockIdx.y * 128;
  const u16* Alist[3] = {Ahi, Ahi, Alo};
  const u16* Wlist[3] = {w1hi, w1lo, w1hi};
  f32x4 acc[4][4] = {};
  for (int p = 0; p < 3; ++p) {
    const u16* Ag = Alist[p] + (size_t)bm * K2C;
    const u16* Wg = Wlist[p] + (size_t)bn * K2C;
    for (int k0 = 0; k0 < K2C; k0 += 64) {
      stage_tile(Ag + k0, K2C, Asb, tid);
      stage_tile(Wg + k0, K2C, Wsb, tid);
      __syncthreads();
#pragma unroll
      for (int ks = 0; ks < 2; ++ks) {
        short8 a[4], b[4];
#pragma unroll
        for (int mi = 0; mi < 4; ++mi) a[mi] = frag_ld(Asb, wr * 64 + mi * 16 + lo, ks * 4 + hi);
#pragma unroll
        for (int nj = 0; nj < 4; ++nj) b[nj] = frag_ld(Wsb, wc * 64 + nj * 16 + lo, ks * 4 + hi);
#pragma unroll
        for (int mi = 0; mi < 4; ++mi)
#pragma unroll
          for (int nj = 0; nj < 4; ++nj)
            acc[mi][nj] = __builtin_amdgcn_mfma_f32_16x16x32_bf16(a[mi], b[nj], acc[mi][nj], 0, 0, 0);
      }
      __syncthreads();
    }
  }
  float bv[4];
#pragma unroll
  for (int nj = 0; nj < 4; ++nj) bv[nj] = b1[bn + wc * 64 + nj * 16 + lo];
#pragma unroll
  for (int mi = 0; mi < 4; ++mi) {
#pragma unroll
    for (int r = 0; r < 4; ++r) {
      int m = bm + wr * 64 + mi * 16 + hi * 4 + r;
#pragma unroll
      for (int nj = 0; nj < 4; ++nj) {
        int n = bn + wc * 64 + nj * 16 + lo;
        float v = acc[mi][nj][r] + bv[nj];
        hid[(size_t)m * HID + n] = v / (1.f + expf(-v));  // SiLU
      }
    }
  }
}

// ---------------- agent logit + threshold + ambiguity list ----------------
__global__ __launch_bounds__(64) void sel_kernel(const float* __restrict__ hidden,
                                                 const float* __restrict__ w2,
                                                 const float* __restrict__ b2,
                                                 int* __restrict__ sel,
                                                 int* __restrict__ ctr,
                                                 int* __restrict__ list) {
  int row = blockIdx.x, t = threadIdx.x;
  const float* hr = hidden + (size_t)row * HID;
  float s = 0.f;
#pragma unroll
  for (int i = 0; i < HID / 64; ++i) s += hr[t + i * 64] * w2[t + i * 64];
  for (int off = 32; off; off >>= 1) s += __shfl_down(s, off);
  if (t == 0) {
    float logit = s + b2[0];
    sel[row] = logit > 0.f ? 1 : 0;
    if (fabsf(logit) < 1e-3f) {
      int idx = atomicAdd(ctr, 1);
      if (idx < FIXCAP) list[idx] = row;
    }
  }
}

// ---------------- exact fp32 recompute of ambiguous rows ----------------
__global__ __launch_bounds__(256) void fixup_kernel(const float* __restrict__ x0,
                                                    const float* __restrict__ x1,
                                                    const float* __restrict__ w1,
                                                    const float* __restrict__ b1,
                                                    const float* __restrict__ w2,
                                                    const float* __restrict__ b2,
                                                    const int* __restrict__ ctr,
                                                    const int* __restrict__ list,
                                                    int* __restrict__ sel) {
  __shared__ float xs[K2C];
  __shared__ float red[4];
  int cnt = ctr[0];
  if (cnt > FIXCAP) cnt = FIXCAP;
  int tid = threadIdx.x;
  for (int ii = blockIdx.x; ii < cnt; ii += gridDim.x) {
    int row = list[ii];
    for (int k = tid; k < C; k += 256) {
      xs[k] = x0[(size_t)row * C + k];
      xs[C + k] = x1[(size_t)row * C + k];
    }
    __syncthreads();
    float partial = 0.f;
#pragma unroll
    for (int u = 0; u < 2; ++u) {
      int n = tid + u * 256;
      const float* wr = w1 + (size_t)n * K2C;
      float acc = 0.f;
      for (int k = 0; k < K2C; ++k) acc = fmaf(wr[k], xs[k], acc);
      acc += b1[n];
      acc = acc / (1.f + expf(-acc));  // SiLU
      partial = fmaf(acc, w2[n], partial);
    }
    for (int off = 32; off; off >>= 1) partial += __shfl_down(partial, off);
    if ((tid & 63) == 0) red[tid >> 6] = partial;
    __syncthreads();
    if (tid == 0) {
      float logit = red[0] + red[1] + red[2] + red[3] + b2[0];
      sel[row] = logit > 0.f ? 1 : 0;
    }
    __syncthreads();
  }
}

// ---------------- batched LayerNorm over C=384 -> bf16, one wave per row ------
__global__ __launch_bounds__(64) void ln_kernel(const float* __restrict__ x,
                                                const float* __restrict__ g_all,
                                                const float* __restrict__ b_all,
                                                u16* __restrict__ y) {
  int row = blockIdx.x, t = threadIdx.x;
  int strm = row >> 13;  // row / M
  const float* g = g_all + strm * C;
  const float* bt = b_all + strm * C;
  const float* xr = x + (size_t)row * C;
  float v[C / 64];
  float s = 0.f, s2 = 0.f;
#pragma unroll
  for (int i = 0; i < C / 64; ++i) {
    float a = xr[t + i * 64];
    v[i] = a;
    s += a;
    s2 += a * a;
  }
  for (int off = 32; off; off >>= 1) {
    s += __shfl_down(s, off);
    s2 += __shfl_down(s2, off);
  }
  s = __shfl(s, 0);
  s2 = __shfl(s2, 0);
  float mean = s / C;
  float var = s2 / C - mean * mean;
  float inv = rsqrtf(var + 1e-5f);
#pragma unroll
  for (int i = 0; i < C / 64; ++i) {
    int c = t + i * 64;
    y[(size_t)row * C + c] = f2bf((v[i] - mean) * inv * g[c] + bt[c]);
  }
}

// ---------------- flash MFMA attention v4 -------------------------------------
// QBLK=128 (2 q-subtiles per wave; K/V LDS reads shared across subtiles),
// KT=64, async reg-staged K/V (global loads for tile t+1 issued before compute
// of tile t; LDS writes after the post-compute barrier), defer-max, P in regs.
__global__ __launch_bounds__(256) void attn_mfma(const u16* __restrict__ qkv,
                                                 const int* __restrict__ sel,
                                                 u16* __restrict__ o_out) {
  __shared__ u16 Ks[64][104];
  __shared__ u16 Vt[96][72];
  __shared__ float msk[S];

  int bq0 = blockIdx.x * 128;
  int bh2 = blockIdx.y;                  // 64 = 2 streams x 8 b x 4 h
  int strm = bh2 >> 5, bh = bh2 & 31;
  int b = bh >> 2, h = bh & 3;
  qkv += (size_t)strm * M * C3;
  o_out += (size_t)strm * M * C;
  int tid = threadIdx.x;
  int wave = tid >> 6, lane = tid & 63;
  int lo = lane & 15, g = lane >> 4;

  const int* selb = sel + b * S;
#pragma unroll
  for (int i = 0; i < 4; ++i) {
    int k = i * 256 + tid;
    msk[k] = selb[k] ? 0.f : -1e9f;
  }

  // Q fragments in registers (2 subtiles), pre-scaled by 1/sqrt(HD)
  const float scale = 0.1020620726f;
  short8 bq[2][3];
#pragma unroll
  for (int su = 0; su < 2; ++su) {
    const u16* qrow =
        qkv + ((size_t)(b * S + bq0 + su * 64 + wave * 16 + lo)) * C3 + h * HD;
#pragma unroll
    for (int c = 0; c < 3; ++c) {
      short8 q = *reinterpret_cast<const short8*>(qrow + c * 32 + g * 8);
      short8 r;
#pragma unroll
      for (int e = 0; e < 8; ++e) r[e] = (short)f2bf(bf2f((u16)q[e]) * scale);
      bq[su][c] = r;
    }
  }

  float m[2] = {-30.f, -30.f}, l[2] = {0.f, 0.f};
  f32x4 o[2][6] = {};
  short8 kr[3], vr[3];

  const u16* kb0 = qkv + (size_t)b * S * C3 + C + h * HD;
  const u16* vb0 = qkv + (size_t)b * S * C3 + 2 * C + h * HD;

  // prologue: load + write tile 0
#pragma unroll
  for (int i = 0; i < 3; ++i) {
    int idx = i * 256 + tid;
    int kr_ = idx / 12, kj = idx - kr_ * 12;
    kr[i] = *reinterpret_cast<const short8*>(kb0 + (size_t)kr_ * C3 + kj * 8);
    int vrw = idx & 63, vj = idx >> 6;
    vr[i] = *reinterpret_cast<const short8*>(vb0 + (size_t)vrw * C3 + vj * 8);
  }
#pragma unroll
  for (int i = 0; i < 3; ++i) {
    int idx = i * 256 + tid;
    int kr_ = idx / 12, kj = idx - kr_ * 12;
    *reinterpret_cast<short8*>(&Ks[kr_][kj * 8]) = kr[i];
    int vrw = idx & 63, vj = idx >> 6;
#pragma unroll
    for (int e = 0; e < 8; ++e) Vt[vj * 8 + e][vrw] = (u16)vr[i][e];
  }
  __syncthreads();

  for (int kt0 = 0; kt0 < S; kt0 += 64) {
    bool haveNext = (kt0 + 64 < S);
    if (haveNext) {
      const u16* kbase = kb0 + (size_t)(kt0 + 64) * C3;
      const u16* vbase = vb0 + (size_t)(kt0 + 64) * C3;
#pragma unroll
      for (int i = 0; i < 3; ++i) {
        int idx = i * 256 + tid;
        int kr_ = idx / 12, kj = idx - kr_ * 12;
        kr[i] = *reinterpret_cast<const short8*>(kbase + (size_t)kr_ * C3 + kj * 8);
        int vrw = idx & 63, vj = idx >> 6;
        vr[i] = *reinterpret_cast<const short8*>(vbase + (size_t)vrw * C3 + vj * 8);
      }
    }

    // QK^T for both subtiles; K fragments shared
    f32x4 st[2][4] = {};
#pragma unroll
    for (int c = 0; c < 3; ++c)
#pragma unroll
      for (int t4 = 0; t4 < 4; ++t4) {
        short8 ak = *reinterpret_cast<const short8*>(&Ks[t4 * 16 + lo][c * 32 + g * 8]);
        st[0][t4] = __builtin_amdgcn_mfma_f32_16x16x32_bf16(ak, bq[0][c], st[0][t4], 0, 0, 0);
        st[1][t4] = __builtin_amdgcn_mfma_f32_16x16x32_bf16(ak, bq[1][c], st[1][t4], 0, 0, 0);
      }

    // masked softmax per subtile (defer-max), pack P
    short8 bp[2][2];
#pragma unroll
    for (int su = 0; su < 2; ++su) {
      float p[4][4];
      float pmax = -INFINITY;
#pragma unroll
      for (int t4 = 0; t4 < 4; ++t4) {
        f32x4 mk = *reinterpret_cast<const f32x4*>(&msk[kt0 + t4 * 16 + g * 4]);
#pragma unroll
        for (int r = 0; r < 4; ++r) {
          float s = st[su][t4][r] + mk[r];
          p[t4][r] = s;
          pmax = fmaxf(pmax, s);
        }
      }
      pmax = fmaxf(pmax, __shfl_xor(pmax, 16));
      pmax = fmaxf(pmax, __shfl_xor(pmax, 32));
      if (__any(pmax - m[su] > 8.f)) {
        float mn = fmaxf(m[su], pmax);
        float sc = __expf(m[su] - mn);
        m[su] = mn;
        l[su] *= sc;
#pragma unroll
        for (int dt = 0; dt < 6; ++dt)
#pragma unroll
          for (int r = 0; r < 4; ++r) o[su][dt][r] *= sc;
      }
      float ps = 0.f;
#pragma unroll
      for (int t4 = 0; t4 < 4; ++t4)
#pragma unroll
        for (int r = 0; r < 4; ++r) {
          float e = __expf(p[t4][r] - m[su]);
          p[t4][r] = e;
          ps += e;
        }
      ps += __shfl_xor(ps, 16);
      ps += __shfl_xor(ps, 32);
      l[su] += ps;
#pragma unroll
      for (int h2 = 0; h2 < 2; ++h2) {
        union { short8 s8; unsigned int u[4]; } u_;
        u_.u[0] = cvtpk(p[2 * h2][0], p[2 * h2][1]);
        u_.u[1] = cvtpk(p[2 * h2][2], p[2 * h2][3]);
        u_.u[2] = cvtpk(p[2 * h2 + 1][0], p[2 * h2 + 1][1]);
        u_.u[3] = cvtpk(p[2 * h2 + 1][2], p[2 * h2 + 1][3]);
        bp[su][h2] = u_.s8;
      }
    }

    // PV: V^T fragments shared across subtiles
#pragma unroll
    for (int dt = 0; dt < 6; ++dt)
#pragma unroll
      for (int h2 = 0; h2 < 2; ++h2) {
        union { short8 s8; short4 s4[2]; } a_;
        a_.s4[0] = *reinterpret_cast<const short4*>(&Vt[dt * 16 + lo][h2 * 32 + g * 4]);
        a_.s4[1] = *reinterpret_cast<const short4*>(&Vt[dt * 16 + lo][h2 * 32 + 16 + g * 4]);
        o[0][dt] = __builtin_amdgcn_mfma_f32_16x16x32_bf16(a_.s8, bp[0][h2], o[0][dt], 0, 0, 0);
        o[1][dt] = __builtin_amdgcn_mfma_f32_16x16x32_bf16(a_.s8, bp[1][h2], o[1][dt], 0, 0, 0);
      }
    __syncthreads();

    if (haveNext) {
#pragma unroll
      for (int i = 0; i < 3; ++i) {
        int idx = i * 256 + tid;
        int kr_ = idx / 12, kj = idx - kr_ * 12;
        *reinterpret_cast<short8*>(&Ks[kr_][kj * 8]) = kr[i];
        int vrw = idx & 63, vj = idx >> 6;
#pragma unroll
        for (int e = 0; e < 8; ++e) Vt[vj * 8 + e][vrw] = (u16)vr[i][e];
      }
    }
    __syncthreads();
  }

#pragma unroll
  for (int su = 0; su < 2; ++su) {
    float inv = 1.f / l[su];
    size_t orow =
        ((size_t)(b * S + bq0 + su * 64 + wave * 16 + lo)) * C + h * HD;
#pragma unroll
    for (int dt = 0; dt < 6; ++dt)
#pragma unroll
      for (int r = 0; r < 4; ++r)
        o_out[orow + dt * 16 + g * 4 + r] = f2bf(o[su][dt][r] * inv);
  }
}

// ---------------- final scatter, LDS-tiled transpose ----------------
__global__ __launch_bounds__(256) void final_kernel(const float* __restrict__ x0,
                                                    const float* __restrict__ x1,
                                                    const int* __restrict__ sel,
                                                    const float* __restrict__ f_ir,
                                                    const float* __restrict__ f_vis,
                                                    float* __restrict__ out) {
  __shared__ float tile[32][33];
  int b = blockIdx.z;
  int s0 = blockIdx.x * 32, c0 = blockIdx.y * 32;
  int tx = threadIdx.x, ty = threadIdx.y;  // 32 x 8
#pragma unroll
  for (int i = 0; i < 32; i += 8) {
    size_t r = ((size_t)(b * S + s0 + ty + i)) * C + c0 + tx;
    tile[ty + i][tx] = x0[r] + x1[r];
  }
  __syncthreads();
  const int* selb = sel + b * S;
#pragma unroll
  for (int i = 0; i < 32; i += 8) {
    int c = c0 + ty + i, s = s0 + tx;
    size_t idx = ((size_t)(b * C + c)) * S + s;
    float v = selb[s] ? tile[tx][ty + i] : (f_ir[idx] + f_vis[idx]);
    out[idx] = v;
  }
}

}  // namespace

extern "C" void kernel_launch(void* const* d_in, const int* in_sizes, int n_in,
                              void* d_out, int out_size, void* d_ws, size_t ws_size,
                              hipStream_t stream) {
  const float* f_ir = (const float*)d_in[0];
  const float* f_vis = (const float*)d_in[1];
  const float* agent_w1 = (const float*)d_in[2];
  const float* agent_b1 = (const float*)d_in[3];
  const float* agent_w2 = (const float*)d_in[4];
  const float* agent_b2 = (const float*)d_in[5];
  const float* norm_g = (const float*)d_in[6];
  const float* norm_b = (const float*)d_in[7];
  const float* in_w = (const float*)d_in[8];
  const float* in_b = (const float*)d_in[9];
  const float* out_w = (const float*)d_in[10];
  const float* out_b = (const float*)d_in[11];
  const float* ffn_w1 = (const float*)d_in[12];
  const float* ffn_b1 = (const float*)d_in[13];
  const float* ffn_w2 = (const float*)d_in[14];
  const float* ffn_b2 = (const float*)d_in[15];
  float* out = (float*)d_out;

  constexpr size_t MS = (size_t)M * C;
  float* ws = (float*)d_ws;
  float* x0 = ws;                                  // fp32 [2M,C]: x0 | x1
  u16* Dbf = (u16*)(x0 + 2 * MS);                  // [2M,C]  xn / attn_o (bf16)
  u16* qkvb = Dbf + 2 * MS;                        // [2M,C3] qkv (bf16)
  u16* Hext = qkvb + (size_t)2 * M * C3;           // [M,FFN] u16 extension
  u16* wb_in = Hext + (size_t)M * FFN;             // 2*C3*C
  u16* wb_out = wb_in + 2 * C3 * C;                // 2*C*C
  u16* wb_f1 = wb_out + 2 * C * C;                 // 2*FFN*C
  u16* wb_f2 = wb_f1 + 2 * FFN * C;                // 2*C*FFN
  u16* w1hi = wb_f2 + 2 * C * FFN;                 // 512*768
  u16* w1lo = w1hi + HID * K2C;                    // 512*768
  int* sel = (int*)(w1lo + HID * K2C);
  int* ctr = sel + M;
  int* fixlist = ctr + 1;
  // aliases (each dead before its host region is rewritten)
  u16* Ahi = qkvb;                                 // [M,768]  (dead before QKV)
  u16* Alo = qkvb + (size_t)M * K2C;               // [M,768]
  float* hiddenF = (float*)Hext;                   // [M,HID] fp32 (dead before FFN)
  u16* Hbf = qkvb;                                 // FFN hidden [2M,FFN] spans qkvb+Hext
  float* x1 = x0 + MS;

  // 0) weights -> bf16 (one dispatch; also zeroes fixup ctr) + w1 hi/lo split
  cvt_all<<<(N4_ALL + 255) / 256, 256, 0, stream>>>(in_w, out_w, ffn_w1, ffn_w2,
                                                    wb_in, ctr);
  cvt_hilo<<<(HID * K2C / 4 + 255) / 256, 256, 0, stream>>>(agent_w1, w1hi, w1lo,
                                                            HID * K2C / 4);

  // 1) both transposes in one dispatch (fused agent hi/lo activation emit)
  transpose_cs<<<dim3(S / 32, C / 32, 2 * B), dim3(32, 8), 0, stream>>>(
      f_ir, f_vis, x0, Ahi, Alo);

  // 2) agent hidden via fused bf16x3 MFMA + SiLU
  gemm_agent<<<dim3(HID / 128, M / 128), 256, 0, stream>>>(Ahi, Alo, w1hi, w1lo,
                                                           agent_b1, hiddenF);

  // 3) selection mask + exact fp32 fixup of near-zero logits
  sel_kernel<<<M, 64, 0, stream>>>(hiddenF, agent_w2, agent_b2, sel, ctr, fixlist);
  fixup_kernel<<<64, 256, 0, stream>>>(x0, x1, agent_w1, agent_b1, agent_w2,
                                       agent_b2, ctr, fixlist, sel);

  // 4) mixer, both streams batched end-to-end
  ln_kernel<<<2 * M, 64, 0, stream>>>(x0, norm_g, norm_b, Dbf);
  gemm_bf16<0><<<dim3(C3 / 128, M / 128, 2), 256, 0, stream>>>(
      Dbf, wb_in, in_b, nullptr, qkvb, C3, C, M * C, C3 * C, C3, M * C3);
  attn_mfma<<<dim3(S / 128, B * HEADS * 2), 256, 0, stream>>>(qkvb, sel, Dbf);
  gemm_bf16<2><<<dim3(C / 128, M / 128, 2), 256, 0, stream>>>(
      Dbf, wb_out, out_b, x0, nullptr, C, C, M * C, C * C, C, M * C);
  ln_kernel<<<2 * M, 64, 0, stream>>>(x0, norm_g, norm_b, Dbf);
  gemm_bf16<1><<<dim3(FFN / 128, M / 128, 2), 256, 0, stream>>>(
      Dbf, wb_f1, ffn_b1, nullptr, Hbf, FFN, C, M * C, FFN * C, FFN, M * FFN);
  gemm_bf16<2><<<dim3(C / 128, M / 128, 2), 256, 0, stream>>>(
      Hbf, wb_f2, ffn_b2, x0, nullptr, C, FFN, M * FFN, C * FFN, C, M * C);

  // 5) final scatter back to [B,C,H,W]
  final_kernel<<<dim3(S / 32, C / 32, B), dim3(32, 8), 0, stream>>>(
      x0, x1, sel, f_ir, f_vis, out);
}

// Round 12
// 340.894 us; speedup vs baseline: 17.3420x; 1.0892x over previous
//
#include <hip/hip_runtime.h>
#include <math.h>

namespace {

constexpr int B = 8, C = 384, S = 1024;
constexpr int HID = 512, HEADS = 4, HD = 96, FFN = 1536;
constexpr int M = B * S;          // 8192 rows
constexpr int C3 = 3 * C;         // 1152
constexpr int K2C = 2 * C;        // 768 (agent K)
constexpr int FIXCAP = 4096;

using u16 = unsigned short;
using short8 = __attribute__((ext_vector_type(8))) short;
using short4 = __attribute__((ext_vector_type(4))) short;
using f32x4 = __attribute__((ext_vector_type(4))) float;
using u16x4 = __attribute__((ext_vector_type(4))) unsigned short;

__device__ inline u16 f2bf(float f) {
  unsigned int u = __builtin_bit_cast(unsigned int, f);
  u += 0x7fffu + ((u >> 16) & 1u);
  return (u16)(u >> 16);
}
__device__ inline float bf2f(u16 h) {
  unsigned int u = ((unsigned int)h) << 16;
  return __builtin_bit_cast(float, u);
}
__device__ inline unsigned int cvtpk(float a, float b) {  // [bf16(b)<<16 | bf16(a)]
  unsigned int r;
  asm("v_cvt_pk_bf16_f32 %0, %1, %2" : "=v"(r) : "v"(a), "v"(b));
  return r;
}

// ------- all mixer weights -> bf16 in one dispatch; also zeroes fixup ctr ----
constexpr int N4_IN = 2 * C3 * C / 4;
constexpr int N4_OUT = 2 * C * C / 4;
constexpr int N4_F1 = 2 * FFN * C / 4;
constexpr int N4_F2 = 2 * C * FFN / 4;
constexpr int N4_ALL = N4_IN + N4_OUT + N4_F1 + N4_F2;

__global__ __launch_bounds__(256) void cvt_all(const float* __restrict__ in_w,
                                               const float* __restrict__ out_w,
                                               const float* __restrict__ f1,
                                               const float* __restrict__ f2,
                                               u16* __restrict__ dst,
                                               int* __restrict__ ctr) {
  int i = blockIdx.x * 256 + threadIdx.x;
  if (i == 0) ctr[0] = 0;
  if (i >= N4_ALL) return;
  const float* src;
  int off = i;
  if (i < N4_IN) {
    src = in_w;
  } else if (i < N4_IN + N4_OUT) {
    src = out_w; off = i - N4_IN;
  } else if (i < N4_IN + N4_OUT + N4_F1) {
    src = f1; off = i - N4_IN - N4_OUT;
  } else {
    src = f2; off = i - N4_IN - N4_OUT - N4_F1;
  }
  f32x4 v = reinterpret_cast<const f32x4*>(src)[off];
  u16x4 o;
#pragma unroll
  for (int j = 0; j < 4; ++j) o[j] = f2bf(v[j]);
  reinterpret_cast<u16x4*>(dst)[i] = o;
}

// ---------------- fp32 -> bf16 hi/lo split (w1) ----------------
__global__ __launch_bounds__(256) void cvt_hilo(const float* __restrict__ in,
                                                u16* __restrict__ hi,
                                                u16* __restrict__ lo, int n4) {
  int i = blockIdx.x * 256 + threadIdx.x;
  if (i >= n4) return;
  f32x4 v = reinterpret_cast<const f32x4*>(in)[i];
  u16x4 oh, ol;
#pragma unroll
  for (int j = 0; j < 4; ++j) {
    u16 h = f2bf(v[j]);
    oh[j] = h;
    ol[j] = f2bf(v[j] - bf2f(h));
  }
  reinterpret_cast<u16x4*>(hi)[i] = oh;
  reinterpret_cast<u16x4*>(lo)[i] = ol;
}

// ------- both transposes [C,S]->[S,C] in one dispatch, fused agent hi/lo -----
__global__ __launch_bounds__(256) void transpose_cs(const float* __restrict__ f_ir,
                                                    const float* __restrict__ f_vis,
                                                    float* __restrict__ x0,
                                                    u16* __restrict__ Ahi,
                                                    u16* __restrict__ Alo) {
  __shared__ float tile[32][33];
  int bz = blockIdx.z;
  int b = bz & 7, which = bz >> 3;
  const float* in = which ? f_vis : f_ir;
  float* out = x0 + (size_t)which * M * C;
  int coff = which ? C : 0;
  int s0 = blockIdx.x * 32, c0 = blockIdx.y * 32;
  const float* ip = in + (size_t)b * C * S;
  float* op = out + (size_t)b * S * C;
  int tx = threadIdx.x, ty = threadIdx.y;   // 32 x 8
#pragma unroll
  for (int i = 0; i < 32; i += 8)
    tile[ty + i][tx] = ip[(size_t)(c0 + ty + i) * S + s0 + tx];
  __syncthreads();
#pragma unroll
  for (int i = 0; i < 32; i += 8) {
    int s = s0 + ty + i;
    float v = tile[tx][ty + i];
    op[(size_t)s * C + c0 + tx] = v;
    u16 hb = f2bf(v);
    size_t am = (size_t)(b * S + s) * K2C + coff + c0 + tx;
    Ahi[am] = hb;
    Alo[am] = f2bf(v - bf2f(hb));
  }
}

// ---------------- bf16 MFMA GEMM helpers (swizzled global_load_lds) ----------
__device__ inline void stage_tile(const u16* __restrict__ g, int ldk,
                                  u16* lds, int tid) {
  int w = tid >> 6, l = tid & 63;
#pragma unroll
  for (int i = 0; i < 4; ++i) {
    int lin = i * 4096 + w * 1024 + l * 16;   // byte within 16KB tile
    int row = lin >> 7;                        // 128B per row (64 bf16)
    int slot = (lin >> 4) & 7;
    int k = (slot ^ (row & 7)) * 8;            // inverse-swizzled source
    const u16* gp = g + (size_t)row * ldk + k;
    u16* lp = lds + i * 2048 + w * 512;        // wave-uniform dest (elements)
    __builtin_amdgcn_global_load_lds(
        (const __attribute__((address_space(1))) unsigned int*)gp,
        (__attribute__((address_space(3))) unsigned int*)lp, 16, 0, 0);
  }
}

__device__ inline short8 frag_ld(const u16* lds, int row, int slot) {
  int s = slot ^ (row & 7);
  return *reinterpret_cast<const short8*>(lds + row * 64 + s * 8);
}

// out[M,N] = A[M,K](bf16) * W[N,K]^T(bf16); 128x128 tile, BK=64, 4 waves 2x2.
// MODE 0: +bias -> bf16. MODE 1: +bias, GELU -> bf16. MODE 2: +bias += fp32 xres.
template <int MODE>
__global__ __launch_bounds__(256) void gemm_bf16(const u16* __restrict__ A,
                                                 const u16* __restrict__ W,
                                                 const float* __restrict__ bias,
                                                 float* __restrict__ xres,
                                                 u16* __restrict__ obf,
                                                 int N, int K,
                                                 int zsA, int zsW, int zsB, int zsO) {
  __shared__ u16 Asb[128 * 64];
  __shared__ u16 Wsb[128 * 64];
  int z = blockIdx.z;
  if (z) {
    A += (size_t)z * zsA;
    W += (size_t)z * zsW;
    bias += (size_t)z * zsB;
    if (MODE == 2) xres += (size_t)z * zsO;
    else obf += (size_t)z * zsO;
  }
  int tid = threadIdx.x;
  int wave = tid >> 6, lane = tid & 63, lo = lane & 15, hi = lane >> 4;
  int wr = wave >> 1, wc = wave & 1;
  int bn = blockIdx.x * 128, bm = blockIdx.y * 128;
  const u16* Ag = A + (size_t)bm * K;
  const u16* Wg = W + (size_t)bn * K;
  f32x4 acc[4][4] = {};
  for (int k0 = 0; k0 < K; k0 += 64) {
    stage_tile(Ag + k0, K, Asb, tid);
    stage_tile(Wg + k0, K, Wsb, tid);
    __syncthreads();
#pragma unroll
    for (int ks = 0; ks < 2; ++ks) {
      short8 a[4], b[4];
#pragma unroll
      for (int mi = 0; mi < 4; ++mi) a[mi] = frag_ld(Asb, wr * 64 + mi * 16 + lo, ks * 4 + hi);
#pragma unroll
      for (int nj = 0; nj < 4; ++nj) b[nj] = frag_ld(Wsb, wc * 64 + nj * 16 + lo, ks * 4 + hi);
#pragma unroll
      for (int mi = 0; mi < 4; ++mi)
#pragma unroll
        for (int nj = 0; nj < 4; ++nj)
          acc[mi][nj] = __builtin_amdgcn_mfma_f32_16x16x32_bf16(a[mi], b[nj], acc[mi][nj], 0, 0, 0);
    }
    __syncthreads();
  }
  float bv[4];
#pragma unroll
  for (int nj = 0; nj < 4; ++nj) bv[nj] = bias[bn + wc * 64 + nj * 16 + lo];
#pragma unroll
  for (int mi = 0; mi < 4; ++mi) {
#pragma unroll
    for (int r = 0; r < 4; ++r) {
      int m = bm + wr * 64 + mi * 16 + hi * 4 + r;
#pragma unroll
      for (int nj = 0; nj < 4; ++nj) {
        int n = bn + wc * 64 + nj * 16 + lo;
        float v = acc[mi][nj][r] + bv[nj];
        size_t idx = (size_t)m * N + n;
        if (MODE == 0) {
          obf[idx] = f2bf(v);
        } else if (MODE == 1) {
          v = 0.5f * v * (1.f + erff(v * 0.70710678f));
          obf[idx] = f2bf(v);
        } else {
          xres[idx] += v;
        }
      }
    }
  }
}

// ---------------- agent fused 3-pass GEMM: SiLU(xh*wh + xh*wl + xl*wh + b1) ----
__global__ __launch_bounds__(256) void gemm_agent(const u16* __restrict__ Ahi,
                                                  const u16* __restrict__ Alo,
                                                  const u16* __restrict__ w1hi,
                                                  const u16* __restrict__ w1lo,
                                                  const float* __restrict__ b1,
                                                  float* __restrict__ hid) {
  __shared__ u16 Asb[128 * 64];
  __shared__ u16 Wsb[128 * 64];
  int tid = threadIdx.x;
  int wave = tid >> 6, lane = tid & 63, lo = lane & 15, hi = lane >> 4;
  int wr = wave >> 1, wc = wave & 1;
  int bn = blockIdx.x * 128, bm = blockIdx.y * 128;
  const u16* Alist[3] = {Ahi, Ahi, Alo};
  const u16* Wlist[3] = {w1hi, w1lo, w1hi};
  f32x4 acc[4][4] = {};
  for (int p = 0; p < 3; ++p) {
    const u16* Ag = Alist[p] + (size_t)bm * K2C;
    const u16* Wg = Wlist[p] + (size_t)bn * K2C;
    for (int k0 = 0; k0 < K2C; k0 += 64) {
      stage_tile(Ag + k0, K2C, Asb, tid);
      stage_tile(Wg + k0, K2C, Wsb, tid);
      __syncthreads();
#pragma unroll
      for (int ks = 0; ks < 2; ++ks) {
        short8 a[4], b[4];
#pragma unroll
        for (int mi = 0; mi < 4; ++mi) a[mi] = frag_ld(Asb, wr * 64 + mi * 16 + lo, ks * 4 + hi);
#pragma unroll
        for (int nj = 0; nj < 4; ++nj) b[nj] = frag_ld(Wsb, wc * 64 + nj * 16 + lo, ks * 4 + hi);
#pragma unroll
        for (int mi = 0; mi < 4; ++mi)
#pragma unroll
          for (int nj = 0; nj < 4; ++nj)
            acc[mi][nj] = __builtin_amdgcn_mfma_f32_16x16x32_bf16(a[mi], b[nj], acc[mi][nj], 0, 0, 0);
      }
      __syncthreads();
    }
  }
  float bv[4];
#pragma unroll
  for (int nj = 0; nj < 4; ++nj) bv[nj] = b1[bn + wc * 64 + nj * 16 + lo];
#pragma unroll
  for (int mi = 0; mi < 4; ++mi) {
#pragma unroll
    for (int r = 0; r < 4; ++r) {
      int m = bm + wr * 64 + mi * 16 + hi * 4 + r;
#pragma unroll
      for (int nj = 0; nj < 4; ++nj) {
        int n = bn + wc * 64 + nj * 16 + lo;
        float v = acc[mi][nj][r] + bv[nj];
        hid[(size_t)m * HID + n] = v / (1.f + expf(-v));  // SiLU
      }
    }
  }
}

// ---------------- agent logit + threshold + ambiguity list ----------------
__global__ __launch_bounds__(64) void sel_kernel(const float* __restrict__ hidden,
                                                 const float* __restrict__ w2,
                                                 const float* __restrict__ b2,
                                                 int* __restrict__ sel,
                                                 int* __restrict__ ctr,
                                                 int* __restrict__ list) {
  int row = blockIdx.x, t = threadIdx.x;
  const float* hr = hidden + (size_t)row * HID;
  float s = 0.f;
#pragma unroll
  for (int i = 0; i < HID / 64; ++i) s += hr[t + i * 64] * w2[t + i * 64];
  for (int off = 32; off; off >>= 1) s += __shfl_down(s, off);
  if (t == 0) {
    float logit = s + b2[0];
    sel[row] = logit > 0.f ? 1 : 0;
    if (fabsf(logit) < 1e-3f) {
      int idx = atomicAdd(ctr, 1);
      if (idx < FIXCAP) list[idx] = row;
    }
  }
}

// ---------------- exact fp32 recompute of ambiguous rows ----------------
__global__ __launch_bounds__(256) void fixup_kernel(const float* __restrict__ x0,
                                                    const float* __restrict__ x1,
                                                    const float* __restrict__ w1,
                                                    const float* __restrict__ b1,
                                                    const float* __restrict__ w2,
                                                    const float* __restrict__ b2,
                                                    const int* __restrict__ ctr,
                                                    const int* __restrict__ list,
                                                    int* __restrict__ sel) {
  __shared__ float xs[K2C];
  __shared__ float red[4];
  int cnt = ctr[0];
  if (cnt > FIXCAP) cnt = FIXCAP;
  int tid = threadIdx.x;
  for (int ii = blockIdx.x; ii < cnt; ii += gridDim.x) {
    int row = list[ii];
    for (int k = tid; k < C; k += 256) {
      xs[k] = x0[(size_t)row * C + k];
      xs[C + k] = x1[(size_t)row * C + k];
    }
    __syncthreads();
    float partial = 0.f;
#pragma unroll
    for (int u = 0; u < 2; ++u) {
      int n = tid + u * 256;
      const float* wr = w1 + (size_t)n * K2C;
      float acc = 0.f;
      for (int k = 0; k < K2C; ++k) acc = fmaf(wr[k], xs[k], acc);
      acc += b1[n];
      acc = acc / (1.f + expf(-acc));  // SiLU
      partial = fmaf(acc, w2[n], partial);
    }
    for (int off = 32; off; off >>= 1) partial += __shfl_down(partial, off);
    if ((tid & 63) == 0) red[tid >> 6] = partial;
    __syncthreads();
    if (tid == 0) {
      float logit = red[0] + red[1] + red[2] + red[3] + b2[0];
      sel[row] = logit > 0.f ? 1 : 0;
    }
    __syncthreads();
  }
}

// ---------------- per-batch exclusive prefix scan of sel ----------------
__global__ __launch_bounds__(256) void prefix_kernel(const int* __restrict__ sel,
                                                     int* __restrict__ pos,
                                                     int* __restrict__ nsel) {
  __shared__ int wsum[4];
  int b = blockIdx.x, tid = threadIdx.x;
  int lane = tid & 63, wv = tid >> 6;
  int v[4], lp[4];
  int tot = 0;
#pragma unroll
  for (int j = 0; j < 4; ++j) {
    v[j] = sel[b * S + tid * 4 + j];
    lp[j] = tot;
    tot += v[j];
  }
  int inc = tot;
#pragma unroll
  for (int off = 1; off < 64; off <<= 1) {
    int n = __shfl_up(inc, off);
    if (lane >= off) inc += n;
  }
  if (lane == 63) wsum[wv] = inc;
  __syncthreads();
  int wbase = 0;
#pragma unroll
  for (int w = 0; w < 4; ++w)
    if (w < wv) wbase += wsum[w];
  int ex = wbase + inc - tot;
#pragma unroll
  for (int j = 0; j < 4; ++j) pos[b * S + tid * 4 + j] = ex + lp[j];
  if (tid == 0) nsel[b] = wsum[0] + wsum[1] + wsum[2] + wsum[3];
}

// ---------------- gather selected K/V rows into dense Kc/Vc -------------------
// grid (S/8, 1, 16); 8 source rows per block, 32 lanes/row.
__global__ __launch_bounds__(256) void compact_kernel(const u16* __restrict__ qkv,
                                                      const int* __restrict__ sel,
                                                      const int* __restrict__ pos,
                                                      const int* __restrict__ nsel,
                                                      u16* __restrict__ Kc,
                                                      u16* __restrict__ Vc) {
  int z = blockIdx.z;
  int strm = z >> 3, b = z & 7;
  int tid = threadIdx.x;
  int r = tid >> 5, c = tid & 31;
  int srow = blockIdx.x * 8 + r;
  const u16* qb = qkv + (size_t)strm * M * C3;
  size_t base_out = (size_t)(strm * 8 + b) * S;
  if (sel[b * S + srow]) {
    int d = pos[b * S + srow];
    const u16* srcK = qb + ((size_t)(b * S + srow)) * C3 + C;
    const u16* srcV = srcK + C;
    u16* dK = Kc + (base_out + d) * C;
    u16* dV = Vc + (base_out + d) * C;
    for (int j = c; j < 48; j += 32) {
      *reinterpret_cast<short8*>(dK + j * 8) =
          *reinterpret_cast<const short8*>(srcK + j * 8);
      *reinterpret_cast<short8*>(dV + j * 8) =
          *reinterpret_cast<const short8*>(srcV + j * 8);
    }
  }
  if (blockIdx.x == 0) {  // zero-pad rows [ns, min(ns+64, S))
    int ns = nsel[b];
    short8 z8 = {};
    for (int u = tid; u < 64 * 48; u += 256) {
      int row = ns + u / 48;
      if (row < S) {
        int j = u % 48;
        *reinterpret_cast<short8*>(Kc + (base_out + row) * C + j * 8) = z8;
        *reinterpret_cast<short8*>(Vc + (base_out + row) * C + j * 8) = z8;
      }
    }
  }
}

// ---------------- batched LayerNorm over C=384 -> bf16, one wave per row ------
__global__ __launch_bounds__(64) void ln_kernel(const float* __restrict__ x,
                                                const float* __restrict__ g_all,
                                                const float* __restrict__ b_all,
                                                u16* __restrict__ y) {
  int row = blockIdx.x, t = threadIdx.x;
  int strm = row >> 13;  // row / M
  const float* g = g_all + strm * C;
  const float* bt = b_all + strm * C;
  const float* xr = x + (size_t)row * C;
  float v[C / 64];
  float s = 0.f, s2 = 0.f;
#pragma unroll
  for (int i = 0; i < C / 64; ++i) {
    float a = xr[t + i * 64];
    v[i] = a;
    s += a;
    s2 += a * a;
  }
  for (int off = 32; off; off >>= 1) {
    s += __shfl_down(s, off);
    s2 += __shfl_down(s2, off);
  }
  s = __shfl(s, 0);
  s2 = __shfl(s2, 0);
  float mean = s / C;
  float var = s2 / C - mean * mean;
  float inv = rsqrtf(var + 1e-5f);
#pragma unroll
  for (int i = 0; i < C / 64; ++i) {
    int c = t + i * 64;
    y[(size_t)row * C + c] = f2bf((v[i] - mean) * inv * g[c] + bt[c]);
  }
}

// ---------------- flash MFMA attention v5 (compacted keys) --------------------
// QBLK=64 (v3 structure), dynamic tile count from nsel[b], in-register tail
// masking, defer-max, P in registers, setprio around MFMA clusters.
__global__ __launch_bounds__(256) void attn_mfma(const u16* __restrict__ qkv,
                                                 const u16* __restrict__ Kc,
                                                 const u16* __restrict__ Vc,
                                                 const int* __restrict__ nsel,
                                                 u16* __restrict__ o_out) {
  __shared__ u16 Ks[64][104];
  __shared__ u16 Vt[96][72];

  int bq0 = blockIdx.x * 64;
  int bh2 = blockIdx.y;                  // 64 = 2 streams x 8 b x 4 h
  int strm = bh2 >> 5, bh = bh2 & 31;
  int b = bh >> 2, h = bh & 3;
  qkv += (size_t)strm * M * C3;
  o_out += (size_t)strm * M * C;
  const u16* kb0 = Kc + ((size_t)(strm * 8 + b)) * S * C + h * HD;
  const u16* vb0 = Vc + ((size_t)(strm * 8 + b)) * S * C + h * HD;
  int ns = nsel[b];
  int tid = threadIdx.x;
  int wave = tid >> 6, lane = tid & 63;
  int lo = lane & 15, g = lane >> 4;

  // Q fragments in registers, pre-scaled by 1/sqrt(HD)
  const float scale = 0.1020620726f;
  short8 bq[3];
  const u16* qrow = qkv + ((size_t)(b * S + bq0 + wave * 16 + lo)) * C3 + h * HD;
#pragma unroll
  for (int c = 0; c < 3; ++c) {
    short8 q = *reinterpret_cast<const short8*>(qrow + c * 32 + g * 8);
    short8 r;
#pragma unroll
    for (int e = 0; e < 8; ++e) r[e] = (short)f2bf(bf2f((u16)q[e]) * scale);
    bq[c] = r;
  }

  float m = -30.f, l = 0.f;
  f32x4 o[6] = {};
  int nt64 = (ns + 63) & ~63;

  for (int kt0 = 0; kt0 < nt64; kt0 += 64) {
    const u16* kbase = kb0 + (size_t)kt0 * C;
    const u16* vbase = vb0 + (size_t)kt0 * C;
#pragma unroll
    for (int i = 0; i < 3; ++i) {
      int idx = i * 256 + tid;
      int r = idx / 12, j = idx - r * 12;
      *reinterpret_cast<short8*>(&Ks[r][j * 8]) =
          *reinterpret_cast<const short8*>(kbase + (size_t)r * C + j * 8);
    }
#pragma unroll
    for (int i = 0; i < 3; ++i) {
      int idx = i * 256 + tid;
      int r = idx & 63, j = idx >> 6;
      short8 v = *reinterpret_cast<const short8*>(vbase + (size_t)r * C + j * 8);
#pragma unroll
      for (int e = 0; e < 8; ++e) Vt[j * 8 + e][r] = (u16)v[e];
    }
    __syncthreads();

    // QK^T: st[t4][r] = S[k=kt0+16t4+4g+r][q=lo]
    f32x4 st[4] = {};
    __builtin_amdgcn_s_setprio(1);
#pragma unroll
    for (int c = 0; c < 3; ++c)
#pragma unroll
      for (int t4 = 0; t4 < 4; ++t4) {
        short8 ak = *reinterpret_cast<const short8*>(&Ks[t4 * 16 + lo][c * 32 + g * 8]);
        st[t4] = __builtin_amdgcn_mfma_f32_16x16x32_bf16(ak, bq[c], st[t4], 0, 0, 0);
      }
    __builtin_amdgcn_s_setprio(0);

    float p[4][4];
    float pmax = -INFINITY;
#pragma unroll
    for (int t4 = 0; t4 < 4; ++t4)
#pragma unroll
      for (int r = 0; r < 4; ++r) p[t4][r] = st[t4][r];
    if (kt0 + 64 > ns) {  // tail tile: mask pad slots
#pragma unroll
      for (int t4 = 0; t4 < 4; ++t4)
#pragma unroll
        for (int r = 0; r < 4; ++r)
          if (kt0 + t4 * 16 + g * 4 + r >= ns) p[t4][r] = -1e9f;
    }
#pragma unroll
    for (int t4 = 0; t4 < 4; ++t4)
#pragma unroll
      for (int r = 0; r < 4; ++r) pmax = fmaxf(pmax, p[t4][r]);
    pmax = fmaxf(pmax, __shfl_xor(pmax, 16));
    pmax = fmaxf(pmax, __shfl_xor(pmax, 32));
    if (__any(pmax - m > 8.f)) {
      float mn = fmaxf(m, pmax);
      float sc = __expf(m - mn);
      m = mn;
      l *= sc;
#pragma unroll
      for (int dt = 0; dt < 6; ++dt)
#pragma unroll
        for (int r = 0; r < 4; ++r) o[dt][r] *= sc;
    }
    float ps = 0.f;
#pragma unroll
    for (int t4 = 0; t4 < 4; ++t4)
#pragma unroll
      for (int r = 0; r < 4; ++r) {
        float e = __expf(p[t4][r] - m);
        p[t4][r] = e;
        ps += e;
      }
    ps += __shfl_xor(ps, 16);
    ps += __shfl_xor(ps, 32);
    l += ps;

    // pack P -> bf16 B-fragments; slot e<4: k=32h2+4g+e, e>=4: k=32h2+16+4g+(e-4)
    short8 bp[2];
#pragma unroll
    for (int h2 = 0; h2 < 2; ++h2) {
      union { short8 s8; unsigned int u[4]; } u_;
      u_.u[0] = cvtpk(p[2 * h2][0], p[2 * h2][1]);
      u_.u[1] = cvtpk(p[2 * h2][2], p[2 * h2][3]);
      u_.u[2] = cvtpk(p[2 * h2 + 1][0], p[2 * h2 + 1][1]);
      u_.u[3] = cvtpk(p[2 * h2 + 1][2], p[2 * h2 + 1][3]);
      bp[h2] = u_.s8;
    }

    // PV: A = V^T with the same k-slot permutation
    __builtin_amdgcn_s_setprio(1);
#pragma unroll
    for (int dt = 0; dt < 6; ++dt)
#pragma unroll
      for (int h2 = 0; h2 < 2; ++h2) {
        union { short8 s8; short4 s4[2]; } a_;
        a_.s4[0] = *reinterpret_cast<const short4*>(&Vt[dt * 16 + lo][h2 * 32 + g * 4]);
        a_.s4[1] = *reinterpret_cast<const short4*>(&Vt[dt * 16 + lo][h2 * 32 + 16 + g * 4]);
        o[dt] = __builtin_amdgcn_mfma_f32_16x16x32_bf16(a_.s8, bp[h2], o[dt], 0, 0, 0);
      }
    __builtin_amdgcn_s_setprio(0);
    __syncthreads();
  }

  float inv = 1.f / l;
  size_t orow = ((size_t)(b * S + bq0 + wave * 16 + lo)) * C + h * HD;
#pragma unroll
  for (int dt = 0; dt < 6; ++dt)
#pragma unroll
    for (int r = 0; r < 4; ++r)
      o_out[orow + dt * 16 + g * 4 + r] = f2bf(o[dt][r] * inv);
}

// ---------------- final scatter, LDS-tiled transpose ----------------
__global__ __launch_bounds__(256) void final_kernel(const float* __restrict__ x0,
                                                    const float* __restrict__ x1,
                                                    const int* __restrict__ sel,
                                                    const float* __restrict__ f_ir,
                                                    const float* __restrict__ f_vis,
                                                    float* __restrict__ out) {
  __shared__ float tile[32][33];
  int b = blockIdx.z;
  int s0 = blockIdx.x * 32, c0 = blockIdx.y * 32;
  int tx = threadIdx.x, ty = threadIdx.y;  // 32 x 8
#pragma unroll
  for (int i = 0; i < 32; i += 8) {
    size_t r = ((size_t)(b * S + s0 + ty + i)) * C + c0 + tx;
    tile[ty + i][tx] = x0[r] + x1[r];
  }
  __syncthreads();
  const int* selb = sel + b * S;
#pragma unroll
  for (int i = 0; i < 32; i += 8) {
    int c = c0 + ty + i, s = s0 + tx;
    size_t idx = ((size_t)(b * C + c)) * S + s;
    float v = selb[s] ? tile[tx][ty + i] : (f_ir[idx] + f_vis[idx]);
    out[idx] = v;
  }
}

}  // namespace

extern "C" void kernel_launch(void* const* d_in, const int* in_sizes, int n_in,
                              void* d_out, int out_size, void* d_ws, size_t ws_size,
                              hipStream_t stream) {
  const float* f_ir = (const float*)d_in[0];
  const float* f_vis = (const float*)d_in[1];
  const float* agent_w1 = (const float*)d_in[2];
  const float* agent_b1 = (const float*)d_in[3];
  const float* agent_w2 = (const float*)d_in[4];
  const float* agent_b2 = (const float*)d_in[5];
  const float* norm_g = (const float*)d_in[6];
  const float* norm_b = (const float*)d_in[7];
  const float* in_w = (const float*)d_in[8];
  const float* in_b = (const float*)d_in[9];
  const float* out_w = (const float*)d_in[10];
  const float* out_b = (const float*)d_in[11];
  const float* ffn_w1 = (const float*)d_in[12];
  const float* ffn_b1 = (const float*)d_in[13];
  const float* ffn_w2 = (const float*)d_in[14];
  const float* ffn_b2 = (const float*)d_in[15];
  float* out = (float*)d_out;

  constexpr size_t MS = (size_t)M * C;
  float* ws = (float*)d_ws;
  float* x0 = ws;                                  // fp32 [2M,C]: x0 | x1
  u16* Dbf = (u16*)(x0 + 2 * MS);                  // [2M,C]  xn / attn_o (bf16)
  u16* qkvb = Dbf + 2 * MS;                        // [2M,C3] qkv (bf16)
  u16* Hext = qkvb + (size_t)2 * M * C3;           // [M,FFN] u16 extension
  u16* wb_in = Hext + (size_t)M * FFN;             // 2*C3*C
  u16* wb_out = wb_in + 2 * C3 * C;                // 2*C*C
  u16* wb_f1 = wb_out + 2 * C * C;                 // 2*FFN*C
  u16* wb_f2 = wb_f1 + 2 * FFN * C;                // 2*C*FFN
  u16* w1hi = wb_f2 + 2 * C * FFN;                 // 512*768
  u16* w1lo = w1hi + HID * K2C;                    // 512*768
  int* sel = (int*)(w1lo + HID * K2C);
  int* ctr = sel + M;
  int* fixlist = ctr + 1;
  int* pos = fixlist + FIXCAP;                     // [8][1024]
  int* nsel = pos + B * S;                         // [8]
  // aliases (each dead before its host region is rewritten)
  u16* Ahi = qkvb;                                 // [M,768]  (dead before QKV)
  u16* Alo = qkvb + (size_t)M * K2C;               // [M,768]
  float* hiddenF = (float*)Hext;                   // [M,HID] fp32 (dead before compact)
  u16* Kc = Hext;                                  // [16][S][C] compact K
  u16* Vc = Hext + (size_t)16 * S * C;             // [16][S][C] compact V
  u16* Hbf = qkvb;                                 // FFN hidden [2M,FFN] spans qkvb+KcHalf
  float* x1 = x0 + MS;

  // 0) weights -> bf16 (one dispatch; also zeroes fixup ctr) + w1 hi/lo split
  cvt_all<<<(N4_ALL + 255) / 256, 256, 0, stream>>>(in_w, out_w, ffn_w1, ffn_w2,
                                                    wb_in, ctr);
  cvt_hilo<<<(HID * K2C / 4 + 255) / 256, 256, 0, stream>>>(agent_w1, w1hi, w1lo,
                                                            HID * K2C / 4);

  // 1) both transposes in one dispatch (fused agent hi/lo activation emit)
  transpose_cs<<<dim3(S / 32, C / 32, 2 * B), dim3(32, 8), 0, stream>>>(
      f_ir, f_vis, x0, Ahi, Alo);

  // 2) agent hidden via fused bf16x3 MFMA + SiLU
  gemm_agent<<<dim3(HID / 128, M / 128), 256, 0, stream>>>(Ahi, Alo, w1hi, w1lo,
                                                           agent_b1, hiddenF);

  // 3) selection mask + exact fp32 fixup + per-batch prefix
  sel_kernel<<<M, 64, 0, stream>>>(hiddenF, agent_w2, agent_b2, sel, ctr, fixlist);
  fixup_kernel<<<64, 256, 0, stream>>>(x0, x1, agent_w1, agent_b1, agent_w2,
                                       agent_b2, ctr, fixlist, sel);
  prefix_kernel<<<B, 256, 0, stream>>>(sel, pos, nsel);

  // 4) mixer, both streams batched end-to-end
  ln_kernel<<<2 * M, 64, 0, stream>>>(x0, norm_g, norm_b, Dbf);
  gemm_bf16<0><<<dim3(C3 / 128, M / 128, 2), 256, 0, stream>>>(
      Dbf, wb_in, in_b, nullptr, qkvb, C3, C, M * C, C3 * C, C3, M * C3);
  compact_kernel<<<dim3(S / 8, 1, 16), 256, 0, stream>>>(qkvb, sel, pos, nsel,
                                                         Kc, Vc);
  attn_mfma<<<dim3(S / 64, B * HEADS * 2), 256, 0, stream>>>(qkvb, Kc, Vc, nsel,
                                                             Dbf);
  gemm_bf16<2><<<dim3(C / 128, M / 128, 2), 256, 0, stream>>>(
      Dbf, wb_out, out_b, x0, nullptr, C, C, M * C, C * C, C, M * C);
  ln_kernel<<<2 * M, 64, 0, stream>>>(x0, norm_g, norm_b, Dbf);
  gemm_bf16<1><<<dim3(FFN / 128, M / 128, 2), 256, 0, stream>>>(
      Dbf, wb_f1, ffn_b1, nullptr, Hbf, FFN, C, M * C, FFN * C, FFN, M * FFN);
  gemm_bf16<2><<<dim3(C / 128, M / 128, 2), 256, 0, stream>>>(
      Hbf, wb_f2, ffn_b2, x0, nullptr, C, FFN, M * FFN, C * FFN, C, M * C);

  // 5) final scatter back to [B,C,H,W]
  final_kernel<<<dim3(S / 32, C / 32, B), dim3(32, 8), 0, stream>>>(
      x0, x1, sel, f_ir, f_vis, out);
}